// Round 8
// baseline (156.935 us; speedup 1.0000x reference)
//
#include <hip/hip_runtime.h>

#define N_NODES 50000
#define N_EDGES 800000
#define D_IN 96
#define HID 64
#define D_OUT 16

#define EPB 2048                                   // edges per block (passes A/C)
#define NBLK_E ((N_EDGES + EPB - 1) / EPB)         // 391
#define BSHIFT 7                                   // 128 nodes per bucket
#define NBKT ((N_NODES + 127) / 128)               // 391
#define DCAP 2560                                  // Ddst LDS edge staging cap

typedef unsigned short u16;
typedef unsigned int u32;
typedef __attribute__((ext_vector_type(4))) float f32x4;
typedef __attribute__((ext_vector_type(8))) short bf16x8;

__device__ inline float bflo(u32 v) { union { u32 i; float f; } u; u.i = v << 16; return u.f; }
__device__ inline float bfhi(u32 v) { union { u32 i; float f; } u; u.i = v & 0xffff0000u; return u.f; }
__device__ inline u16 f2bf(float f) {              // RTNE
    union { float f; u32 i; } u; u.f = f;
    return (u16)((u.i + 0x7fffu + ((u.i >> 16) & 1u)) >> 16);
}
__device__ inline u32 pack2(float lo, float hi) {
    return (u32)f2bf(lo) | ((u32)f2bf(hi) << 16);
}

// ============ CSR build: two-level counting sort, zero global data atomics ============

__global__ __launch_bounds__(256)
void passA(const int* __restrict__ src, const int* __restrict__ dst,
           int* __restrict__ blk_cnt_src, int* __restrict__ blk_cnt_dst,
           int* __restrict__ done) {
    __shared__ int hs[NBKT], hd[NBKT];
    const int t = threadIdx.x, blk = blockIdx.x;
    if (blk == 0 && t == 0) *done = 0;             // reset for fused passB (every call)
    for (int i = t; i < NBKT; i += 256) { hs[i] = 0; hd[i] = 0; }
    __syncthreads();
    const int e0 = blk * EPB;
    const int e1 = (e0 + EPB < N_EDGES) ? e0 + EPB : N_EDGES;
    for (int e = e0 + t; e < e1; e += 256) {
        atomicAdd(&hs[src[e] >> BSHIFT], 1);
        atomicAdd(&hd[dst[e] >> BSHIFT], 1);
    }
    __syncthreads();
    for (int b = t; b < NBKT; b += 256) {
        blk_cnt_src[b * NBLK_E + blk] = hs[b];
        blk_cnt_dst[b * NBLK_E + blk] = hd[b];
    }
}

// Fused passB + passB2: per-bucket scans over blocks; last finishing block scans
// the bucket totals into base_src/base_dst (decoupled completion pattern).
__global__ __launch_bounds__(64)
void passB(int* __restrict__ blk_cnt_src, int* __restrict__ blk_cnt_dst,
           int* __restrict__ tot_src, int* __restrict__ tot_dst,
           int* __restrict__ base_src, int* __restrict__ base_dst,
           int* __restrict__ row_ptr, int* __restrict__ done) {
    const int b = blockIdx.x;
    int* cnt; int* tot;
    if (b < NBKT) { cnt = blk_cnt_dst + b * NBLK_E;          tot = tot_dst + b; }
    else          { cnt = blk_cnt_src + (b - NBKT) * NBLK_E; tot = tot_src + (b - NBKT); }
    const int lane = threadIdx.x;
    int carry = 0;
    for (int base0 = 0; base0 < NBLK_E; base0 += 64) {
        int i = base0 + lane;
        int v = (i < NBLK_E) ? cnt[i] : 0;
        int incl = v;
        #pragma unroll
        for (int off = 1; off < 64; off <<= 1) {
            int x = __shfl_up(incl, off);
            if (lane >= off) incl += x;
        }
        if (i < NBLK_E) cnt[i] = carry + incl - v;
        carry += __shfl(incl, 63);
    }
    if (lane == 0) *tot = carry;
    // --- last-block completion: scan totals -> bases ---
    __shared__ int is_last;
    __threadfence();
    if (lane == 0) is_last = (atomicAdd(done, 1) == 2 * NBKT - 1);
    __syncthreads();
    if (!is_last) return;
    __threadfence();
    for (int pass = 0; pass < 2; ++pass) {
        const int* tt = pass ? tot_src : tot_dst;
        int* bas = pass ? base_src : base_dst;
        int carry2 = 0;
        for (int base0 = 0; base0 < NBKT; base0 += 64) {
            int i = base0 + lane;
            int v = (i < NBKT) ? tt[i] : 0;
            int incl = v;
            #pragma unroll
            for (int off = 1; off < 64; off <<= 1) {
                int x = __shfl_up(incl, off);
                if (lane >= off) incl += x;
            }
            if (i < NBKT) bas[i + 1] = carry2 + incl;
            carry2 += __shfl(incl, 63);
        }
        if (lane == 0) bas[0] = 0;
    }
    if (lane == 0) row_ptr[N_NODES] = N_EDGES;
}

// Pass C: scatter edges into coarse-bucket-sorted arrays; dst side as int2 pairs.
__global__ __launch_bounds__(256)
void passC(const int* __restrict__ src, const int* __restrict__ dst,
           const int* __restrict__ blk_off_src, const int* __restrict__ blk_off_dst,
           const int* __restrict__ base_src, const int* __restrict__ base_dst,
           int* __restrict__ sorted_srconly, int2* __restrict__ sorted_pair) {
    __shared__ int cs[NBKT], cd[NBKT];
    const int t = threadIdx.x, blk = blockIdx.x;
    for (int b = t; b < NBKT; b += 256) {
        cs[b] = base_src[b] + blk_off_src[b * NBLK_E + blk];
        cd[b] = base_dst[b] + blk_off_dst[b * NBLK_E + blk];
    }
    __syncthreads();
    const int e0 = blk * EPB;
    const int e1 = (e0 + EPB < N_EDGES) ? e0 + EPB : N_EDGES;
    for (int e = e0 + t; e < e1; e += 256) {
        int sv = src[e], dv = dst[e];
        int ps = atomicAdd(&cs[sv >> BSHIFT], 1);
        sorted_srconly[ps] = sv;
        int pd = atomicAdd(&cd[dv >> BSHIFT], 1);
        sorted_pair[pd] = make_int2(dv, sv);
    }
}

__global__ __launch_bounds__(256)
void passDsrc(const int* __restrict__ base_src, const int* __restrict__ sorted_srconly,
              float* __restrict__ dis) {
    __shared__ int hist[128];
    const int b = blockIdx.x, t = threadIdx.x;
    if (t < 128) hist[t] = 0;
    __syncthreads();
    const int eb = base_src[b], ee = base_src[b + 1];
    for (int i = eb + t; i < ee; i += 256)
        atomicAdd(&hist[sorted_srconly[i] & 127], 1);
    __syncthreads();
    const int node = (b << BSHIFT) + t;
    if (t < 128 && node < N_NODES) {
        int c = hist[t];
        dis[node] = c > 0 ? rsqrtf((float)c) : 0.0f;
    }
}

// Pass Ddst: per-bucket fine CSR: row_ptr, node-grouped wpair = {src, -dis[s]*dis[d]}.
__global__ __launch_bounds__(256)
void passDdst(const int* __restrict__ base_dst, const int2* __restrict__ sorted_pair,
              const float* __restrict__ dis,
              int* __restrict__ row_ptr, int2* __restrict__ wpair) {
    __shared__ int s_d[DCAP];
    __shared__ int s_s[DCAP];
    __shared__ int hist[128];
    __shared__ int cur[128];
    __shared__ float s_dis[128];
    const int b = blockIdx.x, t = threadIdx.x;
    if (t < 128) {
        hist[t] = 0;
        int node = (b << BSHIFT) + t;
        s_dis[t] = (node < N_NODES) ? dis[node] : 0.0f;
    }
    __syncthreads();
    const int eb = base_dst[b], ee = base_dst[b + 1];
    const int cnt = ee - eb;
    const int stage = cnt < DCAP ? cnt : DCAP;
    for (int i = t; i < stage; i += 256) {
        int2 p = sorted_pair[eb + i];
        int d = p.x & 127;
        s_d[i] = d;
        s_s[i] = p.y;
        atomicAdd(&hist[d], 1);
    }
    for (int i = stage + t; i < cnt; i += 256)
        atomicAdd(&hist[sorted_pair[eb + i].x & 127], 1);
    __syncthreads();
    if (t < 64) {
        int v0 = hist[2 * t], v1 = hist[2 * t + 1];
        int p = v0 + v1;
        int incl = p;
        #pragma unroll
        for (int off = 1; off < 64; off <<= 1) {
            int x = __shfl_up(incl, off);
            if (t >= off) incl += x;
        }
        int excl = incl - p;
        cur[2 * t] = excl;
        cur[2 * t + 1] = excl + v0;
        int node = (b << BSHIFT) + 2 * t;
        if (node < N_NODES) row_ptr[node] = eb + excl;
        if (node + 1 < N_NODES) row_ptr[node + 1] = eb + excl + v0;
    }
    __syncthreads();
    for (int i = t; i < stage; i += 256) {
        int ln = s_d[i], sv = s_s[i];
        int slot = atomicAdd(&cur[ln], 1);
        wpair[eb + slot] = make_int2(sv, __float_as_int(-dis[sv] * s_dis[ln]));
    }
    for (int i = stage + t; i < cnt; i += 256) {
        int2 p = sorted_pair[eb + i];
        int ln = p.x & 127, sv = p.y;
        int slot = atomicAdd(&cur[ln], 1);
        wpair[eb + slot] = make_int2(sv, __float_as_int(-dis[sv] * s_dis[ln]));
    }
}

// ============ weight pack (both layers, MFMA B-fragment order) ============

__global__ void packB_both(const float* __restrict__ W1, const float* __restrict__ W2,
                           u16* __restrict__ Pb1, u16* __restrict__ Pb2) {
    int t = blockIdx.x * blockDim.x + threadIdx.x;
    if (t < 3 * D_IN * HID) {                    // 18432: K=96, NC=192, OUTW=64
        int j = t & 7, rest = t >> 3;
        int c = rest % 192, i = (rest / 192) * 8 + j;
        int kc = c / 64, o = c % 64;
        Pb1[t] = f2bf(W1[((long)kc * D_IN + i) * HID + o]);
    } else if (t < 3 * D_IN * HID + 3 * HID * D_OUT) {
        int t2 = t - 3 * D_IN * HID;             // 3072: K=64, NC=48, OUTW=16
        int j = t2 & 7, rest = t2 >> 3;
        int c = rest % 48, i = (rest / 48) * 8 + j;
        int kc = c / 16, o = c % 16;
        Pb2[t2] = f2bf(W2[((long)kc * HID + i) * D_OUT + o]);
    }
}

// ============ MFMA GEMM: Z = A[N,K] @ B[K,NC], plane-split output ============
// col c = ct*16+r16 stored at Z + (ct/CPK)*CBS + node*LDZ + (ct%CPK)*16 + r16

template<int K, int NC, int LDZ, int CPK, long CBS, bool AF32>
__global__ __launch_bounds__(256)
void gemm_mfma(const void* __restrict__ Av, const u16* __restrict__ P, u16* __restrict__ Z) {
    constexpr int KT = K / 32;
    constexpr int TOT = K * NC;
    __shared__ u16 sP[TOT];
    for (int idx = threadIdx.x * 8; idx < TOT; idx += 2048)
        *(uint4*)&sP[idx] = *(const uint4*)&P[idx];
    __syncthreads();
    const int lane = threadIdx.x & 63;
    const int tile = blockIdx.x * 4 + (threadIdx.x >> 6);
    if (tile * 16 >= N_NODES) return;
    const int node0 = tile * 16;
    const int sub = lane >> 4, r16 = lane & 15;
    bf16x8 a[KT];
    if (AF32) {
        const float* ar = (const float*)Av + (long)(node0 + r16) * K + sub * 8;
        #pragma unroll
        for (int kt = 0; kt < KT; ++kt) {
            float4 a0 = *(const float4*)(ar + kt * 32);
            float4 a1 = *(const float4*)(ar + kt * 32 + 4);
            union { bf16x8 v; uint4 q; } u;
            u.q.x = pack2(a0.x, a0.y); u.q.y = pack2(a0.z, a0.w);
            u.q.z = pack2(a1.x, a1.y); u.q.w = pack2(a1.z, a1.w);
            a[kt] = u.v;
        }
    } else {
        const u16* ar = (const u16*)Av + (long)(node0 + r16) * K + sub * 8;
        #pragma unroll
        for (int kt = 0; kt < KT; ++kt)
            a[kt] = *(const bf16x8*)(ar + kt * 32);
    }
    #pragma unroll
    for (int ct = 0; ct < NC / 16; ++ct) {
        f32x4 acc = {0.f, 0.f, 0.f, 0.f};
        #pragma unroll
        for (int kt = 0; kt < KT; ++kt) {
            bf16x8 bfr = *(const bf16x8*)&sP[((kt * 4 + sub) * NC + ct * 16 + r16) * 8];
            acc = __builtin_amdgcn_mfma_f32_16x16x32_bf16(a[kt], bfr, acc, 0, 0, 0);
        }
        u16* zp = Z + (long)(ct / CPK) * CBS + (long)(node0 + sub * 4) * LDZ + (ct % CPK) * 16 + r16;
        #pragma unroll
        for (int r = 0; r < 4; ++r)
            zp[(long)r * LDZ] = f2bf(acc[r]);
    }
}

// ============ gather propagate: LDS-staged int2 pairs, 8-way unroll, fused epilogues ====
// EPI_S  : S   = aux1 + 2*acc                      (bf16 out)
// EPI_H  : h   = relu(aux1 - aux2 + acc + bias)    (bf16 out)
// EPI_OUT: out = aux1 - aux2 + acc + bias          (f32 out)

#define EPI_S 0
#define EPI_H 1
#define EPI_OUT 2

__device__ inline void accum8(float (&acc)[8], float we, uint4 q) {
    acc[0] = fmaf(we, bflo(q.x), acc[0]);
    acc[1] = fmaf(we, bfhi(q.x), acc[1]);
    acc[2] = fmaf(we, bflo(q.y), acc[2]);
    acc[3] = fmaf(we, bfhi(q.y), acc[3]);
    acc[4] = fmaf(we, bflo(q.z), acc[4]);
    acc[5] = fmaf(we, bfhi(q.z), acc[5]);
    acc[6] = fmaf(we, bflo(q.w), acc[6]);
    acc[7] = fmaf(we, bfhi(q.w), acc[7]);
}

template<int F, int NPB, int CAP, int EPI>
__global__ __launch_bounds__(256)
void gather_prop(const int* __restrict__ row_ptr, const int2* __restrict__ wp,
                 const u16* __restrict__ g,       // gather source plane [N,F]
                 const u16* __restrict__ aux1,
                 const u16* __restrict__ aux2,
                 const float* __restrict__ bias,
                 void* __restrict__ outp) {
    __shared__ int2 s_p[CAP];
    __shared__ int s_beg[NPB + 1];
    const int tid = threadIdx.x;
    const int node0 = blockIdx.x * NPB;
    if (tid <= NPB) {
        int n = node0 + tid;
        s_beg[tid] = row_ptr[n > N_NODES ? N_NODES : n];
    }
    __syncthreads();
    const int ebeg = s_beg[0];
    const int cnt = s_beg[NPB] - ebeg;
    const int stage = cnt < CAP ? cnt : CAP;
    for (int e = tid; e < stage; e += 256)
        s_p[e] = wp[ebeg + e];
    __syncthreads();
    constexpr int CPN = F / 8;
    const int nl = tid / CPN;
    const int node = node0 + nl;
    if (nl >= NPB || node >= N_NODES) return;
    const int c8 = (tid % CPN) * 8;
    float acc[8];
    #pragma unroll
    for (int j = 0; j < 8; ++j) acc[j] = 0.0f;
    const int beg = s_beg[nl] - ebeg;
    const int end = s_beg[nl + 1] - ebeg;
    const int mid = end < stage ? end : stage;
    int e = beg;
    for (; e + 8 <= mid; e += 8) {                 // 8-way MLP from LDS pairs
        int2 p0 = s_p[e],     p1 = s_p[e + 1], p2 = s_p[e + 2], p3 = s_p[e + 3];
        int2 p4 = s_p[e + 4], p5 = s_p[e + 5], p6 = s_p[e + 6], p7 = s_p[e + 7];
        uint4 q0 = *(const uint4*)(g + (long)p0.x * F + c8);
        uint4 q1 = *(const uint4*)(g + (long)p1.x * F + c8);
        uint4 q2 = *(const uint4*)(g + (long)p2.x * F + c8);
        uint4 q3 = *(const uint4*)(g + (long)p3.x * F + c8);
        uint4 q4 = *(const uint4*)(g + (long)p4.x * F + c8);
        uint4 q5 = *(const uint4*)(g + (long)p5.x * F + c8);
        uint4 q6 = *(const uint4*)(g + (long)p6.x * F + c8);
        uint4 q7 = *(const uint4*)(g + (long)p7.x * F + c8);
        accum8(acc, __int_as_float(p0.y), q0); accum8(acc, __int_as_float(p1.y), q1);
        accum8(acc, __int_as_float(p2.y), q2); accum8(acc, __int_as_float(p3.y), q3);
        accum8(acc, __int_as_float(p4.y), q4); accum8(acc, __int_as_float(p5.y), q5);
        accum8(acc, __int_as_float(p6.y), q6); accum8(acc, __int_as_float(p7.y), q7);
    }
    for (; e + 4 <= mid; e += 4) {
        int2 p0 = s_p[e], p1 = s_p[e + 1], p2 = s_p[e + 2], p3 = s_p[e + 3];
        uint4 q0 = *(const uint4*)(g + (long)p0.x * F + c8);
        uint4 q1 = *(const uint4*)(g + (long)p1.x * F + c8);
        uint4 q2 = *(const uint4*)(g + (long)p2.x * F + c8);
        uint4 q3 = *(const uint4*)(g + (long)p3.x * F + c8);
        accum8(acc, __int_as_float(p0.y), q0); accum8(acc, __int_as_float(p1.y), q1);
        accum8(acc, __int_as_float(p2.y), q2); accum8(acc, __int_as_float(p3.y), q3);
    }
    for (; e < mid; ++e) {
        int2 p = s_p[e];
        uint4 q = *(const uint4*)(g + (long)p.x * F + c8);
        accum8(acc, __int_as_float(p.y), q);
    }
    for (e = (beg > stage ? beg : stage); e < end; ++e) {   // overflow fallback (rare)
        int2 p = wp[ebeg + e];
        uint4 q = *(const uint4*)(g + (long)p.x * F + c8);
        accum8(acc, __int_as_float(p.y), q);
    }
    if (EPI == EPI_S) {
        const uint4 z1 = *(const uint4*)(aux1 + (long)node * F + c8);
        uint4 r;
        r.x = pack2(bflo(z1.x) + 2.f * acc[0], bfhi(z1.x) + 2.f * acc[1]);
        r.y = pack2(bflo(z1.y) + 2.f * acc[2], bfhi(z1.y) + 2.f * acc[3]);
        r.z = pack2(bflo(z1.z) + 2.f * acc[4], bfhi(z1.z) + 2.f * acc[5]);
        r.w = pack2(bflo(z1.w) + 2.f * acc[6], bfhi(z1.w) + 2.f * acc[7]);
        *(uint4*)((u16*)outp + (long)node * F + c8) = r;
    } else {
        const uint4 z0 = *(const uint4*)(aux1 + (long)node * F + c8);
        const uint4 z2 = *(const uint4*)(aux2 + (long)node * F + c8);
        const float* bb = bias + c8;
        float v0 = bflo(z0.x) - bflo(z2.x) + acc[0] + bb[0];
        float v1 = bfhi(z0.x) - bfhi(z2.x) + acc[1] + bb[1];
        float v2 = bflo(z0.y) - bflo(z2.y) + acc[2] + bb[2];
        float v3 = bfhi(z0.y) - bfhi(z2.y) + acc[3] + bb[3];
        float v4 = bflo(z0.z) - bflo(z2.z) + acc[4] + bb[4];
        float v5 = bfhi(z0.z) - bfhi(z2.z) + acc[5] + bb[5];
        float v6 = bflo(z0.w) - bflo(z2.w) + acc[6] + bb[6];
        float v7 = bfhi(z0.w) - bfhi(z2.w) + acc[7] + bb[7];
        if (EPI == EPI_H) {
            uint4 r;
            r.x = pack2(fmaxf(v0, 0.f), fmaxf(v1, 0.f));
            r.y = pack2(fmaxf(v2, 0.f), fmaxf(v3, 0.f));
            r.z = pack2(fmaxf(v4, 0.f), fmaxf(v5, 0.f));
            r.w = pack2(fmaxf(v6, 0.f), fmaxf(v7, 0.f));
            *(uint4*)((u16*)outp + (long)node * F + c8) = r;
        } else {
            float* op = (float*)outp + (long)node * F + c8;
            *(float4*)op = make_float4(v0, v1, v2, v3);
            *(float4*)(op + 4) = make_float4(v4, v5, v6, v7);
        }
    }
}

// ============ launch ============

extern "C" void kernel_launch(void* const* d_in, const int* in_sizes, int n_in,
                              void* d_out, int out_size, void* d_ws, size_t ws_size,
                              hipStream_t stream) {
    const float* x  = (const float*)d_in[0];
    const int*   ei = (const int*)d_in[1];
    const float* W1 = (const float*)d_in[2];
    const float* b1 = (const float*)d_in[3];
    const float* W2 = (const float*)d_in[4];
    const float* b2 = (const float*)d_in[5];
    const int* src = ei;
    const int* dst = ei + N_EDGES;

    // ---- workspace (sections aligned; u16 region starts 16B-aligned) ----
    float* dis          = (float*)d_ws;                      // 50000
    int*   row_ptr      = (int*)(dis + N_NODES);             // 50016
    int*   blk_cnt_src  = row_ptr + 50016;                   // 152896
    int*   blk_cnt_dst  = blk_cnt_src + 152896;              // 152896
    int*   tot_src      = blk_cnt_dst + 152896;              // 512
    int*   tot_dst      = tot_src + 512;                     // 512
    int*   base_src     = tot_dst + 512;                     // 512
    int*   base_dst     = base_src + 512;                    // 512
    int*   done         = base_dst + 512;                    // 16 (pad)
    int*   srconly      = done + 16;                         // E
    int2*  sorted_pair  = (int2*)(srconly + N_EDGES);        // E int2
    int2*  wpair        = sorted_pair + N_EDGES;             // E int2
    u16*   Z            = (u16*)(wpair + N_EDGES);           // [3 planes][N][64]
    u16*   S            = Z + (long)3 * N_NODES * HID;       // N*64
    u16*   hb           = S + (long)N_NODES * HID;           // N*64
    u16*   Zp           = hb + (long)N_NODES * HID;          // [3 planes][N][16]
    u16*   Sp           = Zp + (long)3 * N_NODES * D_OUT;    // N*16
    u16*   Pb1          = Sp + (long)N_NODES * D_OUT;        // 18432
    u16*   Pb2          = Pb1 + 18432;                       // 3072

    const long PZ  = (long)N_NODES * HID;    // layer-1 plane stride
    const long PZp = (long)N_NODES * D_OUT;  // layer-2 plane stride

    // ---- CSR build (no global data atomics) ----
    passA<<<NBLK_E, 256, 0, stream>>>(src, dst, blk_cnt_src, blk_cnt_dst, done);
    passB<<<2 * NBKT, 64, 0, stream>>>(blk_cnt_src, blk_cnt_dst, tot_src, tot_dst,
                                       base_src, base_dst, row_ptr, done);
    passC<<<NBLK_E, 256, 0, stream>>>(src, dst, blk_cnt_src, blk_cnt_dst, base_src, base_dst,
                                      srconly, sorted_pair);
    passDsrc<<<NBKT, 256, 0, stream>>>(base_src, srconly, dis);
    passDdst<<<NBKT, 256, 0, stream>>>(base_dst, sorted_pair, dis, row_ptr, wpair);

    // ---- weights ----
    packB_both<<<(3 * D_IN * HID + 3 * HID * D_OUT + 255) / 256, 256, 0, stream>>>(W1, W2, Pb1, Pb2);

    // ---- layer 1: Z = x @ W1 (planes Z0|Z1|Z2), S = Z1 + 2 L Z2, h = relu(Z0 - Z2 + L S + b1) ----
    const int GB = (N_NODES / 16 + 3) / 4;   // 782
    gemm_mfma<D_IN, 192, HID, 4, (long)N_NODES * HID, true><<<GB, 256, 0, stream>>>(x, Pb1, Z);
    gather_prop<HID, 32, 1024, EPI_S><<<(N_NODES + 31) / 32, 256, 0, stream>>>(
        row_ptr, wpair, Z + 2 * PZ, Z + PZ, nullptr, nullptr, S);
    gather_prop<HID, 32, 1024, EPI_H><<<(N_NODES + 31) / 32, 256, 0, stream>>>(
        row_ptr, wpair, S, Z, Z + 2 * PZ, b1, hb);

    // ---- layer 2: Zp = h @ W2 (planes), Sp = Z'1 + 2 L Z'2, out = Z'0 - Z'2 + L Sp + b2 ----
    gemm_mfma<HID, 48, D_OUT, 1, (long)N_NODES * D_OUT, false><<<GB, 256, 0, stream>>>(hb, Pb2, Zp);
    gather_prop<D_OUT, 128, 3072, EPI_S><<<(N_NODES + 127) / 128, 256, 0, stream>>>(
        row_ptr, wpair, Zp + 2 * PZp, Zp + PZp, nullptr, nullptr, Sp);
    gather_prop<D_OUT, 128, 3072, EPI_OUT><<<(N_NODES + 127) / 128, 256, 0, stream>>>(
        row_ptr, wpair, Sp, Zp, Zp + 2 * PZp, b2, (float*)d_out);
}

// Round 9
// 136.974 us; speedup vs baseline: 1.1457x; 1.1457x over previous
//
#include <hip/hip_runtime.h>

#define N_NODES 50000
#define N_EDGES 800000
#define D_IN 96
#define HID 64
#define D_OUT 16

#define EPB 2048                                   // edges per block (passes A/C)
#define NBLK_E ((N_EDGES + EPB - 1) / EPB)         // 391
#define BSHIFT 7                                   // 128 nodes per bucket
#define NBKT ((N_NODES + 127) / 128)               // 391
#define DCAP 2560                                  // Ddst LDS edge staging cap

typedef unsigned short u16;
typedef unsigned int u32;
typedef __attribute__((ext_vector_type(4))) float f32x4;
typedef __attribute__((ext_vector_type(8))) short bf16x8;

__device__ inline float bflo(u32 v) { union { u32 i; float f; } u; u.i = v << 16; return u.f; }
__device__ inline float bfhi(u32 v) { union { u32 i; float f; } u; u.i = v & 0xffff0000u; return u.f; }
__device__ inline u16 f2bf(float f) {              // RTNE
    union { float f; u32 i; } u; u.f = f;
    return (u16)((u.i + 0x7fffu + ((u.i >> 16) & 1u)) >> 16);
}
__device__ inline u32 pack2(float lo, float hi) {
    return (u32)f2bf(lo) | ((u32)f2bf(hi) << 16);
}

// ============ CSR build: two-level counting sort, zero global data atomics ============

__global__ __launch_bounds__(256)
void passA(const int* __restrict__ src, const int* __restrict__ dst,
           int* __restrict__ blk_cnt_src, int* __restrict__ blk_cnt_dst) {
    __shared__ int hs[NBKT], hd[NBKT];
    const int t = threadIdx.x, blk = blockIdx.x;
    for (int i = t; i < NBKT; i += 256) { hs[i] = 0; hd[i] = 0; }
    __syncthreads();
    const int e0 = blk * EPB;
    const int e1 = (e0 + EPB < N_EDGES) ? e0 + EPB : N_EDGES;
    for (int e = e0 + t; e < e1; e += 256) {
        atomicAdd(&hs[src[e] >> BSHIFT], 1);
        atomicAdd(&hd[dst[e] >> BSHIFT], 1);
    }
    __syncthreads();
    for (int b = t; b < NBKT; b += 256) {
        blk_cnt_src[b * NBLK_E + blk] = hs[b];
        blk_cnt_dst[b * NBLK_E + blk] = hd[b];
    }
}

// passB: per-bucket exclusive scan over the block dimension (in place), emit totals.
__global__ __launch_bounds__(64)
void passB(int* __restrict__ blk_cnt_src, int* __restrict__ blk_cnt_dst,
           int* __restrict__ tot_src, int* __restrict__ tot_dst) {
    const int b = blockIdx.x;
    int* cnt; int* tot;
    if (b < NBKT) { cnt = blk_cnt_dst + b * NBLK_E;          tot = tot_dst + b; }
    else          { cnt = blk_cnt_src + (b - NBKT) * NBLK_E; tot = tot_src + (b - NBKT); }
    const int lane = threadIdx.x;
    int carry = 0;
    for (int base0 = 0; base0 < NBLK_E; base0 += 64) {
        int i = base0 + lane;
        int v = (i < NBLK_E) ? cnt[i] : 0;
        int incl = v;
        #pragma unroll
        for (int off = 1; off < 64; off <<= 1) {
            int x = __shfl_up(incl, off);
            if (lane >= off) incl += x;
        }
        if (i < NBLK_E) cnt[i] = carry + incl - v;
        carry += __shfl(incl, 63);
    }
    if (lane == 0) *tot = carry;
}

// passB2: scan bucket totals -> bucket bases (dst and src); row_ptr[N]=E.
__global__ __launch_bounds__(256)
void passB2(const int* __restrict__ tot_src, const int* __restrict__ tot_dst,
            int* __restrict__ base_src, int* __restrict__ base_dst, int* __restrict__ row_ptr) {
    __shared__ int s[512];
    const int t = threadIdx.x;
    for (int pass = 0; pass < 2; ++pass) {
        const int* tot = pass ? tot_src : tot_dst;
        int* bas = pass ? base_src : base_dst;
        s[t]       = (t < NBKT) ? tot[t] : 0;
        s[t + 256] = (t + 256 < NBKT) ? tot[t + 256] : 0;
        __syncthreads();
        for (int off = 1; off < 512; off <<= 1) {
            int a1 = (t >= off) ? s[t - off] : 0;
            int a2 = (t + 256 >= off) ? s[t + 256 - off] : 0;
            __syncthreads();
            s[t] += a1; s[t + 256] += a2;
            __syncthreads();
        }
        if (t == 0) bas[0] = 0;
        if (t < NBKT) bas[t + 1] = s[t];
        if (t + 256 < NBKT) bas[t + 257] = s[t + 256];
        __syncthreads();
    }
    if (t == 0) row_ptr[N_NODES] = N_EDGES;
}

// Pass C: scatter edges into coarse-bucket-sorted arrays; dst side as int2 pairs.
__global__ __launch_bounds__(256)
void passC(const int* __restrict__ src, const int* __restrict__ dst,
           const int* __restrict__ blk_off_src, const int* __restrict__ blk_off_dst,
           const int* __restrict__ base_src, const int* __restrict__ base_dst,
           int* __restrict__ sorted_srconly, int2* __restrict__ sorted_pair) {
    __shared__ int cs[NBKT], cd[NBKT];
    const int t = threadIdx.x, blk = blockIdx.x;
    for (int b = t; b < NBKT; b += 256) {
        cs[b] = base_src[b] + blk_off_src[b * NBLK_E + blk];
        cd[b] = base_dst[b] + blk_off_dst[b * NBLK_E + blk];
    }
    __syncthreads();
    const int e0 = blk * EPB;
    const int e1 = (e0 + EPB < N_EDGES) ? e0 + EPB : N_EDGES;
    for (int e = e0 + t; e < e1; e += 256) {
        int sv = src[e], dv = dst[e];
        int ps = atomicAdd(&cs[sv >> BSHIFT], 1);
        sorted_srconly[ps] = sv;
        int pd = atomicAdd(&cd[dv >> BSHIFT], 1);
        sorted_pair[pd] = make_int2(dv, sv);
    }
}

__global__ __launch_bounds__(256)
void passDsrc(const int* __restrict__ base_src, const int* __restrict__ sorted_srconly,
              float* __restrict__ dis) {
    __shared__ int hist[128];
    const int b = blockIdx.x, t = threadIdx.x;
    if (t < 128) hist[t] = 0;
    __syncthreads();
    const int eb = base_src[b], ee = base_src[b + 1];
    for (int i = eb + t; i < ee; i += 256)
        atomicAdd(&hist[sorted_srconly[i] & 127], 1);
    __syncthreads();
    const int node = (b << BSHIFT) + t;
    if (t < 128 && node < N_NODES) {
        int c = hist[t];
        dis[node] = c > 0 ? rsqrtf((float)c) : 0.0f;
    }
}

// Pass Ddst: per-bucket fine CSR: row_ptr, node-grouped wpair = {src, -dis[s]*dis[d]}.
__global__ __launch_bounds__(256)
void passDdst(const int* __restrict__ base_dst, const int2* __restrict__ sorted_pair,
              const float* __restrict__ dis,
              int* __restrict__ row_ptr, int2* __restrict__ wpair) {
    __shared__ int s_d[DCAP];
    __shared__ int s_s[DCAP];
    __shared__ int hist[128];
    __shared__ int cur[128];
    __shared__ float s_dis[128];
    const int b = blockIdx.x, t = threadIdx.x;
    if (t < 128) {
        hist[t] = 0;
        int node = (b << BSHIFT) + t;
        s_dis[t] = (node < N_NODES) ? dis[node] : 0.0f;
    }
    __syncthreads();
    const int eb = base_dst[b], ee = base_dst[b + 1];
    const int cnt = ee - eb;
    const int stage = cnt < DCAP ? cnt : DCAP;
    for (int i = t; i < stage; i += 256) {
        int2 p = sorted_pair[eb + i];
        int d = p.x & 127;
        s_d[i] = d;
        s_s[i] = p.y;
        atomicAdd(&hist[d], 1);
    }
    for (int i = stage + t; i < cnt; i += 256)
        atomicAdd(&hist[sorted_pair[eb + i].x & 127], 1);
    __syncthreads();
    if (t < 64) {
        int v0 = hist[2 * t], v1 = hist[2 * t + 1];
        int p = v0 + v1;
        int incl = p;
        #pragma unroll
        for (int off = 1; off < 64; off <<= 1) {
            int x = __shfl_up(incl, off);
            if (t >= off) incl += x;
        }
        int excl = incl - p;
        cur[2 * t] = excl;
        cur[2 * t + 1] = excl + v0;
        int node = (b << BSHIFT) + 2 * t;
        if (node < N_NODES) row_ptr[node] = eb + excl;
        if (node + 1 < N_NODES) row_ptr[node + 1] = eb + excl + v0;
    }
    __syncthreads();
    for (int i = t; i < stage; i += 256) {
        int ln = s_d[i], sv = s_s[i];
        int slot = atomicAdd(&cur[ln], 1);
        wpair[eb + slot] = make_int2(sv, __float_as_int(-dis[sv] * s_dis[ln]));
    }
    for (int i = stage + t; i < cnt; i += 256) {
        int2 p = sorted_pair[eb + i];
        int ln = p.x & 127, sv = p.y;
        int slot = atomicAdd(&cur[ln], 1);
        wpair[eb + slot] = make_int2(sv, __float_as_int(-dis[sv] * s_dis[ln]));
    }
}

// ============ weight pack (both layers, MFMA B-fragment order) ============

__global__ void packB_both(const float* __restrict__ W1, const float* __restrict__ W2,
                           u16* __restrict__ Pb1, u16* __restrict__ Pb2) {
    int t = blockIdx.x * blockDim.x + threadIdx.x;
    if (t < 3 * D_IN * HID) {                    // 18432: K=96, NC=192, OUTW=64
        int j = t & 7, rest = t >> 3;
        int c = rest % 192, i = (rest / 192) * 8 + j;
        int kc = c / 64, o = c % 64;
        Pb1[t] = f2bf(W1[((long)kc * D_IN + i) * HID + o]);
    } else if (t < 3 * D_IN * HID + 3 * HID * D_OUT) {
        int t2 = t - 3 * D_IN * HID;             // 3072: K=64, NC=48, OUTW=16
        int j = t2 & 7, rest = t2 >> 3;
        int c = rest % 48, i = (rest / 48) * 8 + j;
        int kc = c / 16, o = c % 16;
        Pb2[t2] = f2bf(W2[((long)kc * HID + i) * D_OUT + o]);
    }
}

// ============ MFMA GEMM: Z = A[N,K] @ B[K,NC], plane-split output ============
// col c = ct*16+r16 stored at Z + (ct/CPK)*CBS + node*LDZ + (ct%CPK)*16 + r16

template<int K, int NC, int LDZ, int CPK, long CBS, bool AF32>
__global__ __launch_bounds__(256)
void gemm_mfma(const void* __restrict__ Av, const u16* __restrict__ P, u16* __restrict__ Z) {
    constexpr int KT = K / 32;
    constexpr int TOT = K * NC;
    __shared__ u16 sP[TOT];
    for (int idx = threadIdx.x * 8; idx < TOT; idx += 2048)
        *(uint4*)&sP[idx] = *(const uint4*)&P[idx];
    __syncthreads();
    const int lane = threadIdx.x & 63;
    const int tile = blockIdx.x * 4 + (threadIdx.x >> 6);
    if (tile * 16 >= N_NODES) return;
    const int node0 = tile * 16;
    const int sub = lane >> 4, r16 = lane & 15;
    bf16x8 a[KT];
    if (AF32) {
        const float* ar = (const float*)Av + (long)(node0 + r16) * K + sub * 8;
        #pragma unroll
        for (int kt = 0; kt < KT; ++kt) {
            float4 a0 = *(const float4*)(ar + kt * 32);
            float4 a1 = *(const float4*)(ar + kt * 32 + 4);
            union { bf16x8 v; uint4 q; } u;
            u.q.x = pack2(a0.x, a0.y); u.q.y = pack2(a0.z, a0.w);
            u.q.z = pack2(a1.x, a1.y); u.q.w = pack2(a1.z, a1.w);
            a[kt] = u.v;
        }
    } else {
        const u16* ar = (const u16*)Av + (long)(node0 + r16) * K + sub * 8;
        #pragma unroll
        for (int kt = 0; kt < KT; ++kt)
            a[kt] = *(const bf16x8*)(ar + kt * 32);
    }
    #pragma unroll
    for (int ct = 0; ct < NC / 16; ++ct) {
        f32x4 acc = {0.f, 0.f, 0.f, 0.f};
        #pragma unroll
        for (int kt = 0; kt < KT; ++kt) {
            bf16x8 bfr = *(const bf16x8*)&sP[((kt * 4 + sub) * NC + ct * 16 + r16) * 8];
            acc = __builtin_amdgcn_mfma_f32_16x16x32_bf16(a[kt], bfr, acc, 0, 0, 0);
        }
        u16* zp = Z + (long)(ct / CPK) * CBS + (long)(node0 + sub * 4) * LDZ + (ct % CPK) * 16 + r16;
        #pragma unroll
        for (int r = 0; r < 4; ++r)
            zp[(long)r * LDZ] = f2bf(acc[r]);
    }
}

// ============ gather propagate: LDS-staged int2 pairs, 8-way unroll, fused epilogues ====
// EPI_S  : S   = aux1 + 2*acc                      (bf16 out)
// EPI_H  : h   = relu(aux1 - aux2 + acc + bias)    (bf16 out)
// EPI_OUT: out = aux1 - aux2 + acc + bias          (f32 out)

#define EPI_S 0
#define EPI_H 1
#define EPI_OUT 2

__device__ inline void accum8(float (&acc)[8], float we, uint4 q) {
    acc[0] = fmaf(we, bflo(q.x), acc[0]);
    acc[1] = fmaf(we, bfhi(q.x), acc[1]);
    acc[2] = fmaf(we, bflo(q.y), acc[2]);
    acc[3] = fmaf(we, bfhi(q.y), acc[3]);
    acc[4] = fmaf(we, bflo(q.z), acc[4]);
    acc[5] = fmaf(we, bfhi(q.z), acc[5]);
    acc[6] = fmaf(we, bflo(q.w), acc[6]);
    acc[7] = fmaf(we, bfhi(q.w), acc[7]);
}

template<int F, int NPB, int CAP, int EPI>
__global__ __launch_bounds__(256)
void gather_prop(const int* __restrict__ row_ptr, const int2* __restrict__ wp,
                 const u16* __restrict__ g,       // gather source plane [N,F]
                 const u16* __restrict__ aux1,
                 const u16* __restrict__ aux2,
                 const float* __restrict__ bias,
                 void* __restrict__ outp) {
    __shared__ int2 s_p[CAP];
    __shared__ int s_beg[NPB + 1];
    const int tid = threadIdx.x;
    const int node0 = blockIdx.x * NPB;
    if (tid <= NPB) {
        int n = node0 + tid;
        s_beg[tid] = row_ptr[n > N_NODES ? N_NODES : n];
    }
    __syncthreads();
    const int ebeg = s_beg[0];
    const int cnt = s_beg[NPB] - ebeg;
    const int stage = cnt < CAP ? cnt : CAP;
    for (int e = tid; e < stage; e += 256)
        s_p[e] = wp[ebeg + e];
    __syncthreads();
    constexpr int CPN = F / 8;
    const int nl = tid / CPN;
    const int node = node0 + nl;
    if (nl >= NPB || node >= N_NODES) return;
    const int c8 = (tid % CPN) * 8;
    float acc[8];
    #pragma unroll
    for (int j = 0; j < 8; ++j) acc[j] = 0.0f;
    const int beg = s_beg[nl] - ebeg;
    const int end = s_beg[nl + 1] - ebeg;
    const int mid = end < stage ? end : stage;
    int e = beg;
    for (; e + 8 <= mid; e += 8) {                 // 8-way MLP from LDS pairs
        int2 p0 = s_p[e],     p1 = s_p[e + 1], p2 = s_p[e + 2], p3 = s_p[e + 3];
        int2 p4 = s_p[e + 4], p5 = s_p[e + 5], p6 = s_p[e + 6], p7 = s_p[e + 7];
        uint4 q0 = *(const uint4*)(g + (long)p0.x * F + c8);
        uint4 q1 = *(const uint4*)(g + (long)p1.x * F + c8);
        uint4 q2 = *(const uint4*)(g + (long)p2.x * F + c8);
        uint4 q3 = *(const uint4*)(g + (long)p3.x * F + c8);
        uint4 q4 = *(const uint4*)(g + (long)p4.x * F + c8);
        uint4 q5 = *(const uint4*)(g + (long)p5.x * F + c8);
        uint4 q6 = *(const uint4*)(g + (long)p6.x * F + c8);
        uint4 q7 = *(const uint4*)(g + (long)p7.x * F + c8);
        accum8(acc, __int_as_float(p0.y), q0); accum8(acc, __int_as_float(p1.y), q1);
        accum8(acc, __int_as_float(p2.y), q2); accum8(acc, __int_as_float(p3.y), q3);
        accum8(acc, __int_as_float(p4.y), q4); accum8(acc, __int_as_float(p5.y), q5);
        accum8(acc, __int_as_float(p6.y), q6); accum8(acc, __int_as_float(p7.y), q7);
    }
    for (; e + 4 <= mid; e += 4) {
        int2 p0 = s_p[e], p1 = s_p[e + 1], p2 = s_p[e + 2], p3 = s_p[e + 3];
        uint4 q0 = *(const uint4*)(g + (long)p0.x * F + c8);
        uint4 q1 = *(const uint4*)(g + (long)p1.x * F + c8);
        uint4 q2 = *(const uint4*)(g + (long)p2.x * F + c8);
        uint4 q3 = *(const uint4*)(g + (long)p3.x * F + c8);
        accum8(acc, __int_as_float(p0.y), q0); accum8(acc, __int_as_float(p1.y), q1);
        accum8(acc, __int_as_float(p2.y), q2); accum8(acc, __int_as_float(p3.y), q3);
    }
    for (; e < mid; ++e) {
        int2 p = s_p[e];
        uint4 q = *(const uint4*)(g + (long)p.x * F + c8);
        accum8(acc, __int_as_float(p.y), q);
    }
    for (e = (beg > stage ? beg : stage); e < end; ++e) {   // overflow fallback (rare)
        int2 p = wp[ebeg + e];
        uint4 q = *(const uint4*)(g + (long)p.x * F + c8);
        accum8(acc, __int_as_float(p.y), q);
    }
    if (EPI == EPI_S) {
        const uint4 z1 = *(const uint4*)(aux1 + (long)node * F + c8);
        uint4 r;
        r.x = pack2(bflo(z1.x) + 2.f * acc[0], bfhi(z1.x) + 2.f * acc[1]);
        r.y = pack2(bflo(z1.y) + 2.f * acc[2], bfhi(z1.y) + 2.f * acc[3]);
        r.z = pack2(bflo(z1.z) + 2.f * acc[4], bfhi(z1.z) + 2.f * acc[5]);
        r.w = pack2(bflo(z1.w) + 2.f * acc[6], bfhi(z1.w) + 2.f * acc[7]);
        *(uint4*)((u16*)outp + (long)node * F + c8) = r;
    } else {
        const uint4 z0 = *(const uint4*)(aux1 + (long)node * F + c8);
        const uint4 z2 = *(const uint4*)(aux2 + (long)node * F + c8);
        const float* bb = bias + c8;
        float v0 = bflo(z0.x) - bflo(z2.x) + acc[0] + bb[0];
        float v1 = bfhi(z0.x) - bfhi(z2.x) + acc[1] + bb[1];
        float v2 = bflo(z0.y) - bflo(z2.y) + acc[2] + bb[2];
        float v3 = bfhi(z0.y) - bfhi(z2.y) + acc[3] + bb[3];
        float v4 = bflo(z0.z) - bflo(z2.z) + acc[4] + bb[4];
        float v5 = bfhi(z0.z) - bfhi(z2.z) + acc[5] + bb[5];
        float v6 = bflo(z0.w) - bflo(z2.w) + acc[6] + bb[6];
        float v7 = bfhi(z0.w) - bfhi(z2.w) + acc[7] + bb[7];
        if (EPI == EPI_H) {
            uint4 r;
            r.x = pack2(fmaxf(v0, 0.f), fmaxf(v1, 0.f));
            r.y = pack2(fmaxf(v2, 0.f), fmaxf(v3, 0.f));
            r.z = pack2(fmaxf(v4, 0.f), fmaxf(v5, 0.f));
            r.w = pack2(fmaxf(v6, 0.f), fmaxf(v7, 0.f));
            *(uint4*)((u16*)outp + (long)node * F + c8) = r;
        } else {
            float* op = (float*)outp + (long)node * F + c8;
            *(float4*)op = make_float4(v0, v1, v2, v3);
            *(float4*)(op + 4) = make_float4(v4, v5, v6, v7);
        }
    }
}

// ============ launch ============

extern "C" void kernel_launch(void* const* d_in, const int* in_sizes, int n_in,
                              void* d_out, int out_size, void* d_ws, size_t ws_size,
                              hipStream_t stream) {
    const float* x  = (const float*)d_in[0];
    const int*   ei = (const int*)d_in[1];
    const float* W1 = (const float*)d_in[2];
    const float* b1 = (const float*)d_in[3];
    const float* W2 = (const float*)d_in[4];
    const float* b2 = (const float*)d_in[5];
    const int* src = ei;
    const int* dst = ei + N_EDGES;

    // ---- workspace (sections aligned; u16 region starts 16B-aligned) ----
    float* dis          = (float*)d_ws;                      // 50000
    int*   row_ptr      = (int*)(dis + N_NODES);             // 50016
    int*   blk_cnt_src  = row_ptr + 50016;                   // 152896
    int*   blk_cnt_dst  = blk_cnt_src + 152896;              // 152896
    int*   tot_src      = blk_cnt_dst + 152896;              // 512
    int*   tot_dst      = tot_src + 512;                     // 512
    int*   base_src     = tot_dst + 512;                     // 512
    int*   base_dst     = base_src + 512;                    // 512
    int*   srconly      = base_dst + 512;                    // E
    int2*  sorted_pair  = (int2*)(srconly + N_EDGES);        // E int2
    int2*  wpair        = sorted_pair + N_EDGES;             // E int2
    u16*   Z            = (u16*)(wpair + N_EDGES);           // [3 planes][N][64]
    u16*   S            = Z + (long)3 * N_NODES * HID;       // N*64
    u16*   hb           = S + (long)N_NODES * HID;           // N*64
    u16*   Zp           = hb + (long)N_NODES * HID;          // [3 planes][N][16]
    u16*   Sp           = Zp + (long)3 * N_NODES * D_OUT;    // N*16
    u16*   Pb1          = Sp + (long)N_NODES * D_OUT;        // 18432
    u16*   Pb2          = Pb1 + 18432;                       // 3072

    const long PZ  = (long)N_NODES * HID;    // layer-1 plane stride
    const long PZp = (long)N_NODES * D_OUT;  // layer-2 plane stride

    // ---- CSR build (no global data atomics) ----
    passA<<<NBLK_E, 256, 0, stream>>>(src, dst, blk_cnt_src, blk_cnt_dst);
    passB<<<2 * NBKT, 64, 0, stream>>>(blk_cnt_src, blk_cnt_dst, tot_src, tot_dst);
    passB2<<<1, 256, 0, stream>>>(tot_src, tot_dst, base_src, base_dst, row_ptr);
    passC<<<NBLK_E, 256, 0, stream>>>(src, dst, blk_cnt_src, blk_cnt_dst, base_src, base_dst,
                                      srconly, sorted_pair);
    passDsrc<<<NBKT, 256, 0, stream>>>(base_src, srconly, dis);
    passDdst<<<NBKT, 256, 0, stream>>>(base_dst, sorted_pair, dis, row_ptr, wpair);

    // ---- weights ----
    packB_both<<<(3 * D_IN * HID + 3 * HID * D_OUT + 255) / 256, 256, 0, stream>>>(W1, W2, Pb1, Pb2);

    // ---- layer 1: Z = x @ W1 (planes Z0|Z1|Z2), S = Z1 + 2 L Z2, h = relu(Z0 - Z2 + L S + b1) ----
    const int GB = (N_NODES / 16 + 3) / 4;   // 782
    gemm_mfma<D_IN, 192, HID, 4, (long)N_NODES * HID, true><<<GB, 256, 0, stream>>>(x, Pb1, Z);
    gather_prop<HID, 32, 1024, EPI_S><<<(N_NODES + 31) / 32, 256, 0, stream>>>(
        row_ptr, wpair, Z + 2 * PZ, Z + PZ, nullptr, nullptr, S);
    gather_prop<HID, 32, 1024, EPI_H><<<(N_NODES + 31) / 32, 256, 0, stream>>>(
        row_ptr, wpair, S, Z, Z + 2 * PZ, b1, hb);

    // ---- layer 2: Zp = h @ W2 (planes), Sp = Z'1 + 2 L Z'2, out = Z'0 - Z'2 + L Sp + b2 ----
    gemm_mfma<HID, 48, D_OUT, 1, (long)N_NODES * D_OUT, false><<<GB, 256, 0, stream>>>(hb, Pb2, Zp);
    gather_prop<D_OUT, 128, 3072, EPI_S><<<(N_NODES + 127) / 128, 256, 0, stream>>>(
        row_ptr, wpair, Zp + 2 * PZp, Zp + PZp, nullptr, nullptr, Sp);
    gather_prop<D_OUT, 128, 3072, EPI_OUT><<<(N_NODES + 127) / 128, 256, 0, stream>>>(
        row_ptr, wpair, Sp, Zp, Zp + 2 * PZp, b2, (float*)d_out);
}

// Round 10
// 129.509 us; speedup vs baseline: 1.2118x; 1.0576x over previous
//
#include <hip/hip_runtime.h>

#define N_NODES 50000
#define N_EDGES 800000
#define D_IN 96
#define HID 64
#define D_OUT 16

#define EPB 2048                                   // edges per block (passes A/C)
#define NBLK_E ((N_EDGES + EPB - 1) / EPB)         // 391
#define BSHIFT 7                                   // 128 nodes per bucket
#define NBKT ((N_NODES + 127) / 128)               // 391
#define DCAP 2560                                  // Ddst LDS edge staging cap
#define PACK_TOT (3 * D_IN * HID + 3 * HID * D_OUT)   // 21504
#define PACK_BLKS (PACK_TOT / 256)                 // 84

typedef unsigned short u16;
typedef unsigned int u32;
typedef __attribute__((ext_vector_type(4))) float f32x4;
typedef __attribute__((ext_vector_type(8))) short bf16x8;

__device__ inline float bflo(u32 v) { union { u32 i; float f; } u; u.i = v << 16; return u.f; }
__device__ inline float bfhi(u32 v) { union { u32 i; float f; } u; u.i = v & 0xffff0000u; return u.f; }
__device__ inline u16 f2bf(float f) {              // RTNE
    union { float f; u32 i; } u; u.f = f;
    return (u16)((u.i + 0x7fffu + ((u.i >> 16) & 1u)) >> 16);
}
__device__ inline u32 pack2(float lo, float hi) {
    return (u32)f2bf(lo) | ((u32)f2bf(hi) << 16);
}

// ============ passA: coarse histograms (+ fused weight pack in extra blocks) ============

__global__ __launch_bounds__(256)
void passA(const int* __restrict__ src, const int* __restrict__ dst,
           int* __restrict__ blk_cnt_src, int* __restrict__ blk_cnt_dst,
           const float* __restrict__ W1, const float* __restrict__ W2,
           u16* __restrict__ Pb1, u16* __restrict__ Pb2) {
    const int t = threadIdx.x, blk = blockIdx.x;
    if (blk >= NBLK_E) {                           // weight-pack blocks
        int tt = (blk - NBLK_E) * 256 + t;
        if (tt < 3 * D_IN * HID) {                 // 18432: K=96, NC=192, OUTW=64
            int j = tt & 7, rest = tt >> 3;
            int c = rest % 192, i = (rest / 192) * 8 + j;
            int kc = c / 64, o = c % 64;
            Pb1[tt] = f2bf(W1[((long)kc * D_IN + i) * HID + o]);
        } else if (tt < PACK_TOT) {
            int t2 = tt - 3 * D_IN * HID;          // 3072: K=64, NC=48, OUTW=16
            int j = t2 & 7, rest = t2 >> 3;
            int c = rest % 48, i = (rest / 48) * 8 + j;
            int kc = c / 16, o = c % 16;
            Pb2[t2] = f2bf(W2[((long)kc * HID + i) * D_OUT + o]);
        }
        return;
    }
    __shared__ int hs[NBKT], hd[NBKT];
    for (int i = t; i < NBKT; i += 256) { hs[i] = 0; hd[i] = 0; }
    __syncthreads();
    const int e0 = blk * EPB;
    const int e1 = (e0 + EPB < N_EDGES) ? e0 + EPB : N_EDGES;
    for (int e = e0 + t; e < e1; e += 256) {
        atomicAdd(&hs[src[e] >> BSHIFT], 1);
        atomicAdd(&hd[dst[e] >> BSHIFT], 1);
    }
    __syncthreads();
    for (int b = t; b < NBKT; b += 256) {
        blk_cnt_src[b * NBLK_E + blk] = hs[b];
        blk_cnt_dst[b * NBLK_E + blk] = hd[b];
    }
}

// passB: per-bucket exclusive scan over the block dimension (in place), emit totals.
__global__ __launch_bounds__(64)
void passB(int* __restrict__ blk_cnt_src, int* __restrict__ blk_cnt_dst,
           int* __restrict__ tot_src, int* __restrict__ tot_dst) {
    const int b = blockIdx.x;
    int* cnt; int* tot;
    if (b < NBKT) { cnt = blk_cnt_dst + b * NBLK_E;          tot = tot_dst + b; }
    else          { cnt = blk_cnt_src + (b - NBKT) * NBLK_E; tot = tot_src + (b - NBKT); }
    const int lane = threadIdx.x;
    int carry = 0;
    for (int base0 = 0; base0 < NBLK_E; base0 += 64) {
        int i = base0 + lane;
        int v = (i < NBLK_E) ? cnt[i] : 0;
        int incl = v;
        #pragma unroll
        for (int off = 1; off < 64; off <<= 1) {
            int x = __shfl_up(incl, off);
            if (lane >= off) incl += x;
        }
        if (i < NBLK_E) cnt[i] = carry + incl - v;
        carry += __shfl(incl, 63);
    }
    if (lane == 0) *tot = carry;
}

// passB2: scan bucket totals -> bucket bases (dst and src); row_ptr[N]=E.
__global__ __launch_bounds__(256)
void passB2(const int* __restrict__ tot_src, const int* __restrict__ tot_dst,
            int* __restrict__ base_src, int* __restrict__ base_dst, int* __restrict__ row_ptr) {
    __shared__ int s[512];
    const int t = threadIdx.x;
    for (int pass = 0; pass < 2; ++pass) {
        const int* tot = pass ? tot_src : tot_dst;
        int* bas = pass ? base_src : base_dst;
        s[t]       = (t < NBKT) ? tot[t] : 0;
        s[t + 256] = (t + 256 < NBKT) ? tot[t + 256] : 0;
        __syncthreads();
        for (int off = 1; off < 512; off <<= 1) {
            int a1 = (t >= off) ? s[t - off] : 0;
            int a2 = (t + 256 >= off) ? s[t + 256 - off] : 0;
            __syncthreads();
            s[t] += a1; s[t + 256] += a2;
            __syncthreads();
        }
        if (t == 0) bas[0] = 0;
        if (t < NBKT) bas[t + 1] = s[t];
        if (t + 256 < NBKT) bas[t + 257] = s[t + 256];
        __syncthreads();
    }
    if (t == 0) row_ptr[N_NODES] = N_EDGES;
}

// passC: scatter edges into coarse-bucket-sorted arrays; u16 src, packed u32 (dst<<16)|src.
__global__ __launch_bounds__(256)
void passC(const int* __restrict__ src, const int* __restrict__ dst,
           const int* __restrict__ blk_off_src, const int* __restrict__ blk_off_dst,
           const int* __restrict__ base_src, const int* __restrict__ base_dst,
           u16* __restrict__ sorted_srconly, u32* __restrict__ sorted_pair) {
    __shared__ int cs[NBKT], cd[NBKT];
    const int t = threadIdx.x, blk = blockIdx.x;
    for (int b = t; b < NBKT; b += 256) {
        cs[b] = base_src[b] + blk_off_src[b * NBLK_E + blk];
        cd[b] = base_dst[b] + blk_off_dst[b * NBLK_E + blk];
    }
    __syncthreads();
    const int e0 = blk * EPB;
    const int e1 = (e0 + EPB < N_EDGES) ? e0 + EPB : N_EDGES;
    for (int e = e0 + t; e < e1; e += 256) {
        int sv = src[e], dv = dst[e];
        int ps = atomicAdd(&cs[sv >> BSHIFT], 1);
        sorted_srconly[ps] = (u16)sv;
        int pd = atomicAdd(&cd[dv >> BSHIFT], 1);
        sorted_pair[pd] = ((u32)dv << 16) | (u32)sv;
    }
}

__global__ __launch_bounds__(256)
void passDsrc(const int* __restrict__ base_src, const u16* __restrict__ sorted_srconly,
              float* __restrict__ dis) {
    __shared__ int hist[128];
    const int b = blockIdx.x, t = threadIdx.x;
    if (t < 128) hist[t] = 0;
    __syncthreads();
    const int eb = base_src[b], ee = base_src[b + 1];
    for (int i = eb + t; i < ee; i += 256)
        atomicAdd(&hist[sorted_srconly[i] & 127], 1);
    __syncthreads();
    const int node = (b << BSHIFT) + t;
    if (t < 128 && node < N_NODES) {
        int c = hist[t];
        dis[node] = c > 0 ? rsqrtf((float)c) : 0.0f;
    }
}

// passDdst: per-bucket fine CSR: row_ptr, node-grouped wpair = (bf16(-dis_s*dis_d)<<16)|src.
__global__ __launch_bounds__(256)
void passDdst(const int* __restrict__ base_dst, const u32* __restrict__ sorted_pair,
              const float* __restrict__ dis,
              int* __restrict__ row_ptr, u32* __restrict__ wpair) {
    __shared__ u32 s_p[DCAP];
    __shared__ int hist[128];
    __shared__ int cur[128];
    __shared__ float s_dis[128];
    const int b = blockIdx.x, t = threadIdx.x;
    if (t < 128) {
        hist[t] = 0;
        int node = (b << BSHIFT) + t;
        s_dis[t] = (node < N_NODES) ? dis[node] : 0.0f;
    }
    __syncthreads();
    const int eb = base_dst[b], ee = base_dst[b + 1];
    const int cnt = ee - eb;
    const int stage = cnt < DCAP ? cnt : DCAP;
    for (int i = t; i < stage; i += 256) {
        u32 v = sorted_pair[eb + i];
        s_p[i] = v;
        atomicAdd(&hist[(v >> 16) & 127], 1);
    }
    for (int i = stage + t; i < cnt; i += 256)
        atomicAdd(&hist[(sorted_pair[eb + i] >> 16) & 127], 1);
    __syncthreads();
    if (t < 64) {
        int v0 = hist[2 * t], v1 = hist[2 * t + 1];
        int p = v0 + v1;
        int incl = p;
        #pragma unroll
        for (int off = 1; off < 64; off <<= 1) {
            int x = __shfl_up(incl, off);
            if (t >= off) incl += x;
        }
        int excl = incl - p;
        cur[2 * t] = excl;
        cur[2 * t + 1] = excl + v0;
        int node = (b << BSHIFT) + 2 * t;
        if (node < N_NODES) row_ptr[node] = eb + excl;
        if (node + 1 < N_NODES) row_ptr[node + 1] = eb + excl + v0;
    }
    __syncthreads();
    for (int i = t; i < stage; i += 256) {
        u32 v = s_p[i];
        int ln = (v >> 16) & 127, sv = v & 0xFFFF;
        int slot = atomicAdd(&cur[ln], 1);
        float w = -dis[sv] * s_dis[ln];
        wpair[eb + slot] = ((u32)f2bf(w) << 16) | (u32)sv;
    }
    for (int i = stage + t; i < cnt; i += 256) {
        u32 v = sorted_pair[eb + i];
        int ln = (v >> 16) & 127, sv = v & 0xFFFF;
        int slot = atomicAdd(&cur[ln], 1);
        float w = -dis[sv] * s_dis[ln];
        wpair[eb + slot] = ((u32)f2bf(w) << 16) | (u32)sv;
    }
}

// ============ MFMA GEMM: Z = A[N,K] @ B[K,NC], plane-split output ============
// col c = ct*16+r16 stored at Z + (ct/CPK)*CBS + node*LDZ + (ct%CPK)*16 + r16

template<int K, int NC, int LDZ, int CPK, long CBS, bool AF32>
__global__ __launch_bounds__(256)
void gemm_mfma(const void* __restrict__ Av, const u16* __restrict__ P, u16* __restrict__ Z) {
    constexpr int KT = K / 32;
    constexpr int TOT = K * NC;
    __shared__ u16 sP[TOT];
    for (int idx = threadIdx.x * 8; idx < TOT; idx += 2048)
        *(uint4*)&sP[idx] = *(const uint4*)&P[idx];
    __syncthreads();
    const int lane = threadIdx.x & 63;
    const int tile = blockIdx.x * 4 + (threadIdx.x >> 6);
    if (tile * 16 >= N_NODES) return;
    const int node0 = tile * 16;
    const int sub = lane >> 4, r16 = lane & 15;
    bf16x8 a[KT];
    if (AF32) {
        const float* ar = (const float*)Av + (long)(node0 + r16) * K + sub * 8;
        #pragma unroll
        for (int kt = 0; kt < KT; ++kt) {
            float4 a0 = *(const float4*)(ar + kt * 32);
            float4 a1 = *(const float4*)(ar + kt * 32 + 4);
            union { bf16x8 v; uint4 q; } u;
            u.q.x = pack2(a0.x, a0.y); u.q.y = pack2(a0.z, a0.w);
            u.q.z = pack2(a1.x, a1.y); u.q.w = pack2(a1.z, a1.w);
            a[kt] = u.v;
        }
    } else {
        const u16* ar = (const u16*)Av + (long)(node0 + r16) * K + sub * 8;
        #pragma unroll
        for (int kt = 0; kt < KT; ++kt)
            a[kt] = *(const bf16x8*)(ar + kt * 32);
    }
    #pragma unroll
    for (int ct = 0; ct < NC / 16; ++ct) {
        f32x4 acc = {0.f, 0.f, 0.f, 0.f};
        #pragma unroll
        for (int kt = 0; kt < KT; ++kt) {
            bf16x8 bfr = *(const bf16x8*)&sP[((kt * 4 + sub) * NC + ct * 16 + r16) * 8];
            acc = __builtin_amdgcn_mfma_f32_16x16x32_bf16(a[kt], bfr, acc, 0, 0, 0);
        }
        u16* zp = Z + (long)(ct / CPK) * CBS + (long)(node0 + sub * 4) * LDZ + (ct % CPK) * 16 + r16;
        #pragma unroll
        for (int r = 0; r < 4; ++r)
            zp[(long)r * LDZ] = f2bf(acc[r]);
    }
}

// ============ gather propagate: LDS-staged packed u32 edges, 8-way unroll ============
// edge record: (bf16 weight << 16) | src_u16 ; weight = bfhi(rec), src = rec & 0xFFFF
// EPI_S  : S   = aux1 + 2*acc                      (bf16 out)
// EPI_H  : h   = relu(aux1 - aux2 + acc + bias)    (bf16 out)
// EPI_OUT: out = aux1 - aux2 + acc + bias          (f32 out)

#define EPI_S 0
#define EPI_H 1
#define EPI_OUT 2

__device__ inline void accum8(float (&acc)[8], float we, uint4 q) {
    acc[0] = fmaf(we, bflo(q.x), acc[0]);
    acc[1] = fmaf(we, bfhi(q.x), acc[1]);
    acc[2] = fmaf(we, bflo(q.y), acc[2]);
    acc[3] = fmaf(we, bfhi(q.y), acc[3]);
    acc[4] = fmaf(we, bflo(q.z), acc[4]);
    acc[5] = fmaf(we, bfhi(q.z), acc[5]);
    acc[6] = fmaf(we, bflo(q.w), acc[6]);
    acc[7] = fmaf(we, bfhi(q.w), acc[7]);
}

template<int F, int NPB, int CAP, int EPI>
__global__ __launch_bounds__(256)
void gather_prop(const int* __restrict__ row_ptr, const u32* __restrict__ wp,
                 const u16* __restrict__ g,       // gather source plane [N,F]
                 const u16* __restrict__ aux1,
                 const u16* __restrict__ aux2,
                 const float* __restrict__ bias,
                 void* __restrict__ outp) {
    __shared__ u32 s_p[CAP];
    __shared__ int s_beg[NPB + 1];
    const int tid = threadIdx.x;
    const int node0 = blockIdx.x * NPB;
    if (tid <= NPB) {
        int n = node0 + tid;
        s_beg[tid] = row_ptr[n > N_NODES ? N_NODES : n];
    }
    __syncthreads();
    const int ebeg = s_beg[0];
    const int cnt = s_beg[NPB] - ebeg;
    const int stage = cnt < CAP ? cnt : CAP;
    for (int e = tid; e < stage; e += 256)
        s_p[e] = wp[ebeg + e];
    __syncthreads();
    constexpr int CPN = F / 8;
    const int nl = tid / CPN;
    const int node = node0 + nl;
    if (nl >= NPB || node >= N_NODES) return;
    const int c8 = (tid % CPN) * 8;
    float acc[8];
    #pragma unroll
    for (int j = 0; j < 8; ++j) acc[j] = 0.0f;
    const int beg = s_beg[nl] - ebeg;
    const int end = s_beg[nl + 1] - ebeg;
    const int mid = end < stage ? end : stage;
    int e = beg;
    for (; e + 8 <= mid; e += 8) {                 // 8-way MLP from LDS records
        u32 p0 = s_p[e],     p1 = s_p[e + 1], p2 = s_p[e + 2], p3 = s_p[e + 3];
        u32 p4 = s_p[e + 4], p5 = s_p[e + 5], p6 = s_p[e + 6], p7 = s_p[e + 7];
        uint4 q0 = *(const uint4*)(g + (long)(p0 & 0xFFFF) * F + c8);
        uint4 q1 = *(const uint4*)(g + (long)(p1 & 0xFFFF) * F + c8);
        uint4 q2 = *(const uint4*)(g + (long)(p2 & 0xFFFF) * F + c8);
        uint4 q3 = *(const uint4*)(g + (long)(p3 & 0xFFFF) * F + c8);
        uint4 q4 = *(const uint4*)(g + (long)(p4 & 0xFFFF) * F + c8);
        uint4 q5 = *(const uint4*)(g + (long)(p5 & 0xFFFF) * F + c8);
        uint4 q6 = *(const uint4*)(g + (long)(p6 & 0xFFFF) * F + c8);
        uint4 q7 = *(const uint4*)(g + (long)(p7 & 0xFFFF) * F + c8);
        accum8(acc, bfhi(p0), q0); accum8(acc, bfhi(p1), q1);
        accum8(acc, bfhi(p2), q2); accum8(acc, bfhi(p3), q3);
        accum8(acc, bfhi(p4), q4); accum8(acc, bfhi(p5), q5);
        accum8(acc, bfhi(p6), q6); accum8(acc, bfhi(p7), q7);
    }
    for (; e + 4 <= mid; e += 4) {
        u32 p0 = s_p[e], p1 = s_p[e + 1], p2 = s_p[e + 2], p3 = s_p[e + 3];
        uint4 q0 = *(const uint4*)(g + (long)(p0 & 0xFFFF) * F + c8);
        uint4 q1 = *(const uint4*)(g + (long)(p1 & 0xFFFF) * F + c8);
        uint4 q2 = *(const uint4*)(g + (long)(p2 & 0xFFFF) * F + c8);
        uint4 q3 = *(const uint4*)(g + (long)(p3 & 0xFFFF) * F + c8);
        accum8(acc, bfhi(p0), q0); accum8(acc, bfhi(p1), q1);
        accum8(acc, bfhi(p2), q2); accum8(acc, bfhi(p3), q3);
    }
    for (; e < mid; ++e) {
        u32 p = s_p[e];
        uint4 q = *(const uint4*)(g + (long)(p & 0xFFFF) * F + c8);
        accum8(acc, bfhi(p), q);
    }
    for (e = (beg > stage ? beg : stage); e < end; ++e) {   // overflow fallback (rare)
        u32 p = wp[ebeg + e];
        uint4 q = *(const uint4*)(g + (long)(p & 0xFFFF) * F + c8);
        accum8(acc, bfhi(p), q);
    }
    if (EPI == EPI_S) {
        const uint4 z1 = *(const uint4*)(aux1 + (long)node * F + c8);
        uint4 r;
        r.x = pack2(bflo(z1.x) + 2.f * acc[0], bfhi(z1.x) + 2.f * acc[1]);
        r.y = pack2(bflo(z1.y) + 2.f * acc[2], bfhi(z1.y) + 2.f * acc[3]);
        r.z = pack2(bflo(z1.z) + 2.f * acc[4], bfhi(z1.z) + 2.f * acc[5]);
        r.w = pack2(bflo(z1.w) + 2.f * acc[6], bfhi(z1.w) + 2.f * acc[7]);
        *(uint4*)((u16*)outp + (long)node * F + c8) = r;
    } else {
        const uint4 z0 = *(const uint4*)(aux1 + (long)node * F + c8);
        const uint4 z2 = *(const uint4*)(aux2 + (long)node * F + c8);
        const float* bb = bias + c8;
        float v0 = bflo(z0.x) - bflo(z2.x) + acc[0] + bb[0];
        float v1 = bfhi(z0.x) - bfhi(z2.x) + acc[1] + bb[1];
        float v2 = bflo(z0.y) - bflo(z2.y) + acc[2] + bb[2];
        float v3 = bfhi(z0.y) - bfhi(z2.y) + acc[3] + bb[3];
        float v4 = bflo(z0.z) - bflo(z2.z) + acc[4] + bb[4];
        float v5 = bfhi(z0.z) - bfhi(z2.z) + acc[5] + bb[5];
        float v6 = bflo(z0.w) - bflo(z2.w) + acc[6] + bb[6];
        float v7 = bfhi(z0.w) - bfhi(z2.w) + acc[7] + bb[7];
        if (EPI == EPI_H) {
            uint4 r;
            r.x = pack2(fmaxf(v0, 0.f), fmaxf(v1, 0.f));
            r.y = pack2(fmaxf(v2, 0.f), fmaxf(v3, 0.f));
            r.z = pack2(fmaxf(v4, 0.f), fmaxf(v5, 0.f));
            r.w = pack2(fmaxf(v6, 0.f), fmaxf(v7, 0.f));
            *(uint4*)((u16*)outp + (long)node * F + c8) = r;
        } else {
            float* op = (float*)outp + (long)node * F + c8;
            *(float4*)op = make_float4(v0, v1, v2, v3);
            *(float4*)(op + 4) = make_float4(v4, v5, v6, v7);
        }
    }
}

// ============ launch ============

extern "C" void kernel_launch(void* const* d_in, const int* in_sizes, int n_in,
                              void* d_out, int out_size, void* d_ws, size_t ws_size,
                              hipStream_t stream) {
    const float* x  = (const float*)d_in[0];
    const int*   ei = (const int*)d_in[1];
    const float* W1 = (const float*)d_in[2];
    const float* b1 = (const float*)d_in[3];
    const float* W2 = (const float*)d_in[4];
    const float* b2 = (const float*)d_in[5];
    const int* src = ei;
    const int* dst = ei + N_EDGES;

    // ---- workspace (sections aligned; u16 region starts 16B-aligned) ----
    float* dis          = (float*)d_ws;                      // 50000
    int*   row_ptr      = (int*)(dis + N_NODES);             // 50016
    int*   blk_cnt_src  = row_ptr + 50016;                   // 152896
    int*   blk_cnt_dst  = blk_cnt_src + 152896;              // 152896
    int*   tot_src      = blk_cnt_dst + 152896;              // 512
    int*   tot_dst      = tot_src + 512;                     // 512
    int*   base_src     = tot_dst + 512;                     // 512
    int*   base_dst     = base_src + 512;                    // 512
    u16*   srconly      = (u16*)(base_dst + 512);            // E u16
    u32*   sorted_pair  = (u32*)(srconly + N_EDGES);         // E u32
    u32*   wpair        = sorted_pair + N_EDGES;             // E u32
    u16*   Z            = (u16*)(wpair + N_EDGES);           // [3 planes][N][64]
    u16*   S            = Z + (long)3 * N_NODES * HID;       // N*64
    u16*   hb           = S + (long)N_NODES * HID;           // N*64
    u16*   Zp           = hb + (long)N_NODES * HID;          // [3 planes][N][16]
    u16*   Sp           = Zp + (long)3 * N_NODES * D_OUT;    // N*16
    u16*   Pb1          = Sp + (long)N_NODES * D_OUT;        // 18432
    u16*   Pb2          = Pb1 + 18432;                       // 3072

    const long PZ  = (long)N_NODES * HID;    // layer-1 plane stride
    const long PZp = (long)N_NODES * D_OUT;  // layer-2 plane stride

    // ---- CSR build (no global data atomics); passA also packs weights ----
    passA<<<NBLK_E + PACK_BLKS, 256, 0, stream>>>(src, dst, blk_cnt_src, blk_cnt_dst,
                                                  W1, W2, Pb1, Pb2);
    passB<<<2 * NBKT, 64, 0, stream>>>(blk_cnt_src, blk_cnt_dst, tot_src, tot_dst);
    passB2<<<1, 256, 0, stream>>>(tot_src, tot_dst, base_src, base_dst, row_ptr);
    passC<<<NBLK_E, 256, 0, stream>>>(src, dst, blk_cnt_src, blk_cnt_dst, base_src, base_dst,
                                      srconly, sorted_pair);
    passDsrc<<<NBKT, 256, 0, stream>>>(base_src, srconly, dis);
    passDdst<<<NBKT, 256, 0, stream>>>(base_dst, sorted_pair, dis, row_ptr, wpair);

    // ---- layer 1: Z = x @ W1 (planes Z0|Z1|Z2), S = Z1 + 2 L Z2, h = relu(Z0 - Z2 + L S + b1) ----
    const int GB = (N_NODES / 16 + 3) / 4;   // 782
    gemm_mfma<D_IN, 192, HID, 4, (long)N_NODES * HID, true><<<GB, 256, 0, stream>>>(x, Pb1, Z);
    gather_prop<HID, 32, 1024, EPI_S><<<(N_NODES + 31) / 32, 256, 0, stream>>>(
        row_ptr, wpair, Z + 2 * PZ, Z + PZ, nullptr, nullptr, S);
    gather_prop<HID, 32, 1024, EPI_H><<<(N_NODES + 31) / 32, 256, 0, stream>>>(
        row_ptr, wpair, S, Z, Z + 2 * PZ, b1, hb);

    // ---- layer 2: Zp = h @ W2 (planes), Sp = Z'1 + 2 L Z'2, out = Z'0 - Z'2 + L Sp + b2 ----
    gemm_mfma<HID, 48, D_OUT, 1, (long)N_NODES * D_OUT, false><<<GB, 256, 0, stream>>>(hb, Pb2, Zp);
    gather_prop<D_OUT, 128, 3072, EPI_S><<<(N_NODES + 127) / 128, 256, 0, stream>>>(
        row_ptr, wpair, Zp + 2 * PZp, Zp + PZp, nullptr, nullptr, Sp);
    gather_prop<D_OUT, 128, 3072, EPI_OUT><<<(N_NODES + 127) / 128, 256, 0, stream>>>(
        row_ptr, wpair, Sp, Zp, Zp + 2 * PZp, b2, (float*)d_out);
}

// Round 11
// 122.839 us; speedup vs baseline: 1.2776x; 1.0543x over previous
//
#include <hip/hip_runtime.h>

#define N_NODES 50000
#define N_EDGES 800000
#define D_IN 96
#define HID 64
#define D_OUT 16

#define EPB 2048                                   // edges per block (passes A/C)
#define NBLK_E ((N_EDGES + EPB - 1) / EPB)         // 391
#define BSHIFT 7                                   // 128 nodes per bucket
#define NBKT ((N_NODES + 127) / 128)               // 391
#define DCAP 2560                                  // Ddst LDS edge staging cap
#define PACK_TOT (3 * D_IN * HID + 3 * HID * D_OUT)   // 21504
#define PACK_BLKS (PACK_TOT / 256)                 // 84

typedef unsigned short u16;
typedef unsigned int u32;
typedef __attribute__((ext_vector_type(4))) float f32x4;
typedef __attribute__((ext_vector_type(8))) short bf16x8;

__device__ inline float bflo(u32 v) { union { u32 i; float f; } u; u.i = v << 16; return u.f; }
__device__ inline float bfhi(u32 v) { union { u32 i; float f; } u; u.i = v & 0xffff0000u; return u.f; }
__device__ inline u16 f2bf(float f) {              // RTNE
    union { float f; u32 i; } u; u.f = f;
    return (u16)((u.i + 0x7fffu + ((u.i >> 16) & 1u)) >> 16);
}
__device__ inline u32 pack2(float lo, float hi) {
    return (u32)f2bf(lo) | ((u32)f2bf(hi) << 16);
}

// ============ passA: coarse histograms (+ fused weight pack in extra blocks) ============

__global__ __launch_bounds__(256)
void passA(const int* __restrict__ src, const int* __restrict__ dst,
           int* __restrict__ blk_cnt_src, int* __restrict__ blk_cnt_dst,
           const float* __restrict__ W1, const float* __restrict__ W2,
           u16* __restrict__ Pb1, u16* __restrict__ Pb2) {
    const int t = threadIdx.x, blk = blockIdx.x;
    if (blk >= NBLK_E) {                           // weight-pack blocks
        int tt = (blk - NBLK_E) * 256 + t;
        if (tt < 3 * D_IN * HID) {                 // 18432: K=96, NC=192, OUTW=64
            int j = tt & 7, rest = tt >> 3;
            int c = rest % 192, i = (rest / 192) * 8 + j;
            int kc = c / 64, o = c % 64;
            Pb1[tt] = f2bf(W1[((long)kc * D_IN + i) * HID + o]);
        } else if (tt < PACK_TOT) {
            int t2 = tt - 3 * D_IN * HID;          // 3072: K=64, NC=48, OUTW=16
            int j = t2 & 7, rest = t2 >> 3;
            int c = rest % 48, i = (rest / 48) * 8 + j;
            int kc = c / 16, o = c % 16;
            Pb2[t2] = f2bf(W2[((long)kc * HID + i) * D_OUT + o]);
        }
        return;
    }
    __shared__ int hs[NBKT], hd[NBKT];
    for (int i = t; i < NBKT; i += 256) { hs[i] = 0; hd[i] = 0; }
    __syncthreads();
    const int e0 = blk * EPB;
    const int e1 = (e0 + EPB < N_EDGES) ? e0 + EPB : N_EDGES;
    for (int e = e0 + t; e < e1; e += 256) {
        atomicAdd(&hs[src[e] >> BSHIFT], 1);
        atomicAdd(&hd[dst[e] >> BSHIFT], 1);
    }
    __syncthreads();
    for (int b = t; b < NBKT; b += 256) {
        blk_cnt_src[b * NBLK_E + blk] = hs[b];
        blk_cnt_dst[b * NBLK_E + blk] = hd[b];
    }
}

// passB: per-bucket exclusive scan over the block dimension (in place), emit totals.
__global__ __launch_bounds__(64)
void passB(int* __restrict__ blk_cnt_src, int* __restrict__ blk_cnt_dst,
           int* __restrict__ tot_src, int* __restrict__ tot_dst) {
    const int b = blockIdx.x;
    int* cnt; int* tot;
    if (b < NBKT) { cnt = blk_cnt_dst + b * NBLK_E;          tot = tot_dst + b; }
    else          { cnt = blk_cnt_src + (b - NBKT) * NBLK_E; tot = tot_src + (b - NBKT); }
    const int lane = threadIdx.x;
    int carry = 0;
    for (int base0 = 0; base0 < NBLK_E; base0 += 64) {
        int i = base0 + lane;
        int v = (i < NBLK_E) ? cnt[i] : 0;
        int incl = v;
        #pragma unroll
        for (int off = 1; off < 64; off <<= 1) {
            int x = __shfl_up(incl, off);
            if (lane >= off) incl += x;
        }
        if (i < NBLK_E) cnt[i] = carry + incl - v;
        carry += __shfl(incl, 63);
    }
    if (lane == 0) *tot = carry;
}

// passB2: scan bucket totals -> bucket bases (dst and src); row_ptr[N]=E.
__global__ __launch_bounds__(256)
void passB2(const int* __restrict__ tot_src, const int* __restrict__ tot_dst,
            int* __restrict__ base_src, int* __restrict__ base_dst, int* __restrict__ row_ptr) {
    __shared__ int s[512];
    const int t = threadIdx.x;
    for (int pass = 0; pass < 2; ++pass) {
        const int* tot = pass ? tot_src : tot_dst;
        int* bas = pass ? base_src : base_dst;
        s[t]       = (t < NBKT) ? tot[t] : 0;
        s[t + 256] = (t + 256 < NBKT) ? tot[t + 256] : 0;
        __syncthreads();
        for (int off = 1; off < 512; off <<= 1) {
            int a1 = (t >= off) ? s[t - off] : 0;
            int a2 = (t + 256 >= off) ? s[t + 256 - off] : 0;
            __syncthreads();
            s[t] += a1; s[t + 256] += a2;
            __syncthreads();
        }
        if (t == 0) bas[0] = 0;
        if (t < NBKT) bas[t + 1] = s[t];
        if (t + 256 < NBKT) bas[t + 257] = s[t + 256];
        __syncthreads();
    }
    if (t == 0) row_ptr[N_NODES] = N_EDGES;
}

// passC: scatter edges into coarse-bucket-sorted arrays; u16 src, packed u32 (dst<<16)|src.
__global__ __launch_bounds__(256)
void passC(const int* __restrict__ src, const int* __restrict__ dst,
           const int* __restrict__ blk_off_src, const int* __restrict__ blk_off_dst,
           const int* __restrict__ base_src, const int* __restrict__ base_dst,
           u16* __restrict__ sorted_srconly, u32* __restrict__ sorted_pair) {
    __shared__ int cs[NBKT], cd[NBKT];
    const int t = threadIdx.x, blk = blockIdx.x;
    for (int b = t; b < NBKT; b += 256) {
        cs[b] = base_src[b] + blk_off_src[b * NBLK_E + blk];
        cd[b] = base_dst[b] + blk_off_dst[b * NBLK_E + blk];
    }
    __syncthreads();
    const int e0 = blk * EPB;
    const int e1 = (e0 + EPB < N_EDGES) ? e0 + EPB : N_EDGES;
    for (int e = e0 + t; e < e1; e += 256) {
        int sv = src[e], dv = dst[e];
        int ps = atomicAdd(&cs[sv >> BSHIFT], 1);
        sorted_srconly[ps] = (u16)sv;
        int pd = atomicAdd(&cd[dv >> BSHIFT], 1);
        sorted_pair[pd] = ((u32)dv << 16) | (u32)sv;
    }
}

// passD: merged Dsrc (deg->dis) + Ddst (fine CSR, u16 src stream; NO weights).
__global__ __launch_bounds__(256)
void passD(const int* __restrict__ base_src, const u16* __restrict__ sorted_srconly,
           const int* __restrict__ base_dst, const u32* __restrict__ sorted_pair,
           float* __restrict__ dis, int* __restrict__ row_ptr, u16* __restrict__ wsrc) {
    const int t = threadIdx.x;
    if (blockIdx.x < NBKT) {                       // ---- Dsrc half ----
        __shared__ int hist[128];
        const int b = blockIdx.x;
        if (t < 128) hist[t] = 0;
        __syncthreads();
        const int eb = base_src[b], ee = base_src[b + 1];
        for (int i = eb + t; i < ee; i += 256)
            atomicAdd(&hist[sorted_srconly[i] & 127], 1);
        __syncthreads();
        const int node = (b << BSHIFT) + t;
        if (t < 128 && node < N_NODES) {
            int c = hist[t];
            dis[node] = c > 0 ? rsqrtf((float)c) : 0.0f;
        }
        return;
    }
    // ---- Ddst half ----
    __shared__ u32 s_p[DCAP];
    __shared__ int hist[128];
    __shared__ int cur[128];
    const int b = blockIdx.x - NBKT;
    if (t < 128) hist[t] = 0;
    __syncthreads();
    const int eb = base_dst[b], ee = base_dst[b + 1];
    const int cnt = ee - eb;
    const int stage = cnt < DCAP ? cnt : DCAP;
    for (int i = t; i < stage; i += 256) {
        u32 v = sorted_pair[eb + i];
        s_p[i] = v;
        atomicAdd(&hist[(v >> 16) & 127], 1);
    }
    for (int i = stage + t; i < cnt; i += 256)
        atomicAdd(&hist[(sorted_pair[eb + i] >> 16) & 127], 1);
    __syncthreads();
    if (t < 64) {
        int v0 = hist[2 * t], v1 = hist[2 * t + 1];
        int p = v0 + v1;
        int incl = p;
        #pragma unroll
        for (int off = 1; off < 64; off <<= 1) {
            int x = __shfl_up(incl, off);
            if (t >= off) incl += x;
        }
        int excl = incl - p;
        cur[2 * t] = excl;
        cur[2 * t + 1] = excl + v0;
        int node = (b << BSHIFT) + 2 * t;
        if (node < N_NODES) row_ptr[node] = eb + excl;
        if (node + 1 < N_NODES) row_ptr[node + 1] = eb + excl + v0;
    }
    __syncthreads();
    for (int i = t; i < stage; i += 256) {
        u32 v = s_p[i];
        int slot = atomicAdd(&cur[(v >> 16) & 127], 1);
        wsrc[eb + slot] = (u16)(v & 0xFFFF);
    }
    for (int i = stage + t; i < cnt; i += 256) {
        u32 v = sorted_pair[eb + i];
        int slot = atomicAdd(&cur[(v >> 16) & 127], 1);
        wsrc[eb + slot] = (u16)(v & 0xFFFF);
    }
}

// ============ MFMA GEMM: Z = A[N,K] @ B[K,NC], plane-split; plane 2 also written
// ============ dis-scaled into Zs (gather source for the first propagate) ============

template<int K, int NC, int LDZ, int CPK, long CBS, bool AF32>
__global__ __launch_bounds__(256)
void gemm_mfma(const void* __restrict__ Av, const u16* __restrict__ P, u16* __restrict__ Z,
               const float* __restrict__ dis, u16* __restrict__ Zs) {
    constexpr int KT = K / 32;
    constexpr int TOT = K * NC;
    __shared__ u16 sP[TOT];
    for (int idx = threadIdx.x * 8; idx < TOT; idx += 2048)
        *(uint4*)&sP[idx] = *(const uint4*)&P[idx];
    __syncthreads();
    const int lane = threadIdx.x & 63;
    const int tile = blockIdx.x * 4 + (threadIdx.x >> 6);
    if (tile * 16 >= N_NODES) return;
    const int node0 = tile * 16;
    const int sub = lane >> 4, r16 = lane & 15;
    float dis4[4];
    #pragma unroll
    for (int r = 0; r < 4; ++r) dis4[r] = dis[node0 + sub * 4 + r];
    bf16x8 a[KT];
    if (AF32) {
        const float* ar = (const float*)Av + (long)(node0 + r16) * K + sub * 8;
        #pragma unroll
        for (int kt = 0; kt < KT; ++kt) {
            float4 a0 = *(const float4*)(ar + kt * 32);
            float4 a1 = *(const float4*)(ar + kt * 32 + 4);
            union { bf16x8 v; uint4 q; } u;
            u.q.x = pack2(a0.x, a0.y); u.q.y = pack2(a0.z, a0.w);
            u.q.z = pack2(a1.x, a1.y); u.q.w = pack2(a1.z, a1.w);
            a[kt] = u.v;
        }
    } else {
        const u16* ar = (const u16*)Av + (long)(node0 + r16) * K + sub * 8;
        #pragma unroll
        for (int kt = 0; kt < KT; ++kt)
            a[kt] = *(const bf16x8*)(ar + kt * 32);
    }
    #pragma unroll
    for (int ct = 0; ct < NC / 16; ++ct) {
        f32x4 acc = {0.f, 0.f, 0.f, 0.f};
        #pragma unroll
        for (int kt = 0; kt < KT; ++kt) {
            bf16x8 bfr = *(const bf16x8*)&sP[((kt * 4 + sub) * NC + ct * 16 + r16) * 8];
            acc = __builtin_amdgcn_mfma_f32_16x16x32_bf16(a[kt], bfr, acc, 0, 0, 0);
        }
        const long rowoff = (long)(node0 + sub * 4) * LDZ + (ct % CPK) * 16 + r16;
        u16* zp = Z + (long)(ct / CPK) * CBS + rowoff;
        #pragma unroll
        for (int r = 0; r < 4; ++r)
            zp[(long)r * LDZ] = f2bf(acc[r]);
        if (ct / CPK == 2) {                       // scaled copy of plane 2
            u16* zs = Zs + rowoff;
            #pragma unroll
            for (int r = 0; r < 4; ++r)
                zs[(long)r * LDZ] = f2bf(acc[r] * dis4[r]);
        }
    }
}

// ============ gather propagate: u16 src records (pre-scaled sources), fused epilogues ===
// acc_d = sum_e g[src_e] ;  (L v)_d = -dis_d * acc_d
// EPI_S  : Ŝ  = dis_d*aux1 - 2*dis_d^2*acc          (bf16 out; pre-scaled for next hop)
// EPI_H  : h  = relu(aux1 - aux2 - dis_d*acc + bias) (bf16 out)
// EPI_OUT: out = aux1 - aux2 - dis_d*acc + bias      (f32 out)

#define EPI_S 0
#define EPI_H 1
#define EPI_OUT 2

__device__ inline void sum8(float (&acc)[8], uint4 q) {
    acc[0] += bflo(q.x); acc[1] += bfhi(q.x);
    acc[2] += bflo(q.y); acc[3] += bfhi(q.y);
    acc[4] += bflo(q.z); acc[5] += bfhi(q.z);
    acc[6] += bflo(q.w); acc[7] += bfhi(q.w);
}

template<int F, int NPB, int CAP, int EPI>
__global__ __launch_bounds__(256)
void gather_prop(const int* __restrict__ row_ptr, const u16* __restrict__ ws,
                 const u16* __restrict__ g,       // PRE-SCALED gather plane [N,F]
                 const u16* __restrict__ aux1,
                 const u16* __restrict__ aux2,
                 const float* __restrict__ bias,
                 const float* __restrict__ dis,
                 void* __restrict__ outp) {
    __shared__ u16 s_p[CAP];
    __shared__ int s_beg[NPB + 1];
    const int tid = threadIdx.x;
    const int node0 = blockIdx.x * NPB;
    if (tid <= NPB) {
        int n = node0 + tid;
        s_beg[tid] = row_ptr[n > N_NODES ? N_NODES : n];
    }
    __syncthreads();
    const int ebeg = s_beg[0];
    const int cnt = s_beg[NPB] - ebeg;
    const int stage = cnt < CAP ? cnt : CAP;
    for (int e = tid; e < stage; e += 256)
        s_p[e] = ws[ebeg + e];
    __syncthreads();
    constexpr int CPN = F / 8;
    const int nl = tid / CPN;
    const int node = node0 + nl;
    if (nl >= NPB || node >= N_NODES) return;
    const int c8 = (tid % CPN) * 8;
    float acc[8];
    #pragma unroll
    for (int j = 0; j < 8; ++j) acc[j] = 0.0f;
    const int beg = s_beg[nl] - ebeg;
    const int end = s_beg[nl + 1] - ebeg;
    const int mid = end < stage ? end : stage;
    int e = beg;
    for (; e + 8 <= mid; e += 8) {                 // 8-way MLP from LDS records
        int p0 = s_p[e],     p1 = s_p[e + 1], p2 = s_p[e + 2], p3 = s_p[e + 3];
        int p4 = s_p[e + 4], p5 = s_p[e + 5], p6 = s_p[e + 6], p7 = s_p[e + 7];
        uint4 q0 = *(const uint4*)(g + (long)p0 * F + c8);
        uint4 q1 = *(const uint4*)(g + (long)p1 * F + c8);
        uint4 q2 = *(const uint4*)(g + (long)p2 * F + c8);
        uint4 q3 = *(const uint4*)(g + (long)p3 * F + c8);
        uint4 q4 = *(const uint4*)(g + (long)p4 * F + c8);
        uint4 q5 = *(const uint4*)(g + (long)p5 * F + c8);
        uint4 q6 = *(const uint4*)(g + (long)p6 * F + c8);
        uint4 q7 = *(const uint4*)(g + (long)p7 * F + c8);
        sum8(acc, q0); sum8(acc, q1); sum8(acc, q2); sum8(acc, q3);
        sum8(acc, q4); sum8(acc, q5); sum8(acc, q6); sum8(acc, q7);
    }
    for (; e + 4 <= mid; e += 4) {
        int p0 = s_p[e], p1 = s_p[e + 1], p2 = s_p[e + 2], p3 = s_p[e + 3];
        uint4 q0 = *(const uint4*)(g + (long)p0 * F + c8);
        uint4 q1 = *(const uint4*)(g + (long)p1 * F + c8);
        uint4 q2 = *(const uint4*)(g + (long)p2 * F + c8);
        uint4 q3 = *(const uint4*)(g + (long)p3 * F + c8);
        sum8(acc, q0); sum8(acc, q1); sum8(acc, q2); sum8(acc, q3);
    }
    for (; e < mid; ++e)
        sum8(acc, *(const uint4*)(g + (long)s_p[e] * F + c8));
    for (e = (beg > stage ? beg : stage); e < end; ++e)     // overflow fallback (rare)
        sum8(acc, *(const uint4*)(g + (long)ws[ebeg + e] * F + c8));
    const float dd = dis[node];
    if (EPI == EPI_S) {
        const float m1 = dd, m2 = -2.0f * dd * dd;
        const uint4 z1 = *(const uint4*)(aux1 + (long)node * F + c8);
        uint4 r;
        r.x = pack2(fmaf(m1, bflo(z1.x), m2 * acc[0]), fmaf(m1, bfhi(z1.x), m2 * acc[1]));
        r.y = pack2(fmaf(m1, bflo(z1.y), m2 * acc[2]), fmaf(m1, bfhi(z1.y), m2 * acc[3]));
        r.z = pack2(fmaf(m1, bflo(z1.z), m2 * acc[4]), fmaf(m1, bfhi(z1.z), m2 * acc[5]));
        r.w = pack2(fmaf(m1, bflo(z1.w), m2 * acc[6]), fmaf(m1, bfhi(z1.w), m2 * acc[7]));
        *(uint4*)((u16*)outp + (long)node * F + c8) = r;
    } else {
        const uint4 z0 = *(const uint4*)(aux1 + (long)node * F + c8);
        const uint4 z2 = *(const uint4*)(aux2 + (long)node * F + c8);
        const float* bb = bias + c8;
        float v0 = bflo(z0.x) - bflo(z2.x) - dd * acc[0] + bb[0];
        float v1 = bfhi(z0.x) - bfhi(z2.x) - dd * acc[1] + bb[1];
        float v2 = bflo(z0.y) - bflo(z2.y) - dd * acc[2] + bb[2];
        float v3 = bfhi(z0.y) - bfhi(z2.y) - dd * acc[3] + bb[3];
        float v4 = bflo(z0.z) - bflo(z2.z) - dd * acc[4] + bb[4];
        float v5 = bfhi(z0.z) - bfhi(z2.z) - dd * acc[5] + bb[5];
        float v6 = bflo(z0.w) - bflo(z2.w) - dd * acc[6] + bb[6];
        float v7 = bfhi(z0.w) - bfhi(z2.w) - dd * acc[7] + bb[7];
        if (EPI == EPI_H) {
            uint4 r;
            r.x = pack2(fmaxf(v0, 0.f), fmaxf(v1, 0.f));
            r.y = pack2(fmaxf(v2, 0.f), fmaxf(v3, 0.f));
            r.z = pack2(fmaxf(v4, 0.f), fmaxf(v5, 0.f));
            r.w = pack2(fmaxf(v6, 0.f), fmaxf(v7, 0.f));
            *(uint4*)((u16*)outp + (long)node * F + c8) = r;
        } else {
            float* op = (float*)outp + (long)node * F + c8;
            *(float4*)op = make_float4(v0, v1, v2, v3);
            *(float4*)(op + 4) = make_float4(v4, v5, v6, v7);
        }
    }
}

// ============ launch ============

extern "C" void kernel_launch(void* const* d_in, const int* in_sizes, int n_in,
                              void* d_out, int out_size, void* d_ws, size_t ws_size,
                              hipStream_t stream) {
    const float* x  = (const float*)d_in[0];
    const int*   ei = (const int*)d_in[1];
    const float* W1 = (const float*)d_in[2];
    const float* b1 = (const float*)d_in[3];
    const float* W2 = (const float*)d_in[4];
    const float* b2 = (const float*)d_in[5];
    const int* src = ei;
    const int* dst = ei + N_EDGES;

    // ---- workspace (sections aligned; u16 region starts 16B-aligned) ----
    float* dis          = (float*)d_ws;                      // 50000
    int*   row_ptr      = (int*)(dis + N_NODES);             // 50016
    int*   blk_cnt_src  = row_ptr + 50016;                   // 152896
    int*   blk_cnt_dst  = blk_cnt_src + 152896;              // 152896
    int*   tot_src      = blk_cnt_dst + 152896;              // 512
    int*   tot_dst      = tot_src + 512;                     // 512
    int*   base_src     = tot_dst + 512;                     // 512
    int*   base_dst     = base_src + 512;                    // 512
    u16*   srconly      = (u16*)(base_dst + 512);            // E u16
    u32*   sorted_pair  = (u32*)(srconly + N_EDGES);         // E u32
    u16*   wsrc         = (u16*)(sorted_pair + N_EDGES);     // E u16
    u16*   Z            = wsrc + N_EDGES;                    // [3 planes][N][64]
    u16*   Zs           = Z  + (long)3 * N_NODES * HID;      // N*64  (dis ⊙ Z2)
    u16*   S            = Zs + (long)N_NODES * HID;          // N*64  (Ŝ, pre-scaled)
    u16*   hb           = S  + (long)N_NODES * HID;          // N*64
    u16*   Zp           = hb + (long)N_NODES * HID;          // [3 planes][N][16]
    u16*   Zsp          = Zp + (long)3 * N_NODES * D_OUT;    // N*16  (dis ⊙ Z'2)
    u16*   Sp           = Zsp + (long)N_NODES * D_OUT;       // N*16  (Ŝ')
    u16*   Pb1          = Sp + (long)N_NODES * D_OUT;        // 18432
    u16*   Pb2          = Pb1 + 18432;                       // 3072

    const long PZ  = (long)N_NODES * HID;    // layer-1 plane stride
    const long PZp = (long)N_NODES * D_OUT;  // layer-2 plane stride

    // ---- CSR build (no global data atomics); passA also packs weights ----
    passA<<<NBLK_E + PACK_BLKS, 256, 0, stream>>>(src, dst, blk_cnt_src, blk_cnt_dst,
                                                  W1, W2, Pb1, Pb2);
    passB<<<2 * NBKT, 64, 0, stream>>>(blk_cnt_src, blk_cnt_dst, tot_src, tot_dst);
    passB2<<<1, 256, 0, stream>>>(tot_src, tot_dst, base_src, base_dst, row_ptr);
    passC<<<NBLK_E, 256, 0, stream>>>(src, dst, blk_cnt_src, blk_cnt_dst, base_src, base_dst,
                                      srconly, sorted_pair);
    passD<<<2 * NBKT, 256, 0, stream>>>(base_src, srconly, base_dst, sorted_pair,
                                        dis, row_ptr, wsrc);

    // ---- layer 1: Z = x @ W1 (+ Zs = dis⊙Z2), Ŝ = dis⊙(Z1 + 2 L Z2), h = relu(...) ----
    const int GB = (N_NODES / 16 + 3) / 4;   // 782
    gemm_mfma<D_IN, 192, HID, 4, (long)N_NODES * HID, true><<<GB, 256, 0, stream>>>(
        x, Pb1, Z, dis, Zs);
    gather_prop<HID, 32, 1024, EPI_S><<<(N_NODES + 31) / 32, 256, 0, stream>>>(
        row_ptr, wsrc, Zs, Z + PZ, nullptr, nullptr, dis, S);
    gather_prop<HID, 32, 1024, EPI_H><<<(N_NODES + 31) / 32, 256, 0, stream>>>(
        row_ptr, wsrc, S, Z, Z + 2 * PZ, b1, dis, hb);

    // ---- layer 2: Zp = h @ W2 (+ Zsp), Ŝ' , out = Z'0 - Z'2 + L Ŝ' + b2 ----
    gemm_mfma<HID, 48, D_OUT, 1, (long)N_NODES * D_OUT, false><<<GB, 256, 0, stream>>>(
        hb, Pb2, Zp, dis, Zsp);
    gather_prop<D_OUT, 128, 3072, EPI_S><<<(N_NODES + 127) / 128, 256, 0, stream>>>(
        row_ptr, wsrc, Zsp, Zp + PZp, nullptr, nullptr, dis, Sp);
    gather_prop<D_OUT, 128, 3072, EPI_OUT><<<(N_NODES + 127) / 128, 256, 0, stream>>>(
        row_ptr, wsrc, Sp, Zp, Zp + 2 * PZp, b2, dis, (float*)d_out);
}

// Round 12
// 120.948 us; speedup vs baseline: 1.2975x; 1.0156x over previous
//
#include <hip/hip_runtime.h>

#define N_NODES 50000
#define N_EDGES 800000
#define D_IN 96
#define HID 64
#define D_OUT 16

#define EPB 2048                                   // edges per block (passes A/C)
#define NBLK_E ((N_EDGES + EPB - 1) / EPB)         // 391
#define BSHIFT 7                                   // 128 nodes per bucket
#define NBKT ((N_NODES + 127) / 128)               // 391
#define DCAP 2560                                  // Ddst LDS edge staging cap
#define PACK_TOT (3 * D_IN * HID + 3 * HID * D_OUT)   // 21504
#define PACK_BLKS (PACK_TOT / 256)                 // 84

typedef unsigned short u16;
typedef unsigned int u32;
typedef __attribute__((ext_vector_type(4))) float f32x4;
typedef __attribute__((ext_vector_type(8))) short bf16x8;

__device__ inline float bflo(u32 v) { union { u32 i; float f; } u; u.i = v << 16; return u.f; }
__device__ inline float bfhi(u32 v) { union { u32 i; float f; } u; u.i = v & 0xffff0000u; return u.f; }
__device__ inline u16 f2bf(float f) {              // RTNE
    union { float f; u32 i; } u; u.f = f;
    return (u16)((u.i + 0x7fffu + ((u.i >> 16) & 1u)) >> 16);
}
__device__ inline u32 pack2(float lo, float hi) {
    return (u32)f2bf(lo) | ((u32)f2bf(hi) << 16);
}

// ============ passA: coarse histograms (+ fused weight pack in extra blocks) ============

__global__ __launch_bounds__(256)
void passA(const int* __restrict__ src, const int* __restrict__ dst,
           int* __restrict__ blk_cnt_src, int* __restrict__ blk_cnt_dst,
           const float* __restrict__ W1, const float* __restrict__ W2,
           u16* __restrict__ Pb1, u16* __restrict__ Pb2) {
    const int t = threadIdx.x, blk = blockIdx.x;
    if (blk >= NBLK_E) {                           // weight-pack blocks
        int tt = (blk - NBLK_E) * 256 + t;
        if (tt < 3 * D_IN * HID) {                 // 18432: K=96, NC=192, OUTW=64
            int j = tt & 7, rest = tt >> 3;
            int c = rest % 192, i = (rest / 192) * 8 + j;
            int kc = c / 64, o = c % 64;
            Pb1[tt] = f2bf(W1[((long)kc * D_IN + i) * HID + o]);
        } else if (tt < PACK_TOT) {
            int t2 = tt - 3 * D_IN * HID;          // 3072: K=64, NC=48, OUTW=16
            int j = t2 & 7, rest = t2 >> 3;
            int c = rest % 48, i = (rest / 48) * 8 + j;
            int kc = c / 16, o = c % 16;
            Pb2[t2] = f2bf(W2[((long)kc * HID + i) * D_OUT + o]);
        }
        return;
    }
    __shared__ int hs[NBKT], hd[NBKT];
    for (int i = t; i < NBKT; i += 256) { hs[i] = 0; hd[i] = 0; }
    __syncthreads();
    const int e0 = blk * EPB;
    const int e1 = (e0 + EPB < N_EDGES) ? e0 + EPB : N_EDGES;
    for (int e = e0 + t; e < e1; e += 256) {
        atomicAdd(&hs[src[e] >> BSHIFT], 1);
        atomicAdd(&hd[dst[e] >> BSHIFT], 1);
    }
    __syncthreads();
    for (int b = t; b < NBKT; b += 256) {
        blk_cnt_src[b * NBLK_E + blk] = hs[b];
        blk_cnt_dst[b * NBLK_E + blk] = hd[b];
    }
}

// passB: per-bucket exclusive scan over the block dimension (in place), emit totals.
__global__ __launch_bounds__(64)
void passB(int* __restrict__ blk_cnt_src, int* __restrict__ blk_cnt_dst,
           int* __restrict__ tot_src, int* __restrict__ tot_dst) {
    const int b = blockIdx.x;
    int* cnt; int* tot;
    if (b < NBKT) { cnt = blk_cnt_dst + b * NBLK_E;          tot = tot_dst + b; }
    else          { cnt = blk_cnt_src + (b - NBKT) * NBLK_E; tot = tot_src + (b - NBKT); }
    const int lane = threadIdx.x;
    int carry = 0;
    for (int base0 = 0; base0 < NBLK_E; base0 += 64) {
        int i = base0 + lane;
        int v = (i < NBLK_E) ? cnt[i] : 0;
        int incl = v;
        #pragma unroll
        for (int off = 1; off < 64; off <<= 1) {
            int x = __shfl_up(incl, off);
            if (lane >= off) incl += x;
        }
        if (i < NBLK_E) cnt[i] = carry + incl - v;
        carry += __shfl(incl, 63);
    }
    if (lane == 0) *tot = carry;
}

// passC: scatter into coarse-bucket-sorted arrays; bucket bases computed via local scan.
__global__ __launch_bounds__(256)
void passC(const int* __restrict__ src, const int* __restrict__ dst,
           const int* __restrict__ blk_off_src, const int* __restrict__ blk_off_dst,
           const int* __restrict__ tot_src, const int* __restrict__ tot_dst,
           u16* __restrict__ sorted_srconly, u32* __restrict__ sorted_pair) {
    __shared__ int s[512];
    __shared__ int cs[NBKT], cd[NBKT];
    const int t = threadIdx.x, blk = blockIdx.x;
    for (int pass = 0; pass < 2; ++pass) {
        const int* tot = pass ? tot_src : tot_dst;
        const int* bo  = pass ? blk_off_src : blk_off_dst;
        int* cx = pass ? cs : cd;
        s[t]       = (t < NBKT) ? tot[t] : 0;
        s[t + 256] = (t + 256 < NBKT) ? tot[t + 256] : 0;
        __syncthreads();
        for (int off = 1; off < 512; off <<= 1) {
            int a1 = (t >= off) ? s[t - off] : 0;
            int a2 = (t + 256 >= off) ? s[t + 256 - off] : 0;
            __syncthreads();
            s[t] += a1; s[t + 256] += a2;
            __syncthreads();
        }
        if (t < NBKT) cx[t] = s[t] - tot[t] + bo[t * NBLK_E + blk];
        if (t + 256 < NBKT) cx[t + 256] = s[t + 256] - tot[t + 256] + bo[(t + 256) * NBLK_E + blk];
        __syncthreads();
    }
    const int e0 = blk * EPB;
    const int e1 = (e0 + EPB < N_EDGES) ? e0 + EPB : N_EDGES;
    for (int e = e0 + t; e < e1; e += 256) {
        int sv = src[e], dv = dst[e];
        int ps = atomicAdd(&cs[sv >> BSHIFT], 1);
        sorted_srconly[ps] = (u16)sv;
        int pd = atomicAdd(&cd[dv >> BSHIFT], 1);
        sorted_pair[pd] = ((u32)dv << 16) | (u32)sv;
    }
}

// passD: merged Dsrc (deg->dis) + Ddst (fine CSR); bucket base via local masked reduce.
__global__ __launch_bounds__(256)
void passD(const int* __restrict__ tot_src, const u16* __restrict__ sorted_srconly,
           const int* __restrict__ tot_dst, const u32* __restrict__ sorted_pair,
           float* __restrict__ dis, int* __restrict__ row_ptr, u16* __restrict__ wsrc) {
    __shared__ int sred[256];
    __shared__ int hist[128];
    __shared__ int cur[128];
    __shared__ u32 s_p[DCAP];
    const int t = threadIdx.x;
    const bool isSrc = blockIdx.x < NBKT;
    const int b = isSrc ? blockIdx.x : blockIdx.x - NBKT;
    const int* tot = isSrc ? tot_src : tot_dst;
    int part = 0;
    for (int i = t; i < b; i += 256) part += tot[i];
    sred[t] = part;
    if (t < 128) hist[t] = 0;
    __syncthreads();
    #pragma unroll
    for (int off = 128; off > 0; off >>= 1) {
        if (t < off) sred[t] += sred[t + off];
        __syncthreads();
    }
    const int eb = sred[0];
    const int ee = eb + tot[b];
    if (isSrc) {                                   // ---- Dsrc half ----
        for (int i = eb + t; i < ee; i += 256)
            atomicAdd(&hist[sorted_srconly[i] & 127], 1);
        __syncthreads();
        const int node = (b << BSHIFT) + t;
        if (t < 128 && node < N_NODES) {
            int c = hist[t];
            dis[node] = c > 0 ? rsqrtf((float)c) : 0.0f;
        }
        return;
    }
    // ---- Ddst half ----
    if (b == 0 && t == 0) row_ptr[N_NODES] = N_EDGES;
    const int cnt = ee - eb;
    const int stage = cnt < DCAP ? cnt : DCAP;
    for (int i = t; i < stage; i += 256) {
        u32 v = sorted_pair[eb + i];
        s_p[i] = v;
        atomicAdd(&hist[(v >> 16) & 127], 1);
    }
    for (int i = stage + t; i < cnt; i += 256)
        atomicAdd(&hist[(sorted_pair[eb + i] >> 16) & 127], 1);
    __syncthreads();
    if (t < 64) {
        int v0 = hist[2 * t], v1 = hist[2 * t + 1];
        int p = v0 + v1;
        int incl = p;
        #pragma unroll
        for (int off = 1; off < 64; off <<= 1) {
            int x = __shfl_up(incl, off);
            if (t >= off) incl += x;
        }
        int excl = incl - p;
        cur[2 * t] = excl;
        cur[2 * t + 1] = excl + v0;
        int node = (b << BSHIFT) + 2 * t;
        if (node < N_NODES) row_ptr[node] = eb + excl;
        if (node + 1 < N_NODES) row_ptr[node + 1] = eb + excl + v0;
    }
    __syncthreads();
    for (int i = t; i < stage; i += 256) {
        u32 v = s_p[i];
        int slot = atomicAdd(&cur[(v >> 16) & 127], 1);
        wsrc[eb + slot] = (u16)(v & 0xFFFF);
    }
    for (int i = stage + t; i < cnt; i += 256) {
        u32 v = sorted_pair[eb + i];
        int slot = atomicAdd(&cur[(v >> 16) & 127], 1);
        wsrc[eb + slot] = (u16)(v & 0xFFFF);
    }
}

// ============ MFMA GEMM: difference-plane output ============
// Emits: D02 = Z0 - Z2 ; Z1 ; Zs = dis ⊙ Z2   (each [N][LDZ] bf16)

template<int K, int NC, int LDZ, int CPK, bool AF32>
__global__ __launch_bounds__(256)
void gemm_mfma(const void* __restrict__ Av, const u16* __restrict__ P,
               u16* __restrict__ D02, u16* __restrict__ Z1, u16* __restrict__ Zs,
               const float* __restrict__ dis) {
    constexpr int KT = K / 32;
    constexpr int TOT = K * NC;
    __shared__ u16 sP[TOT];
    for (int idx = threadIdx.x * 8; idx < TOT; idx += 2048)
        *(uint4*)&sP[idx] = *(const uint4*)&P[idx];
    __syncthreads();
    const int lane = threadIdx.x & 63;
    const int tile = blockIdx.x * 4 + (threadIdx.x >> 6);
    if (tile * 16 >= N_NODES) return;
    const int node0 = tile * 16;
    const int sub = lane >> 4, r16 = lane & 15;
    float dis4[4];
    #pragma unroll
    for (int r = 0; r < 4; ++r) dis4[r] = dis[node0 + sub * 4 + r];
    bf16x8 a[KT];
    if (AF32) {
        const float* ar = (const float*)Av + (long)(node0 + r16) * K + sub * 8;
        #pragma unroll
        for (int kt = 0; kt < KT; ++kt) {
            float4 a0 = *(const float4*)(ar + kt * 32);
            float4 a1 = *(const float4*)(ar + kt * 32 + 4);
            union { bf16x8 v; uint4 q; } u;
            u.q.x = pack2(a0.x, a0.y); u.q.y = pack2(a0.z, a0.w);
            u.q.z = pack2(a1.x, a1.y); u.q.w = pack2(a1.z, a1.w);
            a[kt] = u.v;
        }
    } else {
        const u16* ar = (const u16*)Av + (long)(node0 + r16) * K + sub * 8;
        #pragma unroll
        for (int kt = 0; kt < KT; ++kt)
            a[kt] = *(const bf16x8*)(ar + kt * 32);
    }
    auto cc = [&](int ct) {
        f32x4 acc = {0.f, 0.f, 0.f, 0.f};
        #pragma unroll
        for (int kt = 0; kt < KT; ++kt) {
            bf16x8 bfr = *(const bf16x8*)&sP[((kt * 4 + sub) * NC + ct * 16 + r16) * 8];
            acc = __builtin_amdgcn_mfma_f32_16x16x32_bf16(a[kt], bfr, acc, 0, 0, 0);
        }
        return acc;
    };
    #pragma unroll
    for (int i = 0; i < CPK; ++i) {                // plane0/plane2 pairwise
        f32x4 acc0 = cc(i);
        f32x4 acc2 = cc(2 * CPK + i);
        const long rowoff = (long)(node0 + sub * 4) * LDZ + i * 16 + r16;
        #pragma unroll
        for (int r = 0; r < 4; ++r) {
            D02[rowoff + (long)r * LDZ] = f2bf(acc0[r] - acc2[r]);
            Zs[rowoff + (long)r * LDZ]  = f2bf(acc2[r] * dis4[r]);
        }
    }
    #pragma unroll
    for (int i = 0; i < CPK; ++i) {                // plane1
        f32x4 acc1 = cc(CPK + i);
        const long rowoff = (long)(node0 + sub * 4) * LDZ + i * 16 + r16;
        #pragma unroll
        for (int r = 0; r < 4; ++r)
            Z1[rowoff + (long)r * LDZ] = f2bf(acc1[r]);
    }
}

// ============ gather propagate: u16 src records (pre-scaled sources), fused epilogues ===
// acc_d = sum_e g[src_e] ;  (L v)_d = -dis_d * acc_d
// EPI_S  : Ŝ  = dis_d*aux1 - 2*dis_d^2*acc           (aux1 = Z1; bf16 out)
// EPI_H  : h  = relu(aux1 - dis_d*acc + bias)         (aux1 = D02; bf16 out)
// EPI_OUT: out = aux1 - dis_d*acc + bias              (aux1 = D02'; f32 out)

#define EPI_S 0
#define EPI_H 1
#define EPI_OUT 2

__device__ inline void sum8(float (&acc)[8], uint4 q) {
    acc[0] += bflo(q.x); acc[1] += bfhi(q.x);
    acc[2] += bflo(q.y); acc[3] += bfhi(q.y);
    acc[4] += bflo(q.z); acc[5] += bfhi(q.z);
    acc[6] += bflo(q.w); acc[7] += bfhi(q.w);
}

template<int F, int NPB, int CAP, int EPI>
__global__ __launch_bounds__(256)
void gather_prop(const int* __restrict__ row_ptr, const u16* __restrict__ ws,
                 const u16* __restrict__ g,       // PRE-SCALED gather plane [N,F]
                 const u16* __restrict__ aux1,
                 const float* __restrict__ bias,
                 const float* __restrict__ dis,
                 void* __restrict__ outp) {
    __shared__ u16 s_p[CAP];
    __shared__ int s_beg[NPB + 1];
    const int tid = threadIdx.x;
    const int node0 = blockIdx.x * NPB;
    if (tid <= NPB) {
        int n = node0 + tid;
        s_beg[tid] = row_ptr[n > N_NODES ? N_NODES : n];
    }
    __syncthreads();
    const int ebeg = s_beg[0];
    const int cnt = s_beg[NPB] - ebeg;
    const int stage = cnt < CAP ? cnt : CAP;
    for (int e = tid; e < stage; e += 256)
        s_p[e] = ws[ebeg + e];
    __syncthreads();
    constexpr int CPN = F / 8;
    const int nl = tid / CPN;
    const int node = node0 + nl;
    if (nl >= NPB || node >= N_NODES) return;
    const int c8 = (tid % CPN) * 8;
    float acc[8];
    #pragma unroll
    for (int j = 0; j < 8; ++j) acc[j] = 0.0f;
    const int beg = s_beg[nl] - ebeg;
    const int end = s_beg[nl + 1] - ebeg;
    const int mid = end < stage ? end : stage;
    int e = beg;
    for (; e + 8 <= mid; e += 8) {                 // 8-way MLP from LDS records
        int p0 = s_p[e],     p1 = s_p[e + 1], p2 = s_p[e + 2], p3 = s_p[e + 3];
        int p4 = s_p[e + 4], p5 = s_p[e + 5], p6 = s_p[e + 6], p7 = s_p[e + 7];
        uint4 q0 = *(const uint4*)(g + (long)p0 * F + c8);
        uint4 q1 = *(const uint4*)(g + (long)p1 * F + c8);
        uint4 q2 = *(const uint4*)(g + (long)p2 * F + c8);
        uint4 q3 = *(const uint4*)(g + (long)p3 * F + c8);
        uint4 q4 = *(const uint4*)(g + (long)p4 * F + c8);
        uint4 q5 = *(const uint4*)(g + (long)p5 * F + c8);
        uint4 q6 = *(const uint4*)(g + (long)p6 * F + c8);
        uint4 q7 = *(const uint4*)(g + (long)p7 * F + c8);
        sum8(acc, q0); sum8(acc, q1); sum8(acc, q2); sum8(acc, q3);
        sum8(acc, q4); sum8(acc, q5); sum8(acc, q6); sum8(acc, q7);
    }
    for (; e + 4 <= mid; e += 4) {
        int p0 = s_p[e], p1 = s_p[e + 1], p2 = s_p[e + 2], p3 = s_p[e + 3];
        uint4 q0 = *(const uint4*)(g + (long)p0 * F + c8);
        uint4 q1 = *(const uint4*)(g + (long)p1 * F + c8);
        uint4 q2 = *(const uint4*)(g + (long)p2 * F + c8);
        uint4 q3 = *(const uint4*)(g + (long)p3 * F + c8);
        sum8(acc, q0); sum8(acc, q1); sum8(acc, q2); sum8(acc, q3);
    }
    for (; e < mid; ++e)
        sum8(acc, *(const uint4*)(g + (long)s_p[e] * F + c8));
    for (e = (beg > stage ? beg : stage); e < end; ++e)     // overflow fallback (rare)
        sum8(acc, *(const uint4*)(g + (long)ws[ebeg + e] * F + c8));
    const float dd = dis[node];
    if (EPI == EPI_S) {
        const float m1 = dd, m2 = -2.0f * dd * dd;
        const uint4 z1 = *(const uint4*)(aux1 + (long)node * F + c8);
        uint4 r;
        r.x = pack2(fmaf(m1, bflo(z1.x), m2 * acc[0]), fmaf(m1, bfhi(z1.x), m2 * acc[1]));
        r.y = pack2(fmaf(m1, bflo(z1.y), m2 * acc[2]), fmaf(m1, bfhi(z1.y), m2 * acc[3]));
        r.z = pack2(fmaf(m1, bflo(z1.z), m2 * acc[4]), fmaf(m1, bfhi(z1.z), m2 * acc[5]));
        r.w = pack2(fmaf(m1, bflo(z1.w), m2 * acc[6]), fmaf(m1, bfhi(z1.w), m2 * acc[7]));
        *(uint4*)((u16*)outp + (long)node * F + c8) = r;
    } else {
        const uint4 z0 = *(const uint4*)(aux1 + (long)node * F + c8);
        const float* bb = bias + c8;
        float v0 = bflo(z0.x) - dd * acc[0] + bb[0];
        float v1 = bfhi(z0.x) - dd * acc[1] + bb[1];
        float v2 = bflo(z0.y) - dd * acc[2] + bb[2];
        float v3 = bfhi(z0.y) - dd * acc[3] + bb[3];
        float v4 = bflo(z0.z) - dd * acc[4] + bb[4];
        float v5 = bfhi(z0.z) - dd * acc[5] + bb[5];
        float v6 = bflo(z0.w) - dd * acc[6] + bb[6];
        float v7 = bfhi(z0.w) - dd * acc[7] + bb[7];
        if (EPI == EPI_H) {
            uint4 r;
            r.x = pack2(fmaxf(v0, 0.f), fmaxf(v1, 0.f));
            r.y = pack2(fmaxf(v2, 0.f), fmaxf(v3, 0.f));
            r.z = pack2(fmaxf(v4, 0.f), fmaxf(v5, 0.f));
            r.w = pack2(fmaxf(v6, 0.f), fmaxf(v7, 0.f));
            *(uint4*)((u16*)outp + (long)node * F + c8) = r;
        } else {
            float* op = (float*)outp + (long)node * F + c8;
            *(float4*)op = make_float4(v0, v1, v2, v3);
            *(float4*)(op + 4) = make_float4(v4, v5, v6, v7);
        }
    }
}

// ============ launch ============

extern "C" void kernel_launch(void* const* d_in, const int* in_sizes, int n_in,
                              void* d_out, int out_size, void* d_ws, size_t ws_size,
                              hipStream_t stream) {
    const float* x  = (const float*)d_in[0];
    const int*   ei = (const int*)d_in[1];
    const float* W1 = (const float*)d_in[2];
    const float* b1 = (const float*)d_in[3];
    const float* W2 = (const float*)d_in[4];
    const float* b2 = (const float*)d_in[5];
    const int* src = ei;
    const int* dst = ei + N_EDGES;

    // ---- workspace (sections aligned; u16 region starts 16B-aligned) ----
    float* dis          = (float*)d_ws;                      // 50000
    int*   row_ptr      = (int*)(dis + N_NODES);             // 50016
    int*   blk_cnt_src  = row_ptr + 50016;                   // 152896
    int*   blk_cnt_dst  = blk_cnt_src + 152896;              // 152896
    int*   tot_src      = blk_cnt_dst + 152896;              // 512
    int*   tot_dst      = tot_src + 512;                     // 512
    u16*   srconly      = (u16*)(tot_dst + 512);             // E u16
    u32*   sorted_pair  = (u32*)(srconly + N_EDGES);         // E u32
    u16*   wsrc         = (u16*)(sorted_pair + N_EDGES);     // E u16
    u16*   D02          = wsrc + N_EDGES;                    // N*64  (Z0 - Z2)
    u16*   Z1b          = D02 + (long)N_NODES * HID;         // N*64
    u16*   Zs           = Z1b + (long)N_NODES * HID;         // N*64  (dis ⊙ Z2)
    u16*   S            = Zs  + (long)N_NODES * HID;         // N*64  (Ŝ, pre-scaled)
    u16*   hb           = S   + (long)N_NODES * HID;         // N*64
    u16*   D02p         = hb  + (long)N_NODES * HID;         // N*16
    u16*   Z1p          = D02p + (long)N_NODES * D_OUT;      // N*16
    u16*   Zsp          = Z1p  + (long)N_NODES * D_OUT;      // N*16
    u16*   Sp           = Zsp  + (long)N_NODES * D_OUT;      // N*16
    u16*   Pb1          = Sp   + (long)N_NODES * D_OUT;      // 18432
    u16*   Pb2          = Pb1 + 18432;                       // 3072

    // ---- CSR build (no global data atomics); passA also packs weights ----
    passA<<<NBLK_E + PACK_BLKS, 256, 0, stream>>>(src, dst, blk_cnt_src, blk_cnt_dst,
                                                  W1, W2, Pb1, Pb2);
    passB<<<2 * NBKT, 64, 0, stream>>>(blk_cnt_src, blk_cnt_dst, tot_src, tot_dst);
    passC<<<NBLK_E, 256, 0, stream>>>(src, dst, blk_cnt_src, blk_cnt_dst, tot_src, tot_dst,
                                      srconly, sorted_pair);
    passD<<<2 * NBKT, 256, 0, stream>>>(tot_src, srconly, tot_dst, sorted_pair,
                                        dis, row_ptr, wsrc);

    // ---- layer 1: {D02, Z1, Zs} = x @ W1, Ŝ = dis⊙(Z1 + 2 L Z2), h = relu(D02 + L Ŝ + b1)
    const int GB = (N_NODES / 16 + 3) / 4;   // 782
    gemm_mfma<D_IN, 192, HID, 4, true><<<GB, 256, 0, stream>>>(x, Pb1, D02, Z1b, Zs, dis);
    gather_prop<HID, 32, 1024, EPI_S><<<(N_NODES + 31) / 32, 256, 0, stream>>>(
        row_ptr, wsrc, Zs, Z1b, nullptr, dis, S);
    gather_prop<HID, 32, 1024, EPI_H><<<(N_NODES + 31) / 32, 256, 0, stream>>>(
        row_ptr, wsrc, S, D02, b1, dis, hb);

    // ---- layer 2: {D02', Z'1, Zs'} = h @ W2, Ŝ', out = D02' + L Ŝ' + b2 ----
    gemm_mfma<HID, 48, D_OUT, 1, false><<<GB, 256, 0, stream>>>(hb, Pb2, D02p, Z1p, Zsp, dis);
    gather_prop<D_OUT, 128, 3072, EPI_S><<<(N_NODES + 127) / 128, 256, 0, stream>>>(
        row_ptr, wsrc, Zsp, Z1p, nullptr, dis, Sp);
    gather_prop<D_OUT, 128, 3072, EPI_OUT><<<(N_NODES + 127) / 128, 256, 0, stream>>>(
        row_ptr, wsrc, Sp, D02p, b2, dis, (float*)d_out);
}

// Round 13
// 120.523 us; speedup vs baseline: 1.3021x; 1.0035x over previous
//
#include <hip/hip_runtime.h>

#define N_NODES 50000
#define N_EDGES 800000
#define D_IN 96
#define HID 64
#define D_OUT 16

#define EPB 2048                                   // edges per block (passes A/C)
#define NBLK_E ((N_EDGES + EPB - 1) / EPB)         // 391
#define BSHIFT 7                                   // 128 nodes per bucket
#define NBKT ((N_NODES + 127) / 128)               // 391
#define DCAP 2560                                  // Ddst LDS edge staging cap
#define PACK_TOT (3 * D_IN * HID + 3 * HID * D_OUT)   // 21504
#define PACK_BLKS (PACK_TOT / 256)                 // 84
#define GEMM1_BLKS ((N_NODES / 16 + 3) / 4)        // 782

typedef unsigned short u16;
typedef unsigned int u32;
typedef __attribute__((ext_vector_type(4))) float f32x4;
typedef __attribute__((ext_vector_type(8))) short bf16x8;

__device__ inline float bflo(u32 v) { union { u32 i; float f; } u; u.i = v << 16; return u.f; }
__device__ inline float bfhi(u32 v) { union { u32 i; float f; } u; u.i = v & 0xffff0000u; return u.f; }
__device__ inline u16 f2bf(float f) {              // RTNE
    union { float f; u32 i; } u; u.f = f;
    return (u16)((u.i + 0x7fffu + ((u.i >> 16) & 1u)) >> 16);
}
__device__ inline u32 pack2(float lo, float hi) {
    return (u32)f2bf(lo) | ((u32)f2bf(hi) << 16);
}

// ============ passA: coarse histograms (+ fused weight pack in extra blocks) ============

__global__ __launch_bounds__(256)
void passA(const int* __restrict__ src, const int* __restrict__ dst,
           int* __restrict__ blk_cnt_src, int* __restrict__ blk_cnt_dst,
           const float* __restrict__ W1, const float* __restrict__ W2,
           u16* __restrict__ Pb1, u16* __restrict__ Pb2) {
    const int t = threadIdx.x, blk = blockIdx.x;
    if (blk >= NBLK_E) {                           // weight-pack blocks
        int tt = (blk - NBLK_E) * 256 + t;
        if (tt < 3 * D_IN * HID) {                 // 18432: K=96, NC=192, OUTW=64
            int j = tt & 7, rest = tt >> 3;
            int c = rest % 192, i = (rest / 192) * 8 + j;
            int kc = c / 64, o = c % 64;
            Pb1[tt] = f2bf(W1[((long)kc * D_IN + i) * HID + o]);
        } else if (tt < PACK_TOT) {
            int t2 = tt - 3 * D_IN * HID;          // 3072: K=64, NC=48, OUTW=16
            int j = t2 & 7, rest = t2 >> 3;
            int c = rest % 48, i = (rest / 48) * 8 + j;
            int kc = c / 16, o = c % 16;
            Pb2[t2] = f2bf(W2[((long)kc * HID + i) * D_OUT + o]);
        }
        return;
    }
    __shared__ int hs[NBKT], hd[NBKT];
    for (int i = t; i < NBKT; i += 256) { hs[i] = 0; hd[i] = 0; }
    __syncthreads();
    const int e0 = blk * EPB;
    const int e1 = (e0 + EPB < N_EDGES) ? e0 + EPB : N_EDGES;
    for (int e = e0 + t; e < e1; e += 256) {
        atomicAdd(&hs[src[e] >> BSHIFT], 1);
        atomicAdd(&hd[dst[e] >> BSHIFT], 1);
    }
    __syncthreads();
    for (int b = t; b < NBKT; b += 256) {
        blk_cnt_src[b * NBLK_E + blk] = hs[b];
        blk_cnt_dst[b * NBLK_E + blk] = hd[b];
    }
}

// passB: per-bucket exclusive scan over the block dimension (in place), emit totals.
__global__ __launch_bounds__(64)
void passB(int* __restrict__ blk_cnt_src, int* __restrict__ blk_cnt_dst,
           int* __restrict__ tot_src, int* __restrict__ tot_dst) {
    const int b = blockIdx.x;
    int* cnt; int* tot;
    if (b < NBKT) { cnt = blk_cnt_dst + b * NBLK_E;          tot = tot_dst + b; }
    else          { cnt = blk_cnt_src + (b - NBKT) * NBLK_E; tot = tot_src + (b - NBKT); }
    const int lane = threadIdx.x;
    int carry = 0;
    for (int base0 = 0; base0 < NBLK_E; base0 += 64) {
        int i = base0 + lane;
        int v = (i < NBLK_E) ? cnt[i] : 0;
        int incl = v;
        #pragma unroll
        for (int off = 1; off < 64; off <<= 1) {
            int x = __shfl_up(incl, off);
            if (lane >= off) incl += x;
        }
        if (i < NBLK_E) cnt[i] = carry + incl - v;
        carry += __shfl(incl, 63);
    }
    if (lane == 0) *tot = carry;
}

// ============ gemm body (shared by merged layer-1 kernel and standalone layer-2) ======
// Emits: D02 = Z0 - Z2 ; Z1 ; Z2out = (SCALE ? dis⊙Z2 : Z2)

template<int K, int NC, int LDZ, int CPK, bool AF32, bool SCALE>
__device__ __forceinline__
void gemm_body(int tile, int lane, const void* __restrict__ Av, const u16* sP,
               u16* __restrict__ D02, u16* __restrict__ Z1, u16* __restrict__ Z2out,
               const float* __restrict__ dis) {
    constexpr int KT = K / 32;
    const int node0 = tile * 16;
    const int sub = lane >> 4, r16 = lane & 15;
    float dis4[4];
    if constexpr (SCALE) {
        #pragma unroll
        for (int r = 0; r < 4; ++r) dis4[r] = dis[node0 + sub * 4 + r];
    }
    bf16x8 a[KT];
    if constexpr (AF32) {
        const float* ar = (const float*)Av + (long)(node0 + r16) * K + sub * 8;
        #pragma unroll
        for (int kt = 0; kt < KT; ++kt) {
            float4 a0 = *(const float4*)(ar + kt * 32);
            float4 a1 = *(const float4*)(ar + kt * 32 + 4);
            union { bf16x8 v; uint4 q; } u;
            u.q.x = pack2(a0.x, a0.y); u.q.y = pack2(a0.z, a0.w);
            u.q.z = pack2(a1.x, a1.y); u.q.w = pack2(a1.z, a1.w);
            a[kt] = u.v;
        }
    } else {
        const u16* ar = (const u16*)Av + (long)(node0 + r16) * K + sub * 8;
        #pragma unroll
        for (int kt = 0; kt < KT; ++kt)
            a[kt] = *(const bf16x8*)(ar + kt * 32);
    }
    auto cc = [&](int ct) {
        f32x4 acc = {0.f, 0.f, 0.f, 0.f};
        #pragma unroll
        for (int kt = 0; kt < KT; ++kt) {
            bf16x8 bfr = *(const bf16x8*)&sP[((kt * 4 + sub) * NC + ct * 16 + r16) * 8];
            acc = __builtin_amdgcn_mfma_f32_16x16x32_bf16(a[kt], bfr, acc, 0, 0, 0);
        }
        return acc;
    };
    #pragma unroll
    for (int i = 0; i < CPK; ++i) {                // plane0/plane2 pairwise
        f32x4 acc0 = cc(i);
        f32x4 acc2 = cc(2 * CPK + i);
        const long rowoff = (long)(node0 + sub * 4) * LDZ + i * 16 + r16;
        #pragma unroll
        for (int r = 0; r < 4; ++r) {
            D02[rowoff + (long)r * LDZ] = f2bf(acc0[r] - acc2[r]);
            Z2out[rowoff + (long)r * LDZ] = SCALE ? f2bf(acc2[r] * dis4[r]) : f2bf(acc2[r]);
        }
    }
    #pragma unroll
    for (int i = 0; i < CPK; ++i) {                // plane1
        f32x4 acc1 = cc(CPK + i);
        const long rowoff = (long)(node0 + sub * 4) * LDZ + i * 16 + r16;
        #pragma unroll
        for (int r = 0; r < 4; ++r)
            Z1[rowoff + (long)r * LDZ] = f2bf(acc1[r]);
    }
}

// ============ merged passC + gemm1: independent work, one launch ============
// blocks [0, NBLK_E): edge scatter ; blocks [NBLK_E, NBLK_E+GEMM1_BLKS): x @ W1

__global__ __launch_bounds__(256)
void passC_gemm1(const int* __restrict__ src, const int* __restrict__ dst,
                 const int* __restrict__ blk_off_src, const int* __restrict__ blk_off_dst,
                 const int* __restrict__ tot_src, const int* __restrict__ tot_dst,
                 u16* __restrict__ sorted_srconly, u32* __restrict__ sorted_pair,
                 const float* __restrict__ x, const u16* __restrict__ Pb1,
                 u16* __restrict__ D02, u16* __restrict__ Z1, u16* __restrict__ Zs) {
    __shared__ __align__(16) char smem[36864];     // gemm sP (36KB) / passC scan+cursors
    const int t = threadIdx.x, blk = blockIdx.x;
    if (blk >= NBLK_E) {                           // ---- gemm1 blocks ----
        u16* sP = (u16*)smem;
        for (int idx = t * 8; idx < D_IN * 192; idx += 2048)
            *(uint4*)&sP[idx] = *(const uint4*)&Pb1[idx];
        __syncthreads();
        const int tile = (blk - NBLK_E) * 4 + (t >> 6);
        if (tile * 16 >= N_NODES) return;
        gemm_body<D_IN, 192, HID, 4, true, false>(tile, t & 63, x, sP, D02, Z1, Zs, nullptr);
        return;
    }
    // ---- passC blocks ----
    int* s  = (int*)smem;                          // 512
    int* cs = s + 512;                             // NBKT
    int* cd = cs + NBKT;                           // NBKT
    for (int pass = 0; pass < 2; ++pass) {
        const int* tot = pass ? tot_src : tot_dst;
        const int* bo  = pass ? blk_off_src : blk_off_dst;
        int* cx = pass ? cs : cd;
        s[t]       = (t < NBKT) ? tot[t] : 0;
        s[t + 256] = (t + 256 < NBKT) ? tot[t + 256] : 0;
        __syncthreads();
        for (int off = 1; off < 512; off <<= 1) {
            int a1 = (t >= off) ? s[t - off] : 0;
            int a2 = (t + 256 >= off) ? s[t + 256 - off] : 0;
            __syncthreads();
            s[t] += a1; s[t + 256] += a2;
            __syncthreads();
        }
        if (t < NBKT) cx[t] = s[t] - tot[t] + bo[t * NBLK_E + blk];
        if (t + 256 < NBKT) cx[t + 256] = s[t + 256] - tot[t + 256] + bo[(t + 256) * NBLK_E + blk];
        __syncthreads();
    }
    const int e0 = blk * EPB;
    const int e1 = (e0 + EPB < N_EDGES) ? e0 + EPB : N_EDGES;
    for (int e = e0 + t; e < e1; e += 256) {
        int sv = src[e], dv = dst[e];
        int ps = atomicAdd(&cs[sv >> BSHIFT], 1);
        sorted_srconly[ps] = (u16)sv;
        int pd = atomicAdd(&cd[dv >> BSHIFT], 1);
        sorted_pair[pd] = ((u32)dv << 16) | (u32)sv;
    }
}

// passD: merged Dsrc (deg->dis + in-place Zs scaling) + Ddst (fine CSR).
__global__ __launch_bounds__(256)
void passD(const int* __restrict__ tot_src, const u16* __restrict__ sorted_srconly,
           const int* __restrict__ tot_dst, const u32* __restrict__ sorted_pair,
           float* __restrict__ dis, int* __restrict__ row_ptr, u16* __restrict__ wsrc,
           u16* __restrict__ Zs) {
    __shared__ int sred[256];
    __shared__ int hist[128];
    __shared__ int cur[128];
    __shared__ float s_dis[128];
    __shared__ u32 s_p[DCAP];
    const int t = threadIdx.x;
    const bool isSrc = blockIdx.x < NBKT;
    const int b = isSrc ? blockIdx.x : blockIdx.x - NBKT;
    const int* tot = isSrc ? tot_src : tot_dst;
    int part = 0;
    for (int i = t; i < b; i += 256) part += tot[i];
    sred[t] = part;
    if (t < 128) hist[t] = 0;
    __syncthreads();
    #pragma unroll
    for (int off = 128; off > 0; off >>= 1) {
        if (t < off) sred[t] += sred[t + off];
        __syncthreads();
    }
    const int eb = sred[0];
    const int ee = eb + tot[b];
    if (isSrc) {                                   // ---- Dsrc half ----
        for (int i = eb + t; i < ee; i += 256)
            atomicAdd(&hist[sorted_srconly[i] & 127], 1);
        __syncthreads();
        const int node0 = b << BSHIFT;
        if (t < 128) {
            int c = hist[t];
            float dv = c > 0 ? rsqrtf((float)c) : 0.0f;
            s_dis[t] = dv;
            if (node0 + t < N_NODES) dis[node0 + t] = dv;
        }
        __syncthreads();
        // in-place scale: Zs rows (raw Z2 from gemm1) *= dis, 128 rows x 8 uint4
        for (int c = t; c < 128 * 8; c += 256) {
            int ln = c >> 3, off8 = (c & 7) * 8;
            int n = node0 + ln;
            if (n >= N_NODES) continue;
            float dv = s_dis[ln];
            u16* zp = Zs + (long)n * HID + off8;
            uint4 q = *(uint4*)zp;
            uint4 r;
            r.x = pack2(bflo(q.x) * dv, bfhi(q.x) * dv);
            r.y = pack2(bflo(q.y) * dv, bfhi(q.y) * dv);
            r.z = pack2(bflo(q.z) * dv, bfhi(q.z) * dv);
            r.w = pack2(bflo(q.w) * dv, bfhi(q.w) * dv);
            *(uint4*)zp = r;
        }
        return;
    }
    // ---- Ddst half ----
    if (b == 0 && t == 0) row_ptr[N_NODES] = N_EDGES;
    const int cnt = ee - eb;
    const int stage = cnt < DCAP ? cnt : DCAP;
    for (int i = t; i < stage; i += 256) {
        u32 v = sorted_pair[eb + i];
        s_p[i] = v;
        atomicAdd(&hist[(v >> 16) & 127], 1);
    }
    for (int i = stage + t; i < cnt; i += 256)
        atomicAdd(&hist[(sorted_pair[eb + i] >> 16) & 127], 1);
    __syncthreads();
    if (t < 64) {
        int v0 = hist[2 * t], v1 = hist[2 * t + 1];
        int p = v0 + v1;
        int incl = p;
        #pragma unroll
        for (int off = 1; off < 64; off <<= 1) {
            int x = __shfl_up(incl, off);
            if (t >= off) incl += x;
        }
        int excl = incl - p;
        cur[2 * t] = excl;
        cur[2 * t + 1] = excl + v0;
        int node = (b << BSHIFT) + 2 * t;
        if (node < N_NODES) row_ptr[node] = eb + excl;
        if (node + 1 < N_NODES) row_ptr[node + 1] = eb + excl + v0;
    }
    __syncthreads();
    for (int i = t; i < stage; i += 256) {
        u32 v = s_p[i];
        int slot = atomicAdd(&cur[(v >> 16) & 127], 1);
        wsrc[eb + slot] = (u16)(v & 0xFFFF);
    }
    for (int i = stage + t; i < cnt; i += 256) {
        u32 v = sorted_pair[eb + i];
        int slot = atomicAdd(&cur[(v >> 16) & 127], 1);
        wsrc[eb + slot] = (u16)(v & 0xFFFF);
    }
}

// ============ standalone layer-2 gemm (with fused dis scaling) ============

__global__ __launch_bounds__(256)
void gemm2_kernel(const u16* __restrict__ A, const u16* __restrict__ P,
                  u16* __restrict__ D02, u16* __restrict__ Z1, u16* __restrict__ Zs,
                  const float* __restrict__ dis) {
    __shared__ u16 sP[HID * 48];
    for (int idx = threadIdx.x * 8; idx < HID * 48; idx += 2048)
        *(uint4*)&sP[idx] = *(const uint4*)&P[idx];
    __syncthreads();
    const int tile = blockIdx.x * 4 + (threadIdx.x >> 6);
    if (tile * 16 >= N_NODES) return;
    gemm_body<HID, 48, D_OUT, 1, false, true>(tile, threadIdx.x & 63, A, sP, D02, Z1, Zs, dis);
}

// ============ gather propagate: u16 src records, optional column-half split ============
// FS = column slice per block (F or F/2); half = blockIdx % (F/FS) -> XCD parity locality
// EPI_S  : Ŝ  = dis_d*aux1 - 2*dis_d^2*acc           (aux1 = Z1; bf16 out)
// EPI_H  : h  = relu(aux1 - dis_d*acc + bias)         (aux1 = D02; bf16 out)
// EPI_OUT: out = aux1 - dis_d*acc + bias              (aux1 = D02'; f32 out)

#define EPI_S 0
#define EPI_H 1
#define EPI_OUT 2

__device__ inline void sum8(float (&acc)[8], uint4 q) {
    acc[0] += bflo(q.x); acc[1] += bfhi(q.x);
    acc[2] += bflo(q.y); acc[3] += bfhi(q.y);
    acc[4] += bflo(q.z); acc[5] += bfhi(q.z);
    acc[6] += bflo(q.w); acc[7] += bfhi(q.w);
}

template<int F, int FS, int NPB, int CAP, int EPI>
__global__ __launch_bounds__(256)
void gather_prop(const int* __restrict__ row_ptr, const u16* __restrict__ ws,
                 const u16* __restrict__ g,       // PRE-SCALED gather plane [N,F]
                 const u16* __restrict__ aux1,
                 const float* __restrict__ bias,
                 const float* __restrict__ dis,
                 void* __restrict__ outp) {
    static_assert(NPB * (FS / 8) == 256, "block geometry");
    constexpr int SPLIT = F / FS;
    __shared__ u16 s_p[CAP];
    __shared__ int s_beg[NPB + 1];
    const int tid = threadIdx.x;
    const int nodeblk = blockIdx.x / SPLIT;
    const int half = blockIdx.x % SPLIT;
    const int node0 = nodeblk * NPB;
    if (tid <= NPB) {
        int n = node0 + tid;
        s_beg[tid] = row_ptr[n > N_NODES ? N_NODES : n];
    }
    __syncthreads();
    const int ebeg = s_beg[0];
    const int cnt = s_beg[NPB] - ebeg;
    const int stage = cnt < CAP ? cnt : CAP;
    for (int e = tid; e < stage; e += 256)
        s_p[e] = ws[ebeg + e];
    __syncthreads();
    constexpr int CPN = FS / 8;
    const int nl = tid / CPN;
    const int node = node0 + nl;
    if (node >= N_NODES) return;
    const int c8 = (tid % CPN) * 8 + half * FS;
    float acc[8];
    #pragma unroll
    for (int j = 0; j < 8; ++j) acc[j] = 0.0f;
    const int beg = s_beg[nl] - ebeg;
    const int end = s_beg[nl + 1] - ebeg;
    const int mid = end < stage ? end : stage;
    int e = beg;
    for (; e + 8 <= mid; e += 8) {                 // 8-way MLP from LDS records
        int p0 = s_p[e],     p1 = s_p[e + 1], p2 = s_p[e + 2], p3 = s_p[e + 3];
        int p4 = s_p[e + 4], p5 = s_p[e + 5], p6 = s_p[e + 6], p7 = s_p[e + 7];
        uint4 q0 = *(const uint4*)(g + (long)p0 * F + c8);
        uint4 q1 = *(const uint4*)(g + (long)p1 * F + c8);
        uint4 q2 = *(const uint4*)(g + (long)p2 * F + c8);
        uint4 q3 = *(const uint4*)(g + (long)p3 * F + c8);
        uint4 q4 = *(const uint4*)(g + (long)p4 * F + c8);
        uint4 q5 = *(const uint4*)(g + (long)p5 * F + c8);
        uint4 q6 = *(const uint4*)(g + (long)p6 * F + c8);
        uint4 q7 = *(const uint4*)(g + (long)p7 * F + c8);
        sum8(acc, q0); sum8(acc, q1); sum8(acc, q2); sum8(acc, q3);
        sum8(acc, q4); sum8(acc, q5); sum8(acc, q6); sum8(acc, q7);
    }
    for (; e + 4 <= mid; e += 4) {
        int p0 = s_p[e], p1 = s_p[e + 1], p2 = s_p[e + 2], p3 = s_p[e + 3];
        uint4 q0 = *(const uint4*)(g + (long)p0 * F + c8);
        uint4 q1 = *(const uint4*)(g + (long)p1 * F + c8);
        uint4 q2 = *(const uint4*)(g + (long)p2 * F + c8);
        uint4 q3 = *(const uint4*)(g + (long)p3 * F + c8);
        sum8(acc, q0); sum8(acc, q1); sum8(acc, q2); sum8(acc, q3);
    }
    for (; e < mid; ++e)
        sum8(acc, *(const uint4*)(g + (long)s_p[e] * F + c8));
    for (e = (beg > stage ? beg : stage); e < end; ++e)     // overflow fallback (rare)
        sum8(acc, *(const uint4*)(g + (long)ws[ebeg + e] * F + c8));
    const float dd = dis[node];
    if (EPI == EPI_S) {
        const float m1 = dd, m2 = -2.0f * dd * dd;
        const uint4 z1 = *(const uint4*)(aux1 + (long)node * F + c8);
        uint4 r;
        r.x = pack2(fmaf(m1, bflo(z1.x), m2 * acc[0]), fmaf(m1, bfhi(z1.x), m2 * acc[1]));
        r.y = pack2(fmaf(m1, bflo(z1.y), m2 * acc[2]), fmaf(m1, bfhi(z1.y), m2 * acc[3]));
        r.z = pack2(fmaf(m1, bflo(z1.z), m2 * acc[4]), fmaf(m1, bfhi(z1.z), m2 * acc[5]));
        r.w = pack2(fmaf(m1, bflo(z1.w), m2 * acc[6]), fmaf(m1, bfhi(z1.w), m2 * acc[7]));
        *(uint4*)((u16*)outp + (long)node * F + c8) = r;
    } else {
        const uint4 z0 = *(const uint4*)(aux1 + (long)node * F + c8);
        const float* bb = bias + c8;
        float v0 = bflo(z0.x) - dd * acc[0] + bb[0];
        float v1 = bfhi(z0.x) - dd * acc[1] + bb[1];
        float v2 = bflo(z0.y) - dd * acc[2] + bb[2];
        float v3 = bfhi(z0.y) - dd * acc[3] + bb[3];
        float v4 = bflo(z0.z) - dd * acc[4] + bb[4];
        float v5 = bfhi(z0.z) - dd * acc[5] + bb[5];
        float v6 = bflo(z0.w) - dd * acc[6] + bb[6];
        float v7 = bfhi(z0.w) - dd * acc[7] + bb[7];
        if (EPI == EPI_H) {
            uint4 r;
            r.x = pack2(fmaxf(v0, 0.f), fmaxf(v1, 0.f));
            r.y = pack2(fmaxf(v2, 0.f), fmaxf(v3, 0.f));
            r.z = pack2(fmaxf(v4, 0.f), fmaxf(v5, 0.f));
            r.w = pack2(fmaxf(v6, 0.f), fmaxf(v7, 0.f));
            *(uint4*)((u16*)outp + (long)node * F + c8) = r;
        } else {
            float* op = (float*)outp + (long)node * F + c8;
            *(float4*)op = make_float4(v0, v1, v2, v3);
            *(float4*)(op + 4) = make_float4(v4, v5, v6, v7);
        }
    }
}

// ============ launch ============

extern "C" void kernel_launch(void* const* d_in, const int* in_sizes, int n_in,
                              void* d_out, int out_size, void* d_ws, size_t ws_size,
                              hipStream_t stream) {
    const float* x  = (const float*)d_in[0];
    const int*   ei = (const int*)d_in[1];
    const float* W1 = (const float*)d_in[2];
    const float* b1 = (const float*)d_in[3];
    const float* W2 = (const float*)d_in[4];
    const float* b2 = (const float*)d_in[5];
    const int* src = ei;
    const int* dst = ei + N_EDGES;

    // ---- workspace (sections aligned; u16 region starts 16B-aligned) ----
    float* dis          = (float*)d_ws;                      // 50000
    int*   row_ptr      = (int*)(dis + N_NODES);             // 50016
    int*   blk_cnt_src  = row_ptr + 50016;                   // 152896
    int*   blk_cnt_dst  = blk_cnt_src + 152896;              // 152896
    int*   tot_src      = blk_cnt_dst + 152896;              // 512
    int*   tot_dst      = tot_src + 512;                     // 512
    u16*   srconly      = (u16*)(tot_dst + 512);             // E u16
    u32*   sorted_pair  = (u32*)(srconly + N_EDGES);         // E u32
    u16*   wsrc         = (u16*)(sorted_pair + N_EDGES);     // E u16
    u16*   D02          = wsrc + N_EDGES;                    // N*64  (Z0 - Z2)
    u16*   Z1b          = D02 + (long)N_NODES * HID;         // N*64
    u16*   Zs           = Z1b + (long)N_NODES * HID;         // N*64  (Z2, scaled in passD)
    u16*   S            = Zs  + (long)N_NODES * HID;         // N*64  (Ŝ, pre-scaled)
    u16*   hb           = S   + (long)N_NODES * HID;         // N*64
    u16*   D02p         = hb  + (long)N_NODES * HID;         // N*16
    u16*   Z1p          = D02p + (long)N_NODES * D_OUT;      // N*16
    u16*   Zsp          = Z1p  + (long)N_NODES * D_OUT;      // N*16
    u16*   Sp           = Zsp  + (long)N_NODES * D_OUT;      // N*16
    u16*   Pb1          = Sp   + (long)N_NODES * D_OUT;      // 18432
    u16*   Pb2          = Pb1 + 18432;                       // 3072

    // ---- build + layer-1 GEMM (gemm1 overlapped with passC) ----
    passA<<<NBLK_E + PACK_BLKS, 256, 0, stream>>>(src, dst, blk_cnt_src, blk_cnt_dst,
                                                  W1, W2, Pb1, Pb2);
    passB<<<2 * NBKT, 64, 0, stream>>>(blk_cnt_src, blk_cnt_dst, tot_src, tot_dst);
    passC_gemm1<<<NBLK_E + GEMM1_BLKS, 256, 0, stream>>>(
        src, dst, blk_cnt_src, blk_cnt_dst, tot_src, tot_dst,
        srconly, sorted_pair, x, Pb1, D02, Z1b, Zs);
    passD<<<2 * NBKT, 256, 0, stream>>>(tot_src, srconly, tot_dst, sorted_pair,
                                        dis, row_ptr, wsrc, Zs);

    // ---- layer 1 props (column-half split for XCD L2 locality) ----
    gather_prop<HID, 32, 64, 1536, EPI_S><<<2 * ((N_NODES + 63) / 64), 256, 0, stream>>>(
        row_ptr, wsrc, Zs, Z1b, nullptr, dis, S);
    gather_prop<HID, 32, 64, 1536, EPI_H><<<2 * ((N_NODES + 63) / 64), 256, 0, stream>>>(
        row_ptr, wsrc, S, D02, b1, dis, hb);

    // ---- layer 2 ----
    gemm2_kernel<<<GEMM1_BLKS, 256, 0, stream>>>(hb, Pb2, D02p, Z1p, Zsp, dis);
    gather_prop<D_OUT, 16, 128, 3072, EPI_S><<<(N_NODES + 127) / 128, 256, 0, stream>>>(
        row_ptr, wsrc, Zsp, Z1p, nullptr, dis, Sp);
    gather_prop<D_OUT, 16, 128, 3072, EPI_OUT><<<(N_NODES + 127) / 128, 256, 0, stream>>>(
        row_ptr, wsrc, Sp, D02p, b2, dis, (float*)d_out);
}

// Round 14
// 117.676 us; speedup vs baseline: 1.3336x; 1.0242x over previous
//
#include <hip/hip_runtime.h>

#define N_NODES 50000
#define N_EDGES 800000
#define D_IN 96
#define HID 64
#define D_OUT 16

#define EPB 2048                                   // edges per block (passes A/C)
#define NBLK_E ((N_EDGES + EPB - 1) / EPB)         // 391
#define BSHIFT 7                                   // 128 nodes per bucket
#define NBKT ((N_NODES + 127) / 128)               // 391
#define DCAP 2560                                  // Ddst LDS edge staging cap
#define PACK_TOT (3 * D_IN * HID + 3 * HID * D_OUT)   // 21504
#define PACK_BLKS (PACK_TOT / 256)                 // 84
#define GEMM1_BLKS ((N_NODES / 16 + 3) / 4)        // 782

typedef unsigned short u16;
typedef unsigned int u32;
typedef __attribute__((ext_vector_type(4))) float f32x4;
typedef __attribute__((ext_vector_type(8))) short bf16x8;

__device__ inline float bflo(u32 v) { union { u32 i; float f; } u; u.i = v << 16; return u.f; }
__device__ inline float bfhi(u32 v) { union { u32 i; float f; } u; u.i = v & 0xffff0000u; return u.f; }
__device__ inline u16 f2bf(float f) {              // RTNE
    union { float f; u32 i; } u; u.f = f;
    return (u16)((u.i + 0x7fffu + ((u.i >> 16) & 1u)) >> 16);
}
__device__ inline u32 pack2(float lo, float hi) {
    return (u32)f2bf(lo) | ((u32)f2bf(hi) << 16);
}

// ============ passA: coarse histograms (+ fused weight pack in extra blocks) ============

__global__ __launch_bounds__(256)
void passA(const int* __restrict__ src, const int* __restrict__ dst,
           int* __restrict__ blk_cnt_src, int* __restrict__ blk_cnt_dst,
           const float* __restrict__ W1, const float* __restrict__ W2,
           u16* __restrict__ Pb1, u16* __restrict__ Pb2) {
    const int t = threadIdx.x, blk = blockIdx.x;
    if (blk >= NBLK_E) {                           // weight-pack blocks
        int tt = (blk - NBLK_E) * 256 + t;
        if (tt < 3 * D_IN * HID) {                 // 18432: K=96, NC=192, OUTW=64
            int j = tt & 7, rest = tt >> 3;
            int c = rest % 192, i = (rest / 192) * 8 + j;
            int kc = c / 64, o = c % 64;
            Pb1[tt] = f2bf(W1[((long)kc * D_IN + i) * HID + o]);
        } else if (tt < PACK_TOT) {
            int t2 = tt - 3 * D_IN * HID;          // 3072: K=64, NC=48, OUTW=16
            int j = t2 & 7, rest = t2 >> 3;
            int c = rest % 48, i = (rest / 48) * 8 + j;
            int kc = c / 16, o = c % 16;
            Pb2[t2] = f2bf(W2[((long)kc * HID + i) * D_OUT + o]);
        }
        return;
    }
    __shared__ int hs[NBKT], hd[NBKT];
    for (int i = t; i < NBKT; i += 256) { hs[i] = 0; hd[i] = 0; }
    __syncthreads();
    const int e0 = blk * EPB;
    const int e1 = (e0 + EPB < N_EDGES) ? e0 + EPB : N_EDGES;
    for (int e = e0 + t; e < e1; e += 256) {
        atomicAdd(&hs[src[e] >> BSHIFT], 1);
        atomicAdd(&hd[dst[e] >> BSHIFT], 1);
    }
    __syncthreads();
    for (int b = t; b < NBKT; b += 256) {
        blk_cnt_src[b * NBLK_E + blk] = hs[b];
        blk_cnt_dst[b * NBLK_E + blk] = hd[b];
    }
}

// passB: per-bucket exclusive scan over the block dimension (in place), emit totals.
__global__ __launch_bounds__(64)
void passB(int* __restrict__ blk_cnt_src, int* __restrict__ blk_cnt_dst,
           int* __restrict__ tot_src, int* __restrict__ tot_dst) {
    const int b = blockIdx.x;
    int* cnt; int* tot;
    if (b < NBKT) { cnt = blk_cnt_dst + b * NBLK_E;          tot = tot_dst + b; }
    else          { cnt = blk_cnt_src + (b - NBKT) * NBLK_E; tot = tot_src + (b - NBKT); }
    const int lane = threadIdx.x;
    int carry = 0;
    for (int base0 = 0; base0 < NBLK_E; base0 += 64) {
        int i = base0 + lane;
        int v = (i < NBLK_E) ? cnt[i] : 0;
        int incl = v;
        #pragma unroll
        for (int off = 1; off < 64; off <<= 1) {
            int x = __shfl_up(incl, off);
            if (lane >= off) incl += x;
        }
        if (i < NBLK_E) cnt[i] = carry + incl - v;
        carry += __shfl(incl, 63);
    }
    if (lane == 0) *tot = carry;
}

// ============ gemm body (layer-1) ============
// Emits: D02 = Z0 - Z2 ; Z1 ; Z2out = Z2 (raw; scaled later in passD)

template<int K, int NC, int LDZ, int CPK, bool AF32>
__device__ __forceinline__
void gemm_body(int tile, int lane, const void* __restrict__ Av, const u16* sP,
               u16* __restrict__ D02, u16* __restrict__ Z1, u16* __restrict__ Z2out) {
    constexpr int KT = K / 32;
    const int node0 = tile * 16;
    const int sub = lane >> 4, r16 = lane & 15;
    bf16x8 a[KT];
    if constexpr (AF32) {
        const float* ar = (const float*)Av + (long)(node0 + r16) * K + sub * 8;
        #pragma unroll
        for (int kt = 0; kt < KT; ++kt) {
            float4 a0 = *(const float4*)(ar + kt * 32);
            float4 a1 = *(const float4*)(ar + kt * 32 + 4);
            union { bf16x8 v; uint4 q; } u;
            u.q.x = pack2(a0.x, a0.y); u.q.y = pack2(a0.z, a0.w);
            u.q.z = pack2(a1.x, a1.y); u.q.w = pack2(a1.z, a1.w);
            a[kt] = u.v;
        }
    } else {
        const u16* ar = (const u16*)Av + (long)(node0 + r16) * K + sub * 8;
        #pragma unroll
        for (int kt = 0; kt < KT; ++kt)
            a[kt] = *(const bf16x8*)(ar + kt * 32);
    }
    auto cc = [&](int ct) {
        f32x4 acc = {0.f, 0.f, 0.f, 0.f};
        #pragma unroll
        for (int kt = 0; kt < KT; ++kt) {
            bf16x8 bfr = *(const bf16x8*)&sP[((kt * 4 + sub) * NC + ct * 16 + r16) * 8];
            acc = __builtin_amdgcn_mfma_f32_16x16x32_bf16(a[kt], bfr, acc, 0, 0, 0);
        }
        return acc;
    };
    #pragma unroll
    for (int i = 0; i < CPK; ++i) {                // plane0/plane2 pairwise
        f32x4 acc0 = cc(i);
        f32x4 acc2 = cc(2 * CPK + i);
        const long rowoff = (long)(node0 + sub * 4) * LDZ + i * 16 + r16;
        #pragma unroll
        for (int r = 0; r < 4; ++r) {
            D02[rowoff + (long)r * LDZ] = f2bf(acc0[r] - acc2[r]);
            Z2out[rowoff + (long)r * LDZ] = f2bf(acc2[r]);
        }
    }
    #pragma unroll
    for (int i = 0; i < CPK; ++i) {                // plane1
        f32x4 acc1 = cc(CPK + i);
        const long rowoff = (long)(node0 + sub * 4) * LDZ + i * 16 + r16;
        #pragma unroll
        for (int r = 0; r < 4; ++r)
            Z1[rowoff + (long)r * LDZ] = f2bf(acc1[r]);
    }
}

// ============ merged passC + gemm1: independent work, one launch ============

__global__ __launch_bounds__(256)
void passC_gemm1(const int* __restrict__ src, const int* __restrict__ dst,
                 const int* __restrict__ blk_off_src, const int* __restrict__ blk_off_dst,
                 const int* __restrict__ tot_src, const int* __restrict__ tot_dst,
                 u16* __restrict__ sorted_srconly, u32* __restrict__ sorted_pair,
                 const float* __restrict__ x, const u16* __restrict__ Pb1,
                 u16* __restrict__ D02, u16* __restrict__ Z1, u16* __restrict__ Zs) {
    __shared__ __align__(16) char smem[36864];     // gemm sP (36KB) / passC scan+cursors
    const int t = threadIdx.x, blk = blockIdx.x;
    if (blk >= NBLK_E) {                           // ---- gemm1 blocks ----
        u16* sP = (u16*)smem;
        for (int idx = t * 8; idx < D_IN * 192; idx += 2048)
            *(uint4*)&sP[idx] = *(const uint4*)&Pb1[idx];
        __syncthreads();
        const int tile = (blk - NBLK_E) * 4 + (t >> 6);
        if (tile * 16 >= N_NODES) return;
        gemm_body<D_IN, 192, HID, 4, true>(tile, t & 63, x, sP, D02, Z1, Zs);
        return;
    }
    // ---- passC blocks ----
    int* s  = (int*)smem;                          // 512
    int* cs = s + 512;                             // NBKT
    int* cd = cs + NBKT;                           // NBKT
    for (int pass = 0; pass < 2; ++pass) {
        const int* tot = pass ? tot_src : tot_dst;
        const int* bo  = pass ? blk_off_src : blk_off_dst;
        int* cx = pass ? cs : cd;
        s[t]       = (t < NBKT) ? tot[t] : 0;
        s[t + 256] = (t + 256 < NBKT) ? tot[t + 256] : 0;
        __syncthreads();
        for (int off = 1; off < 512; off <<= 1) {
            int a1 = (t >= off) ? s[t - off] : 0;
            int a2 = (t + 256 >= off) ? s[t + 256 - off] : 0;
            __syncthreads();
            s[t] += a1; s[t + 256] += a2;
            __syncthreads();
        }
        if (t < NBKT) cx[t] = s[t] - tot[t] + bo[t * NBLK_E + blk];
        if (t + 256 < NBKT) cx[t + 256] = s[t + 256] - tot[t + 256] + bo[(t + 256) * NBLK_E + blk];
        __syncthreads();
    }
    const int e0 = blk * EPB;
    const int e1 = (e0 + EPB < N_EDGES) ? e0 + EPB : N_EDGES;
    for (int e = e0 + t; e < e1; e += 256) {
        int sv = src[e], dv = dst[e];
        int ps = atomicAdd(&cs[sv >> BSHIFT], 1);
        sorted_srconly[ps] = (u16)sv;
        int pd = atomicAdd(&cd[dv >> BSHIFT], 1);
        sorted_pair[pd] = ((u32)dv << 16) | (u32)sv;
    }
}

// passD: merged Dsrc (deg->dis + in-place Zs scaling) + Ddst (fine CSR).
__global__ __launch_bounds__(256)
void passD(const int* __restrict__ tot_src, const u16* __restrict__ sorted_srconly,
           const int* __restrict__ tot_dst, const u32* __restrict__ sorted_pair,
           float* __restrict__ dis, int* __restrict__ row_ptr, u16* __restrict__ wsrc,
           u16* __restrict__ Zs) {
    __shared__ int sred[256];
    __shared__ int hist[128];
    __shared__ int cur[128];
    __shared__ float s_dis[128];
    __shared__ u32 s_p[DCAP];
    const int t = threadIdx.x;
    const bool isSrc = blockIdx.x < NBKT;
    const int b = isSrc ? blockIdx.x : blockIdx.x - NBKT;
    const int* tot = isSrc ? tot_src : tot_dst;
    int part = 0;
    for (int i = t; i < b; i += 256) part += tot[i];
    sred[t] = part;
    if (t < 128) hist[t] = 0;
    __syncthreads();
    #pragma unroll
    for (int off = 128; off > 0; off >>= 1) {
        if (t < off) sred[t] += sred[t + off];
        __syncthreads();
    }
    const int eb = sred[0];
    const int ee = eb + tot[b];
    if (isSrc) {                                   // ---- Dsrc half ----
        for (int i = eb + t; i < ee; i += 256)
            atomicAdd(&hist[sorted_srconly[i] & 127], 1);
        __syncthreads();
        const int node0 = b << BSHIFT;
        if (t < 128) {
            int c = hist[t];
            float dv = c > 0 ? rsqrtf((float)c) : 0.0f;
            s_dis[t] = dv;
            if (node0 + t < N_NODES) dis[node0 + t] = dv;
        }
        __syncthreads();
        for (int c = t; c < 128 * 8; c += 256) {   // in-place scale Zs *= dis
            int ln = c >> 3, off8 = (c & 7) * 8;
            int n = node0 + ln;
            if (n >= N_NODES) continue;
            float dv = s_dis[ln];
            u16* zp = Zs + (long)n * HID + off8;
            uint4 q = *(uint4*)zp;
            uint4 r;
            r.x = pack2(bflo(q.x) * dv, bfhi(q.x) * dv);
            r.y = pack2(bflo(q.y) * dv, bfhi(q.y) * dv);
            r.z = pack2(bflo(q.z) * dv, bfhi(q.z) * dv);
            r.w = pack2(bflo(q.w) * dv, bfhi(q.w) * dv);
            *(uint4*)zp = r;
        }
        return;
    }
    // ---- Ddst half ----
    if (b == 0 && t == 0) row_ptr[N_NODES] = N_EDGES;
    const int cnt = ee - eb;
    const int stage = cnt < DCAP ? cnt : DCAP;
    for (int i = t; i < stage; i += 256) {
        u32 v = sorted_pair[eb + i];
        s_p[i] = v;
        atomicAdd(&hist[(v >> 16) & 127], 1);
    }
    for (int i = stage + t; i < cnt; i += 256)
        atomicAdd(&hist[(sorted_pair[eb + i] >> 16) & 127], 1);
    __syncthreads();
    if (t < 64) {
        int v0 = hist[2 * t], v1 = hist[2 * t + 1];
        int p = v0 + v1;
        int incl = p;
        #pragma unroll
        for (int off = 1; off < 64; off <<= 1) {
            int x = __shfl_up(incl, off);
            if (t >= off) incl += x;
        }
        int excl = incl - p;
        cur[2 * t] = excl;
        cur[2 * t + 1] = excl + v0;
        int node = (b << BSHIFT) + 2 * t;
        if (node < N_NODES) row_ptr[node] = eb + excl;
        if (node + 1 < N_NODES) row_ptr[node + 1] = eb + excl + v0;
    }
    __syncthreads();
    for (int i = t; i < stage; i += 256) {
        u32 v = s_p[i];
        int slot = atomicAdd(&cur[(v >> 16) & 127], 1);
        wsrc[eb + slot] = (u16)(v & 0xFFFF);
    }
    for (int i = stage + t; i < cnt; i += 256) {
        u32 v = sorted_pair[eb + i];
        int slot = atomicAdd(&cur[(v >> 16) & 127], 1);
        wsrc[eb + slot] = (u16)(v & 0xFFFF);
    }
}

// ============ gather helpers ============

__device__ inline void sum8(float (&acc)[8], uint4 q) {
    acc[0] += bflo(q.x); acc[1] += bfhi(q.x);
    acc[2] += bflo(q.y); acc[3] += bfhi(q.y);
    acc[4] += bflo(q.z); acc[5] += bfhi(q.z);
    acc[6] += bflo(q.w); acc[7] += bfhi(q.w);
}

template<int F>
__device__ __forceinline__
void gather_loop(float (&acc)[8], const u16* s_p, const u16* ws, const u16* g,
                 int beg, int mid, int end, int stage, int ebeg, int c8) {
    int e = beg;
    for (; e + 8 <= mid; e += 8) {
        int p0 = s_p[e],     p1 = s_p[e + 1], p2 = s_p[e + 2], p3 = s_p[e + 3];
        int p4 = s_p[e + 4], p5 = s_p[e + 5], p6 = s_p[e + 6], p7 = s_p[e + 7];
        uint4 q0 = *(const uint4*)(g + (long)p0 * F + c8);
        uint4 q1 = *(const uint4*)(g + (long)p1 * F + c8);
        uint4 q2 = *(const uint4*)(g + (long)p2 * F + c8);
        uint4 q3 = *(const uint4*)(g + (long)p3 * F + c8);
        uint4 q4 = *(const uint4*)(g + (long)p4 * F + c8);
        uint4 q5 = *(const uint4*)(g + (long)p5 * F + c8);
        uint4 q6 = *(const uint4*)(g + (long)p6 * F + c8);
        uint4 q7 = *(const uint4*)(g + (long)p7 * F + c8);
        sum8(acc, q0); sum8(acc, q1); sum8(acc, q2); sum8(acc, q3);
        sum8(acc, q4); sum8(acc, q5); sum8(acc, q6); sum8(acc, q7);
    }
    for (; e + 4 <= mid; e += 4) {
        int p0 = s_p[e], p1 = s_p[e + 1], p2 = s_p[e + 2], p3 = s_p[e + 3];
        uint4 q0 = *(const uint4*)(g + (long)p0 * F + c8);
        uint4 q1 = *(const uint4*)(g + (long)p1 * F + c8);
        uint4 q2 = *(const uint4*)(g + (long)p2 * F + c8);
        uint4 q3 = *(const uint4*)(g + (long)p3 * F + c8);
        sum8(acc, q0); sum8(acc, q1); sum8(acc, q2); sum8(acc, q3);
    }
    for (; e < mid; ++e)
        sum8(acc, *(const uint4*)(g + (long)s_p[e] * F + c8));
    for (e = (beg > stage ? beg : stage); e < end; ++e)     // overflow fallback (rare)
        sum8(acc, *(const uint4*)(g + (long)ws[ebeg + e] * F + c8));
}

// ============ gather propagate (P1 / P3 / P4) ============
// EPI_S  : Ŝ  = dis_d*aux1 - 2*dis_d^2*acc           (aux1 = Z1; bf16 out)
// EPI_OUT: out = aux1 - dis_d*acc + bias              (aux1 = D02'; f32 out)

#define EPI_S 0
#define EPI_OUT 2

template<int F, int FS, int NPB, int CAP, int EPI>
__global__ __launch_bounds__(256)
void gather_prop(const int* __restrict__ row_ptr, const u16* __restrict__ ws,
                 const u16* __restrict__ g, const u16* __restrict__ aux1,
                 const float* __restrict__ bias, const float* __restrict__ dis,
                 void* __restrict__ outp) {
    static_assert(NPB * (FS / 8) == 256, "block geometry");
    constexpr int SPLIT = F / FS;
    __shared__ u16 s_p[CAP];
    __shared__ int s_beg[NPB + 1];
    const int tid = threadIdx.x;
    const int nodeblk = blockIdx.x / SPLIT;
    const int half = blockIdx.x % SPLIT;
    const int node0 = nodeblk * NPB;
    if (tid <= NPB) {
        int n = node0 + tid;
        s_beg[tid] = row_ptr[n > N_NODES ? N_NODES : n];
    }
    __syncthreads();
    const int ebeg = s_beg[0];
    const int cnt = s_beg[NPB] - ebeg;
    const int stage = cnt < CAP ? cnt : CAP;
    for (int e = tid; e < stage; e += 256)
        s_p[e] = ws[ebeg + e];
    __syncthreads();
    constexpr int CPN = FS / 8;
    const int nl = tid / CPN;
    const int node = node0 + nl;
    if (node >= N_NODES) return;
    const int c8 = (tid % CPN) * 8 + half * FS;
    float acc[8];
    #pragma unroll
    for (int j = 0; j < 8; ++j) acc[j] = 0.0f;
    const int beg = s_beg[nl] - ebeg;
    const int end = s_beg[nl + 1] - ebeg;
    const int mid = end < stage ? end : stage;
    gather_loop<F>(acc, s_p, ws, g, beg, mid, end, stage, ebeg, c8);
    const float dd = dis[node];
    if (EPI == EPI_S) {
        const float m1 = dd, m2 = -2.0f * dd * dd;
        const uint4 z1 = *(const uint4*)(aux1 + (long)node * F + c8);
        uint4 r;
        r.x = pack2(fmaf(m1, bflo(z1.x), m2 * acc[0]), fmaf(m1, bfhi(z1.x), m2 * acc[1]));
        r.y = pack2(fmaf(m1, bflo(z1.y), m2 * acc[2]), fmaf(m1, bfhi(z1.y), m2 * acc[3]));
        r.z = pack2(fmaf(m1, bflo(z1.z), m2 * acc[4]), fmaf(m1, bfhi(z1.z), m2 * acc[5]));
        r.w = pack2(fmaf(m1, bflo(z1.w), m2 * acc[6]), fmaf(m1, bfhi(z1.w), m2 * acc[7]));
        *(uint4*)((u16*)outp + (long)node * F + c8) = r;
    } else {
        const uint4 z0 = *(const uint4*)(aux1 + (long)node * F + c8);
        const float* bb = bias + c8;
        float v0 = bflo(z0.x) - dd * acc[0] + bb[0];
        float v1 = bfhi(z0.x) - dd * acc[1] + bb[1];
        float v2 = bflo(z0.y) - dd * acc[2] + bb[2];
        float v3 = bfhi(z0.y) - dd * acc[3] + bb[3];
        float v4 = bflo(z0.z) - dd * acc[4] + bb[4];
        float v5 = bfhi(z0.z) - dd * acc[5] + bb[5];
        float v6 = bflo(z0.w) - dd * acc[6] + bb[6];
        float v7 = bfhi(z0.w) - dd * acc[7] + bb[7];
        float* op = (float*)outp + (long)node * F + c8;
        *(float4*)op = make_float4(v0, v1, v2, v3);
        *(float4*)(op + 4) = make_float4(v4, v5, v6, v7);
    }
}

// ============ fused P2 + gemm2 ============
// Per block: 32 nodes. Prop: h = relu(D02 - dis*Σ S[src] + b1) -> LDS h_tile.
// Then waves 0-1 run the K=64 MFMA gemm2 (2 tiles of 16 nodes) from LDS.

__global__ __launch_bounds__(256)
void prop2_gemm2(const int* __restrict__ row_ptr, const u16* __restrict__ ws,
                 const u16* __restrict__ S, const u16* __restrict__ D02,
                 const float* __restrict__ b1, const float* __restrict__ dis,
                 const u16* __restrict__ Pb2,
                 u16* __restrict__ D02p, u16* __restrict__ Z1p, u16* __restrict__ Zsp) {
    constexpr int NPB = 32, CAP = 1280;
    __shared__ u16 s_p[CAP];
    __shared__ int s_beg[NPB + 1];
    __shared__ u16 sP[HID * 48];                   // 6 KB: packed W2 fragments
    __shared__ u16 h_tile[NPB][HID + 8];           // +8 pad: break 128B-stride banks
    const int tid = threadIdx.x;
    const int node0 = blockIdx.x * NPB;
    for (int idx = tid * 8; idx < HID * 48; idx += 2048)
        *(uint4*)&sP[idx] = *(const uint4*)&Pb2[idx];
    if (tid <= NPB) {
        int n = node0 + tid;
        s_beg[tid] = row_ptr[n > N_NODES ? N_NODES : n];
    }
    __syncthreads();
    const int ebeg = s_beg[0];
    const int cnt = s_beg[NPB] - ebeg;
    const int stage = cnt < CAP ? cnt : CAP;
    for (int e = tid; e < stage; e += 256)
        s_p[e] = ws[ebeg + e];
    __syncthreads();
    const int nl = tid >> 3;                       // CPN = 8
    const int node = node0 + nl;
    const int c8 = (tid & 7) * 8;
    if (node < N_NODES) {                          // NO early return (barrier below)
        float acc[8];
        #pragma unroll
        for (int j = 0; j < 8; ++j) acc[j] = 0.0f;
        const int beg = s_beg[nl] - ebeg;
        const int end = s_beg[nl + 1] - ebeg;
        const int mid = end < stage ? end : stage;
        gather_loop<HID>(acc, s_p, ws, S, beg, mid, end, stage, ebeg, c8);
        const float dd = dis[node];
        const uint4 z0 = *(const uint4*)(D02 + (long)node * HID + c8);
        const float* bb = b1 + c8;
        float v0 = bflo(z0.x) - dd * acc[0] + bb[0];
        float v1 = bfhi(z0.x) - dd * acc[1] + bb[1];
        float v2 = bflo(z0.y) - dd * acc[2] + bb[2];
        float v3 = bfhi(z0.y) - dd * acc[3] + bb[3];
        float v4 = bflo(z0.z) - dd * acc[4] + bb[4];
        float v5 = bfhi(z0.z) - dd * acc[5] + bb[5];
        float v6 = bflo(z0.w) - dd * acc[6] + bb[6];
        float v7 = bfhi(z0.w) - dd * acc[7] + bb[7];
        uint4 r;
        r.x = pack2(fmaxf(v0, 0.f), fmaxf(v1, 0.f));
        r.y = pack2(fmaxf(v2, 0.f), fmaxf(v3, 0.f));
        r.z = pack2(fmaxf(v4, 0.f), fmaxf(v5, 0.f));
        r.w = pack2(fmaxf(v6, 0.f), fmaxf(v7, 0.f));
        *(uint4*)&h_tile[nl][c8] = r;
    }
    __syncthreads();
    // ---- gemm2 from LDS h_tile: waves 0,1 handle the block's two 16-node tiles ----
    const int w = tid >> 6;
    if (w >= 2) return;
    const int tile = blockIdx.x * 2 + w;
    if (tile * 16 >= N_NODES) return;
    const int lane = tid & 63;
    const int sub = lane >> 4, r16 = lane & 15;
    const int gnode0 = tile * 16;
    float dis4[4];
    #pragma unroll
    for (int r = 0; r < 4; ++r) dis4[r] = dis[gnode0 + sub * 4 + r];
    bf16x8 a[2];
    const u16* ar = &h_tile[w * 16 + r16][sub * 8];
    a[0] = *(const bf16x8*)(ar);
    a[1] = *(const bf16x8*)(ar + 32);
    auto cc = [&](int ct) {
        f32x4 acc = {0.f, 0.f, 0.f, 0.f};
        #pragma unroll
        for (int kt = 0; kt < 2; ++kt) {
            bf16x8 bfr = *(const bf16x8*)&sP[((kt * 4 + sub) * 48 + ct * 16 + r16) * 8];
            acc = __builtin_amdgcn_mfma_f32_16x16x32_bf16(a[kt], bfr, acc, 0, 0, 0);
        }
        return acc;
    };
    f32x4 acc0 = cc(0);
    f32x4 acc2 = cc(2);
    f32x4 acc1 = cc(1);
    const long rowoff = (long)(gnode0 + sub * 4) * D_OUT + r16;
    #pragma unroll
    for (int r = 0; r < 4; ++r) {
        D02p[rowoff + (long)r * D_OUT] = f2bf(acc0[r] - acc2[r]);
        Zsp[rowoff + (long)r * D_OUT]  = f2bf(acc2[r] * dis4[r]);
        Z1p[rowoff + (long)r * D_OUT]  = f2bf(acc1[r]);
    }
}

// ============ launch ============

extern "C" void kernel_launch(void* const* d_in, const int* in_sizes, int n_in,
                              void* d_out, int out_size, void* d_ws, size_t ws_size,
                              hipStream_t stream) {
    const float* x  = (const float*)d_in[0];
    const int*   ei = (const int*)d_in[1];
    const float* W1 = (const float*)d_in[2];
    const float* b1 = (const float*)d_in[3];
    const float* W2 = (const float*)d_in[4];
    const float* b2 = (const float*)d_in[5];
    const int* src = ei;
    const int* dst = ei + N_EDGES;

    // ---- workspace (sections aligned; u16 region starts 16B-aligned) ----
    float* dis          = (float*)d_ws;                      // 50000
    int*   row_ptr      = (int*)(dis + N_NODES);             // 50016
    int*   blk_cnt_src  = row_ptr + 50016;                   // 152896
    int*   blk_cnt_dst  = blk_cnt_src + 152896;              // 152896
    int*   tot_src      = blk_cnt_dst + 152896;              // 512
    int*   tot_dst      = tot_src + 512;                     // 512
    u16*   srconly      = (u16*)(tot_dst + 512);             // E u16
    u32*   sorted_pair  = (u32*)(srconly + N_EDGES);         // E u32
    u16*   wsrc         = (u16*)(sorted_pair + N_EDGES);     // E u16
    u16*   D02          = wsrc + N_EDGES;                    // N*64  (Z0 - Z2)
    u16*   Z1b          = D02 + (long)N_NODES * HID;         // N*64
    u16*   Zs           = Z1b + (long)N_NODES * HID;         // N*64  (Z2, scaled in passD)
    u16*   S            = Zs  + (long)N_NODES * HID;         // N*64  (Ŝ, pre-scaled)
    u16*   D02p         = S   + (long)N_NODES * HID;         // N*16
    u16*   Z1p          = D02p + (long)N_NODES * D_OUT;      // N*16
    u16*   Zsp          = Z1p  + (long)N_NODES * D_OUT;      // N*16
    u16*   Sp           = Zsp  + (long)N_NODES * D_OUT;      // N*16
    u16*   Pb1          = Sp   + (long)N_NODES * D_OUT;      // 18432
    u16*   Pb2          = Pb1 + 18432;                       // 3072

    // ---- build + layer-1 GEMM (gemm1 overlapped with passC) ----
    passA<<<NBLK_E + PACK_BLKS, 256, 0, stream>>>(src, dst, blk_cnt_src, blk_cnt_dst,
                                                  W1, W2, Pb1, Pb2);
    passB<<<2 * NBKT, 64, 0, stream>>>(blk_cnt_src, blk_cnt_dst, tot_src, tot_dst);
    passC_gemm1<<<NBLK_E + GEMM1_BLKS, 256, 0, stream>>>(
        src, dst, blk_cnt_src, blk_cnt_dst, tot_src, tot_dst,
        srconly, sorted_pair, x, Pb1, D02, Z1b, Zs);
    passD<<<2 * NBKT, 256, 0, stream>>>(tot_src, srconly, tot_dst, sorted_pair,
                                        dis, row_ptr, wsrc, Zs);

    // ---- layer 1: P1 (split), then fused P2+gemm2 ----
    gather_prop<HID, 32, 64, 1536, EPI_S><<<2 * ((N_NODES + 63) / 64), 256, 0, stream>>>(
        row_ptr, wsrc, Zs, Z1b, nullptr, dis, S);
    prop2_gemm2<<<(N_NODES + 31) / 32, 256, 0, stream>>>(
        row_ptr, wsrc, S, D02, b1, dis, Pb2, D02p, Z1p, Zsp);

    // ---- layer 2 props ----
    gather_prop<D_OUT, 16, 128, 3072, EPI_S><<<(N_NODES + 127) / 128, 256, 0, stream>>>(
        row_ptr, wsrc, Zsp, Z1p, nullptr, dis, Sp);
    gather_prop<D_OUT, 16, 128, 3072, EPI_OUT><<<(N_NODES + 127) / 128, 256, 0, stream>>>(
        row_ptr, wsrc, Sp, D02p, b2, dis, (float*)d_out);
}

// Round 15
// 116.147 us; speedup vs baseline: 1.3512x; 1.0132x over previous
//
#include <hip/hip_runtime.h>

#define N_NODES 50000
#define N_EDGES 800000
#define D_IN 96
#define HID 64
#define D_OUT 16

#define EPB 2048                                   // edges per block (passes A/C)
#define NBLK_E ((N_EDGES + EPB - 1) / EPB)         // 391
#define BSHIFT 7                                   // 128 nodes per bucket
#define NBKT ((N_NODES + 127) / 128)               // 391
#define DCAP 2560                                  // Ddst LDS edge staging cap
#define PACK_TOT (3 * D_IN * HID + 3 * HID * D_OUT)   // 21504
#define PACK_BLKS (PACK_TOT / 256)                 // 84
#define GEMM1_BLKS ((N_NODES / 16 + 3) / 4)        // 782

typedef unsigned short u16;
typedef unsigned int u32;
typedef __attribute__((ext_vector_type(4))) float f32x4;
typedef __attribute__((ext_vector_type(8))) short bf16x8;

__device__ inline float bflo(u32 v) { union { u32 i; float f; } u; u.i = v << 16; return u.f; }
__device__ inline float bfhi(u32 v) { union { u32 i; float f; } u; u.i = v & 0xffff0000u; return u.f; }
__device__ inline u16 f2bf(float f) {              // RTNE
    union { float f; u32 i; } u; u.f = f;
    return (u16)((u.i + 0x7fffu + ((u.i >> 16) & 1u)) >> 16);
}
__device__ inline u32 pack2(float lo, float hi) {
    return (u32)f2bf(lo) | ((u32)f2bf(hi) << 16);
}

// ============ passA: coarse histograms (+ fused weight pack in extra blocks) ============

__global__ __launch_bounds__(256)
void passA(const int* __restrict__ src, const int* __restrict__ dst,
           int* __restrict__ blk_cnt_src, int* __restrict__ blk_cnt_dst,
           const float* __restrict__ W1, const float* __restrict__ W2,
           u16* __restrict__ Pb1, u16* __restrict__ Pb2) {
    const int t = threadIdx.x, blk = blockIdx.x;
    if (blk >= NBLK_E) {                           // weight-pack blocks
        int tt = (blk - NBLK_E) * 256 + t;
        if (tt < 3 * D_IN * HID) {                 // 18432: K=96, NC=192, OUTW=64
            int j = tt & 7, rest = tt >> 3;
            int c = rest % 192, i = (rest / 192) * 8 + j;
            int kc = c / 64, o = c % 64;
            Pb1[tt] = f2bf(W1[((long)kc * D_IN + i) * HID + o]);
        } else if (tt < PACK_TOT) {
            int t2 = tt - 3 * D_IN * HID;          // 3072: K=64, NC=48, OUTW=16
            int j = t2 & 7, rest = t2 >> 3;
            int c = rest % 48, i = (rest / 48) * 8 + j;
            int kc = c / 16, o = c % 16;
            Pb2[t2] = f2bf(W2[((long)kc * HID + i) * D_OUT + o]);
        }
        return;
    }
    __shared__ int hs[NBKT], hd[NBKT];
    for (int i = t; i < NBKT; i += 256) { hs[i] = 0; hd[i] = 0; }
    __syncthreads();
    const int e0 = blk * EPB;
    const int e1 = (e0 + EPB < N_EDGES) ? e0 + EPB : N_EDGES;
    for (int e = e0 + t; e < e1; e += 256) {
        atomicAdd(&hs[src[e] >> BSHIFT], 1);
        atomicAdd(&hd[dst[e] >> BSHIFT], 1);
    }
    __syncthreads();
    for (int b = t; b < NBKT; b += 256) {
        blk_cnt_src[b * NBLK_E + blk] = hs[b];
        blk_cnt_dst[b * NBLK_E + blk] = hd[b];
    }
}

// passB: per-bucket exclusive scan over the block dimension (in place), emit totals.
__global__ __launch_bounds__(64)
void passB(int* __restrict__ blk_cnt_src, int* __restrict__ blk_cnt_dst,
           int* __restrict__ tot_src, int* __restrict__ tot_dst) {
    const int b = blockIdx.x;
    int* cnt; int* tot;
    if (b < NBKT) { cnt = blk_cnt_dst + b * NBLK_E;          tot = tot_dst + b; }
    else          { cnt = blk_cnt_src + (b - NBKT) * NBLK_E; tot = tot_src + (b - NBKT); }
    const int lane = threadIdx.x;
    int carry = 0;
    for (int base0 = 0; base0 < NBLK_E; base0 += 64) {
        int i = base0 + lane;
        int v = (i < NBLK_E) ? cnt[i] : 0;
        int incl = v;
        #pragma unroll
        for (int off = 1; off < 64; off <<= 1) {
            int x = __shfl_up(incl, off);
            if (lane >= off) incl += x;
        }
        if (i < NBLK_E) cnt[i] = carry + incl - v;
        carry += __shfl(incl, 63);
    }
    if (lane == 0) *tot = carry;
}

// ============ gemm body (B-fragments read DIRECT from global; no LDS staging) ======
// Emits: D02 = Z0 - Z2 ; Z1 ; Z2out = Z2 (raw; scaled later in passD)

template<int K, int NC, int LDZ, int CPK, bool AF32>
__device__ __forceinline__
void gemm_body(int tile, int lane, const void* __restrict__ Av, const u16* __restrict__ P,
               u16* __restrict__ D02, u16* __restrict__ Z1, u16* __restrict__ Z2out) {
    constexpr int KT = K / 32;
    const int node0 = tile * 16;
    const int sub = lane >> 4, r16 = lane & 15;
    bf16x8 a[KT];
    if constexpr (AF32) {
        const float* ar = (const float*)Av + (long)(node0 + r16) * K + sub * 8;
        #pragma unroll
        for (int kt = 0; kt < KT; ++kt) {
            float4 a0 = *(const float4*)(ar + kt * 32);
            float4 a1 = *(const float4*)(ar + kt * 32 + 4);
            union { bf16x8 v; uint4 q; } u;
            u.q.x = pack2(a0.x, a0.y); u.q.y = pack2(a0.z, a0.w);
            u.q.z = pack2(a1.x, a1.y); u.q.w = pack2(a1.z, a1.w);
            a[kt] = u.v;
        }
    } else {
        const u16* ar = (const u16*)Av + (long)(node0 + r16) * K + sub * 8;
        #pragma unroll
        for (int kt = 0; kt < KT; ++kt)
            a[kt] = *(const bf16x8*)(ar + kt * 32);
    }
    auto cc = [&](int ct) {
        f32x4 acc = {0.f, 0.f, 0.f, 0.f};
        #pragma unroll
        for (int kt = 0; kt < KT; ++kt) {
            bf16x8 bfr = *(const bf16x8*)&P[((kt * 4 + sub) * NC + ct * 16 + r16) * 8];
            acc = __builtin_amdgcn_mfma_f32_16x16x32_bf16(a[kt], bfr, acc, 0, 0, 0);
        }
        return acc;
    };
    #pragma unroll
    for (int i = 0; i < CPK; ++i) {                // plane0/plane2 pairwise
        f32x4 acc0 = cc(i);
        f32x4 acc2 = cc(2 * CPK + i);
        const long rowoff = (long)(node0 + sub * 4) * LDZ + i * 16 + r16;
        #pragma unroll
        for (int r = 0; r < 4; ++r) {
            D02[rowoff + (long)r * LDZ] = f2bf(acc0[r] - acc2[r]);
            Z2out[rowoff + (long)r * LDZ] = f2bf(acc2[r]);
        }
    }
    #pragma unroll
    for (int i = 0; i < CPK; ++i) {                // plane1
        f32x4 acc1 = cc(CPK + i);
        const long rowoff = (long)(node0 + sub * 4) * LDZ + i * 16 + r16;
        #pragma unroll
        for (int r = 0; r < 4; ++r)
            Z1[rowoff + (long)r * LDZ] = f2bf(acc1[r]);
    }
}

// ============ merged passC + gemm1 (LDS now only 5.2 KB: passC tables) ============

__global__ __launch_bounds__(256)
void passC_gemm1(const int* __restrict__ src, const int* __restrict__ dst,
                 const int* __restrict__ blk_off_src, const int* __restrict__ blk_off_dst,
                 const int* __restrict__ tot_src, const int* __restrict__ tot_dst,
                 u16* __restrict__ sorted_srconly, u32* __restrict__ sorted_pair,
                 const float* __restrict__ x, const u16* __restrict__ Pb1,
                 u16* __restrict__ D02, u16* __restrict__ Z1, u16* __restrict__ Zs) {
    __shared__ int s[512];
    __shared__ int cs[NBKT], cd[NBKT];
    const int t = threadIdx.x, blk = blockIdx.x;
    if (blk >= NBLK_E) {                           // ---- gemm1 blocks (no LDS use) ----
        const int tile = (blk - NBLK_E) * 4 + (t >> 6);
        if (tile * 16 >= N_NODES) return;
        gemm_body<D_IN, 192, HID, 4, true>(tile, t & 63, x, Pb1, D02, Z1, Zs);
        return;
    }
    // ---- passC blocks ----
    for (int pass = 0; pass < 2; ++pass) {
        const int* tot = pass ? tot_src : tot_dst;
        const int* bo  = pass ? blk_off_src : blk_off_dst;
        int* cx = pass ? cs : cd;
        s[t]       = (t < NBKT) ? tot[t] : 0;
        s[t + 256] = (t + 256 < NBKT) ? tot[t + 256] : 0;
        __syncthreads();
        for (int off = 1; off < 512; off <<= 1) {
            int a1 = (t >= off) ? s[t - off] : 0;
            int a2 = (t + 256 >= off) ? s[t + 256 - off] : 0;
            __syncthreads();
            s[t] += a1; s[t + 256] += a2;
            __syncthreads();
        }
        if (t < NBKT) cx[t] = s[t] - tot[t] + bo[t * NBLK_E + blk];
        if (t + 256 < NBKT) cx[t + 256] = s[t + 256] - tot[t + 256] + bo[(t + 256) * NBLK_E + blk];
        __syncthreads();
    }
    const int e0 = blk * EPB;
    const int e1 = (e0 + EPB < N_EDGES) ? e0 + EPB : N_EDGES;
    for (int e = e0 + t; e < e1; e += 256) {
        int sv = src[e], dv = dst[e];
        int ps = atomicAdd(&cs[sv >> BSHIFT], 1);
        sorted_srconly[ps] = (u16)sv;
        int pd = atomicAdd(&cd[dv >> BSHIFT], 1);
        sorted_pair[pd] = ((u32)dv << 16) | (u32)sv;
    }
}

// passD: merged Dsrc (deg->dis + in-place Zs scaling) + Ddst (fine CSR).
__global__ __launch_bounds__(256)
void passD(const int* __restrict__ tot_src, const u16* __restrict__ sorted_srconly,
           const int* __restrict__ tot_dst, const u32* __restrict__ sorted_pair,
           float* __restrict__ dis, int* __restrict__ row_ptr, u16* __restrict__ wsrc,
           u16* __restrict__ Zs) {
    __shared__ int sred[256];
    __shared__ int hist[128];
    __shared__ int cur[128];
    __shared__ float s_dis[128];
    __shared__ u32 s_p[DCAP];
    const int t = threadIdx.x;
    const bool isSrc = blockIdx.x < NBKT;
    const int b = isSrc ? blockIdx.x : blockIdx.x - NBKT;
    const int* tot = isSrc ? tot_src : tot_dst;
    int part = 0;
    for (int i = t; i < b; i += 256) part += tot[i];
    sred[t] = part;
    if (t < 128) hist[t] = 0;
    __syncthreads();
    #pragma unroll
    for (int off = 128; off > 0; off >>= 1) {
        if (t < off) sred[t] += sred[t + off];
        __syncthreads();
    }
    const int eb = sred[0];
    const int ee = eb + tot[b];
    if (isSrc) {                                   // ---- Dsrc half ----
        for (int i = eb + t; i < ee; i += 256)
            atomicAdd(&hist[sorted_srconly[i] & 127], 1);
        __syncthreads();
        const int node0 = b << BSHIFT;
        if (t < 128) {
            int c = hist[t];
            float dv = c > 0 ? rsqrtf((float)c) : 0.0f;
            s_dis[t] = dv;
            if (node0 + t < N_NODES) dis[node0 + t] = dv;
        }
        __syncthreads();
        for (int c = t; c < 128 * 8; c += 256) {   // in-place scale Zs *= dis
            int ln = c >> 3, off8 = (c & 7) * 8;
            int n = node0 + ln;
            if (n >= N_NODES) continue;
            float dv = s_dis[ln];
            u16* zp = Zs + (long)n * HID + off8;
            uint4 q = *(uint4*)zp;
            uint4 r;
            r.x = pack2(bflo(q.x) * dv, bfhi(q.x) * dv);
            r.y = pack2(bflo(q.y) * dv, bfhi(q.y) * dv);
            r.z = pack2(bflo(q.z) * dv, bfhi(q.z) * dv);
            r.w = pack2(bflo(q.w) * dv, bfhi(q.w) * dv);
            *(uint4*)zp = r;
        }
        return;
    }
    // ---- Ddst half ----
    if (b == 0 && t == 0) row_ptr[N_NODES] = N_EDGES;
    const int cnt = ee - eb;
    const int stage = cnt < DCAP ? cnt : DCAP;
    for (int i = t; i < stage; i += 256) {
        u32 v = sorted_pair[eb + i];
        s_p[i] = v;
        atomicAdd(&hist[(v >> 16) & 127], 1);
    }
    for (int i = stage + t; i < cnt; i += 256)
        atomicAdd(&hist[(sorted_pair[eb + i] >> 16) & 127], 1);
    __syncthreads();
    if (t < 64) {
        int v0 = hist[2 * t], v1 = hist[2 * t + 1];
        int p = v0 + v1;
        int incl = p;
        #pragma unroll
        for (int off = 1; off < 64; off <<= 1) {
            int x = __shfl_up(incl, off);
            if (t >= off) incl += x;
        }
        int excl = incl - p;
        cur[2 * t] = excl;
        cur[2 * t + 1] = excl + v0;
        int node = (b << BSHIFT) + 2 * t;
        if (node < N_NODES) row_ptr[node] = eb + excl;
        if (node + 1 < N_NODES) row_ptr[node + 1] = eb + excl + v0;
    }
    __syncthreads();
    for (int i = t; i < stage; i += 256) {
        u32 v = s_p[i];
        int slot = atomicAdd(&cur[(v >> 16) & 127], 1);
        wsrc[eb + slot] = (u16)(v & 0xFFFF);
    }
    for (int i = stage + t; i < cnt; i += 256) {
        u32 v = sorted_pair[eb + i];
        int slot = atomicAdd(&cur[(v >> 16) & 127], 1);
        wsrc[eb + slot] = (u16)(v & 0xFFFF);
    }
}

// ============ gather helpers ============

__device__ inline void sum8(float (&acc)[8], uint4 q) {
    acc[0] += bflo(q.x); acc[1] += bfhi(q.x);
    acc[2] += bflo(q.y); acc[3] += bfhi(q.y);
    acc[4] += bflo(q.z); acc[5] += bfhi(q.z);
    acc[6] += bflo(q.w); acc[7] += bfhi(q.w);
}

template<int F>
__device__ __forceinline__
void gather_loop(float (&acc)[8], const u16* s_p, const u16* ws, const u16* g,
                 int beg, int mid, int end, int stage, int ebeg, int c8) {
    int e = beg;
    for (; e + 8 <= mid; e += 8) {
        int p0 = s_p[e],     p1 = s_p[e + 1], p2 = s_p[e + 2], p3 = s_p[e + 3];
        int p4 = s_p[e + 4], p5 = s_p[e + 5], p6 = s_p[e + 6], p7 = s_p[e + 7];
        uint4 q0 = *(const uint4*)(g + (long)p0 * F + c8);
        uint4 q1 = *(const uint4*)(g + (long)p1 * F + c8);
        uint4 q2 = *(const uint4*)(g + (long)p2 * F + c8);
        uint4 q3 = *(const uint4*)(g + (long)p3 * F + c8);
        uint4 q4 = *(const uint4*)(g + (long)p4 * F + c8);
        uint4 q5 = *(const uint4*)(g + (long)p5 * F + c8);
        uint4 q6 = *(const uint4*)(g + (long)p6 * F + c8);
        uint4 q7 = *(const uint4*)(g + (long)p7 * F + c8);
        sum8(acc, q0); sum8(acc, q1); sum8(acc, q2); sum8(acc, q3);
        sum8(acc, q4); sum8(acc, q5); sum8(acc, q6); sum8(acc, q7);
    }
    for (; e + 4 <= mid; e += 4) {
        int p0 = s_p[e], p1 = s_p[e + 1], p2 = s_p[e + 2], p3 = s_p[e + 3];
        uint4 q0 = *(const uint4*)(g + (long)p0 * F + c8);
        uint4 q1 = *(const uint4*)(g + (long)p1 * F + c8);
        uint4 q2 = *(const uint4*)(g + (long)p2 * F + c8);
        uint4 q3 = *(const uint4*)(g + (long)p3 * F + c8);
        sum8(acc, q0); sum8(acc, q1); sum8(acc, q2); sum8(acc, q3);
    }
    for (; e < mid; ++e)
        sum8(acc, *(const uint4*)(g + (long)s_p[e] * F + c8));
    for (e = (beg > stage ? beg : stage); e < end; ++e)     // overflow fallback (rare)
        sum8(acc, *(const uint4*)(g + (long)ws[ebeg + e] * F + c8));
}

// ============ gather propagate (P1 / P3 / P4) ============
// EPI_S  : Ŝ  = dis_d*aux1 - 2*dis_d^2*acc           (aux1 = Z1; bf16 out)
// EPI_OUT: out = aux1 - dis_d*acc + bias              (aux1 = D02'; f32 out)

#define EPI_S 0
#define EPI_OUT 2

template<int F, int FS, int NPB, int CAP, int EPI>
__global__ __launch_bounds__(256)
void gather_prop(const int* __restrict__ row_ptr, const u16* __restrict__ ws,
                 const u16* __restrict__ g, const u16* __restrict__ aux1,
                 const float* __restrict__ bias, const float* __restrict__ dis,
                 void* __restrict__ outp) {
    static_assert(NPB * (FS / 8) == 256, "block geometry");
    constexpr int SPLIT = F / FS;
    __shared__ u16 s_p[CAP];
    __shared__ int s_beg[NPB + 1];
    const int tid = threadIdx.x;
    const int nodeblk = blockIdx.x / SPLIT;
    const int half = blockIdx.x % SPLIT;
    const int node0 = nodeblk * NPB;
    if (tid <= NPB) {
        int n = node0 + tid;
        s_beg[tid] = row_ptr[n > N_NODES ? N_NODES : n];
    }
    __syncthreads();
    const int ebeg = s_beg[0];
    const int cnt = s_beg[NPB] - ebeg;
    const int stage = cnt < CAP ? cnt : CAP;
    for (int e = tid; e < stage; e += 256)
        s_p[e] = ws[ebeg + e];
    __syncthreads();
    constexpr int CPN = FS / 8;
    const int nl = tid / CPN;
    const int node = node0 + nl;
    if (node >= N_NODES) return;
    const int c8 = (tid % CPN) * 8 + half * FS;
    float acc[8];
    #pragma unroll
    for (int j = 0; j < 8; ++j) acc[j] = 0.0f;
    const int beg = s_beg[nl] - ebeg;
    const int end = s_beg[nl + 1] - ebeg;
    const int mid = end < stage ? end : stage;
    gather_loop<F>(acc, s_p, ws, g, beg, mid, end, stage, ebeg, c8);
    const float dd = dis[node];
    if (EPI == EPI_S) {
        const float m1 = dd, m2 = -2.0f * dd * dd;
        const uint4 z1 = *(const uint4*)(aux1 + (long)node * F + c8);
        uint4 r;
        r.x = pack2(fmaf(m1, bflo(z1.x), m2 * acc[0]), fmaf(m1, bfhi(z1.x), m2 * acc[1]));
        r.y = pack2(fmaf(m1, bflo(z1.y), m2 * acc[2]), fmaf(m1, bfhi(z1.y), m2 * acc[3]));
        r.z = pack2(fmaf(m1, bflo(z1.z), m2 * acc[4]), fmaf(m1, bfhi(z1.z), m2 * acc[5]));
        r.w = pack2(fmaf(m1, bflo(z1.w), m2 * acc[6]), fmaf(m1, bfhi(z1.w), m2 * acc[7]));
        *(uint4*)((u16*)outp + (long)node * F + c8) = r;
    } else {
        const uint4 z0 = *(const uint4*)(aux1 + (long)node * F + c8);
        const float* bb = bias + c8;
        float v0 = bflo(z0.x) - dd * acc[0] + bb[0];
        float v1 = bfhi(z0.x) - dd * acc[1] + bb[1];
        float v2 = bflo(z0.y) - dd * acc[2] + bb[2];
        float v3 = bfhi(z0.y) - dd * acc[3] + bb[3];
        float v4 = bflo(z0.z) - dd * acc[4] + bb[4];
        float v5 = bfhi(z0.z) - dd * acc[5] + bb[5];
        float v6 = bflo(z0.w) - dd * acc[6] + bb[6];
        float v7 = bfhi(z0.w) - dd * acc[7] + bb[7];
        float* op = (float*)outp + (long)node * F + c8;
        *(float4*)op = make_float4(v0, v1, v2, v3);
        *(float4*)(op + 4) = make_float4(v4, v5, v6, v7);
    }
}

// ============ fused P2 + gemm2 (W2 fragments read direct from global) ============
// Per block: 32 nodes. Prop: h = relu(D02 - dis*Σ S[src] + b1) -> LDS h_tile.
// Then waves 0-1 run the K=64 MFMA gemm2 (2 tiles of 16 nodes) from LDS.

__global__ __launch_bounds__(256)
void prop2_gemm2(const int* __restrict__ row_ptr, const u16* __restrict__ ws,
                 const u16* __restrict__ S, const u16* __restrict__ D02,
                 const float* __restrict__ b1, const float* __restrict__ dis,
                 const u16* __restrict__ Pb2,
                 u16* __restrict__ D02p, u16* __restrict__ Z1p, u16* __restrict__ Zsp) {
    constexpr int NPB = 32, CAP = 1280;
    __shared__ u16 s_p[CAP];
    __shared__ int s_beg[NPB + 1];
    __shared__ u16 h_tile[NPB][HID + 8];           // +8 pad: break 128B-stride banks
    const int tid = threadIdx.x;
    const int node0 = blockIdx.x * NPB;
    if (tid <= NPB) {
        int n = node0 + tid;
        s_beg[tid] = row_ptr[n > N_NODES ? N_NODES : n];
    }
    __syncthreads();
    const int ebeg = s_beg[0];
    const int cnt = s_beg[NPB] - ebeg;
    const int stage = cnt < CAP ? cnt : CAP;
    for (int e = tid; e < stage; e += 256)
        s_p[e] = ws[ebeg + e];
    __syncthreads();
    const int nl = tid >> 3;                       // CPN = 8
    const int node = node0 + nl;
    const int c8 = (tid & 7) * 8;
    if (node < N_NODES) {                          // NO early return (barrier below)
        float acc[8];
        #pragma unroll
        for (int j = 0; j < 8; ++j) acc[j] = 0.0f;
        const int beg = s_beg[nl] - ebeg;
        const int end = s_beg[nl + 1] - ebeg;
        const int mid = end < stage ? end : stage;
        gather_loop<HID>(acc, s_p, ws, S, beg, mid, end, stage, ebeg, c8);
        const float dd = dis[node];
        const uint4 z0 = *(const uint4*)(D02 + (long)node * HID + c8);
        const float* bb = b1 + c8;
        float v0 = bflo(z0.x) - dd * acc[0] + bb[0];
        float v1 = bfhi(z0.x) - dd * acc[1] + bb[1];
        float v2 = bflo(z0.y) - dd * acc[2] + bb[2];
        float v3 = bfhi(z0.y) - dd * acc[3] + bb[3];
        float v4 = bflo(z0.z) - dd * acc[4] + bb[4];
        float v5 = bfhi(z0.z) - dd * acc[5] + bb[5];
        float v6 = bflo(z0.w) - dd * acc[6] + bb[6];
        float v7 = bfhi(z0.w) - dd * acc[7] + bb[7];
        uint4 r;
        r.x = pack2(fmaxf(v0, 0.f), fmaxf(v1, 0.f));
        r.y = pack2(fmaxf(v2, 0.f), fmaxf(v3, 0.f));
        r.z = pack2(fmaxf(v4, 0.f), fmaxf(v5, 0.f));
        r.w = pack2(fmaxf(v6, 0.f), fmaxf(v7, 0.f));
        *(uint4*)&h_tile[nl][c8] = r;
    }
    __syncthreads();
    // ---- gemm2 from LDS h_tile: waves 0,1 handle the block's two 16-node tiles ----
    const int w = tid >> 6;
    if (w >= 2) return;
    const int tile = blockIdx.x * 2 + w;
    if (tile * 16 >= N_NODES) return;
    const int lane = tid & 63;
    const int sub = lane >> 4, r16 = lane & 15;
    const int gnode0 = tile * 16;
    float dis4[4];
    #pragma unroll
    for (int r = 0; r < 4; ++r) dis4[r] = dis[gnode0 + sub * 4 + r];
    bf16x8 a[2];
    const u16* ar = &h_tile[w * 16 + r16][sub * 8];
    a[0] = *(const bf16x8*)(ar);
    a[1] = *(const bf16x8*)(ar + 32);
    auto cc = [&](int ct) {
        f32x4 acc = {0.f, 0.f, 0.f, 0.f};
        #pragma unroll
        for (int kt = 0; kt < 2; ++kt) {
            bf16x8 bfr = *(const bf16x8*)&Pb2[((kt * 4 + sub) * 48 + ct * 16 + r16) * 8];
            acc = __builtin_amdgcn_mfma_f32_16x16x32_bf16(a[kt], bfr, acc, 0, 0, 0);
        }
        return acc;
    };
    f32x4 acc0 = cc(0);
    f32x4 acc2 = cc(2);
    f32x4 acc1 = cc(1);
    const long rowoff = (long)(gnode0 + sub * 4) * D_OUT + r16;
    #pragma unroll
    for (int r = 0; r < 4; ++r) {
        D02p[rowoff + (long)r * D_OUT] = f2bf(acc0[r] - acc2[r]);
        Zsp[rowoff + (long)r * D_OUT]  = f2bf(acc2[r] * dis4[r]);
        Z1p[rowoff + (long)r * D_OUT]  = f2bf(acc1[r]);
    }
}

// ============ launch ============

extern "C" void kernel_launch(void* const* d_in, const int* in_sizes, int n_in,
                              void* d_out, int out_size, void* d_ws, size_t ws_size,
                              hipStream_t stream) {
    const float* x  = (const float*)d_in[0];
    const int*   ei = (const int*)d_in[1];
    const float* W1 = (const float*)d_in[2];
    const float* b1 = (const float*)d_in[3];
    const float* W2 = (const float*)d_in[4];
    const float* b2 = (const float*)d_in[5];
    const int* src = ei;
    const int* dst = ei + N_EDGES;

    // ---- workspace (sections aligned; u16 region starts 16B-aligned) ----
    float* dis          = (float*)d_ws;                      // 50000
    int*   row_ptr      = (int*)(dis + N_NODES);             // 50016
    int*   blk_cnt_src  = row_ptr + 50016;                   // 152896
    int*   blk_cnt_dst  = blk_cnt_src + 152896;              // 152896
    int*   tot_src      = blk_cnt_dst + 152896;              // 512
    int*   tot_dst      = tot_src + 512;                     // 512
    u16*   srconly      = (u16*)(tot_dst + 512);             // E u16
    u32*   sorted_pair  = (u32*)(srconly + N_EDGES);         // E u32
    u16*   wsrc         = (u16*)(sorted_pair + N_EDGES);     // E u16
    u16*   D02          = wsrc + N_EDGES;                    // N*64  (Z0 - Z2)
    u16*   Z1b          = D02 + (long)N_NODES * HID;         // N*64
    u16*   Zs           = Z1b + (long)N_NODES * HID;         // N*64  (Z2, scaled in passD)
    u16*   S            = Zs  + (long)N_NODES * HID;         // N*64  (Ŝ, pre-scaled)
    u16*   D02p         = S   + (long)N_NODES * HID;         // N*16
    u16*   Z1p          = D02p + (long)N_NODES * D_OUT;      // N*16
    u16*   Zsp          = Z1p  + (long)N_NODES * D_OUT;      // N*16
    u16*   Sp           = Zsp  + (long)N_NODES * D_OUT;      // N*16
    u16*   Pb1          = Sp   + (long)N_NODES * D_OUT;      // 18432
    u16*   Pb2          = Pb1 + 18432;                       // 3072

    // ---- build + layer-1 GEMM (gemm1 overlapped with passC) ----
    passA<<<NBLK_E + PACK_BLKS, 256, 0, stream>>>(src, dst, blk_cnt_src, blk_cnt_dst,
                                                  W1, W2, Pb1, Pb2);
    passB<<<2 * NBKT, 64, 0, stream>>>(blk_cnt_src, blk_cnt_dst, tot_src, tot_dst);
    passC_gemm1<<<NBLK_E + GEMM1_BLKS, 256, 0, stream>>>(
        src, dst, blk_cnt_src, blk_cnt_dst, tot_src, tot_dst,
        srconly, sorted_pair, x, Pb1, D02, Z1b, Zs);
    passD<<<2 * NBKT, 256, 0, stream>>>(tot_src, srconly, tot_dst, sorted_pair,
                                        dis, row_ptr, wsrc, Zs);

    // ---- layer 1: P1 (split), then fused P2+gemm2 ----
    gather_prop<HID, 32, 64, 1536, EPI_S><<<2 * ((N_NODES + 63) / 64), 256, 0, stream>>>(
        row_ptr, wsrc, Zs, Z1b, nullptr, dis, S);
    prop2_gemm2<<<(N_NODES + 31) / 32, 256, 0, stream>>>(
        row_ptr, wsrc, S, D02, b1, dis, Pb2, D02p, Z1p, Zsp);

    // ---- layer 2 props ----
    gather_prop<D_OUT, 16, 128, 3072, EPI_S><<<(N_NODES + 127) / 128, 256, 0, stream>>>(
        row_ptr, wsrc, Zsp, Z1p, nullptr, dis, Sp);
    gather_prop<D_OUT, 16, 128, 3072, EPI_OUT><<<(N_NODES + 127) / 128, 256, 0, stream>>>(
        row_ptr, wsrc, Sp, D02p, b2, dis, (float*)d_out);
}

// Round 16
// 110.068 us; speedup vs baseline: 1.4258x; 1.0552x over previous
//
#include <hip/hip_runtime.h>

#define N_NODES 50000
#define N_EDGES 800000
#define D_IN 96
#define HID 64
#define D_OUT 16

#define EPB 2048                                   // edges per block (passes A/C)
#define NBLK_E ((N_EDGES + EPB - 1) / EPB)         // 391
#define BSHIFT 7                                   // 128 nodes per bucket
#define NBKT ((N_NODES + 127) / 128)               // 391
#define DCAP 2560                                  // Ddst LDS edge staging cap
#define PACK_TOT (3 * D_IN * HID + 3 * HID * D_OUT)   // 21504
#define PACK_BLKS (PACK_TOT / 256)                 // 84
#define CVT_N (N_NODES * D_IN)                     // 4800000
#define CVT_BLKS ((CVT_N / 8 + 255) / 256)         // 2344
#define GEMM1_BLKS ((N_NODES / 16 + 3) / 4)        // 782

typedef unsigned short u16;
typedef unsigned int u32;
typedef __attribute__((ext_vector_type(4))) float f32x4;
typedef __attribute__((ext_vector_type(8))) short bf16x8;

__device__ inline float bflo(u32 v) { union { u32 i; float f; } u; u.i = v << 16; return u.f; }
__device__ inline float bfhi(u32 v) { union { u32 i; float f; } u; u.i = v & 0xffff0000u; return u.f; }
__device__ inline u16 f2bf(float f) {              // RTNE
    union { float f; u32 i; } u; u.f = f;
    return (u16)((u.i + 0x7fffu + ((u.i >> 16) & 1u)) >> 16);
}
__device__ inline u32 pack2(float lo, float hi) {
    return (u32)f2bf(lo) | ((u32)f2bf(hi) << 16);
}

// ============ passA: coarse histograms + weight pack + x->bf16 convert ============

__global__ __launch_bounds__(256)
void passA(const int* __restrict__ src, const int* __restrict__ dst,
           int* __restrict__ blk_cnt_src, int* __restrict__ blk_cnt_dst,
           const float* __restrict__ W1, const float* __restrict__ W2,
           u16* __restrict__ Pb1, u16* __restrict__ Pb2,
           const float* __restrict__ x, u16* __restrict__ xb) {
    const int t = threadIdx.x, blk = blockIdx.x;
    if (blk >= NBLK_E + PACK_BLKS) {               // ---- x convert blocks ----
        long idx8 = ((long)(blk - NBLK_E - PACK_BLKS) * 256 + t) * 8;
        if (idx8 < CVT_N) {
            float4 a0 = *(const float4*)(x + idx8);
            float4 a1 = *(const float4*)(x + idx8 + 4);
            uint4 r;
            r.x = pack2(a0.x, a0.y); r.y = pack2(a0.z, a0.w);
            r.z = pack2(a1.x, a1.y); r.w = pack2(a1.z, a1.w);
            *(uint4*)(xb + idx8) = r;
        }
        return;
    }
    if (blk >= NBLK_E) {                           // ---- weight-pack blocks ----
        int tt = (blk - NBLK_E) * 256 + t;
        if (tt < 3 * D_IN * HID) {                 // 18432: K=96, NC=192, OUTW=64
            int j = tt & 7, rest = tt >> 3;
            int c = rest % 192, i = (rest / 192) * 8 + j;
            int kc = c / 64, o = c % 64;
            Pb1[tt] = f2bf(W1[((long)kc * D_IN + i) * HID + o]);
        } else if (tt < PACK_TOT) {
            int t2 = tt - 3 * D_IN * HID;          // 3072: K=64, NC=48, OUTW=16
            int j = t2 & 7, rest = t2 >> 3;
            int c = rest % 48, i = (rest / 48) * 8 + j;
            int kc = c / 16, o = c % 16;
            Pb2[t2] = f2bf(W2[((long)kc * HID + i) * D_OUT + o]);
        }
        return;
    }
    // ---- histogram blocks ----
    __shared__ int hs[NBKT], hd[NBKT];
    for (int i = t; i < NBKT; i += 256) { hs[i] = 0; hd[i] = 0; }
    __syncthreads();
    const int e0 = blk * EPB;
    if (e0 + EPB <= N_EDGES) {                     // full block: 8 edges/thread, int4 loads
        const int base = e0 + t * 8;
        int4 s0 = *(const int4*)(src + base), s1 = *(const int4*)(src + base + 4);
        int4 d0 = *(const int4*)(dst + base), d1 = *(const int4*)(dst + base + 4);
        atomicAdd(&hs[s0.x >> BSHIFT], 1); atomicAdd(&hs[s0.y >> BSHIFT], 1);
        atomicAdd(&hs[s0.z >> BSHIFT], 1); atomicAdd(&hs[s0.w >> BSHIFT], 1);
        atomicAdd(&hs[s1.x >> BSHIFT], 1); atomicAdd(&hs[s1.y >> BSHIFT], 1);
        atomicAdd(&hs[s1.z >> BSHIFT], 1); atomicAdd(&hs[s1.w >> BSHIFT], 1);
        atomicAdd(&hd[d0.x >> BSHIFT], 1); atomicAdd(&hd[d0.y >> BSHIFT], 1);
        atomicAdd(&hd[d0.z >> BSHIFT], 1); atomicAdd(&hd[d0.w >> BSHIFT], 1);
        atomicAdd(&hd[d1.x >> BSHIFT], 1); atomicAdd(&hd[d1.y >> BSHIFT], 1);
        atomicAdd(&hd[d1.z >> BSHIFT], 1); atomicAdd(&hd[d1.w >> BSHIFT], 1);
    } else {                                       // tail block
        for (int e = e0 + t; e < N_EDGES; e += 256) {
            atomicAdd(&hs[src[e] >> BSHIFT], 1);
            atomicAdd(&hd[dst[e] >> BSHIFT], 1);
        }
    }
    __syncthreads();
    for (int b = t; b < NBKT; b += 256) {
        blk_cnt_src[b * NBLK_E + blk] = hs[b];
        blk_cnt_dst[b * NBLK_E + blk] = hd[b];
    }
}

// passB: per-bucket exclusive scan over the block dimension (in place), emit totals.
__global__ __launch_bounds__(64)
void passB(int* __restrict__ blk_cnt_src, int* __restrict__ blk_cnt_dst,
           int* __restrict__ tot_src, int* __restrict__ tot_dst) {
    const int b = blockIdx.x;
    int* cnt; int* tot;
    if (b < NBKT) { cnt = blk_cnt_dst + b * NBLK_E;          tot = tot_dst + b; }
    else          { cnt = blk_cnt_src + (b - NBKT) * NBLK_E; tot = tot_src + (b - NBKT); }
    const int lane = threadIdx.x;
    int carry = 0;
    for (int base0 = 0; base0 < NBLK_E; base0 += 64) {
        int i = base0 + lane;
        int v = (i < NBLK_E) ? cnt[i] : 0;
        int incl = v;
        #pragma unroll
        for (int off = 1; off < 64; off <<= 1) {
            int x = __shfl_up(incl, off);
            if (lane >= off) incl += x;
        }
        if (i < NBLK_E) cnt[i] = carry + incl - v;
        carry += __shfl(incl, 63);
    }
    if (lane == 0) *tot = carry;
}

// ============ gemm body (bf16 A; B-fragments direct from global) ============
// Emits: D02 = Z0 - Z2 ; Z1 ; Z2out = Z2 (raw; scaled later in passD)

template<int K, int NC, int LDZ, int CPK>
__device__ __forceinline__
void gemm_body(int tile, int lane, const u16* __restrict__ A, const u16* __restrict__ P,
               u16* __restrict__ D02, u16* __restrict__ Z1, u16* __restrict__ Z2out) {
    constexpr int KT = K / 32;
    const int node0 = tile * 16;
    const int sub = lane >> 4, r16 = lane & 15;
    bf16x8 a[KT];
    const u16* ar = A + (long)(node0 + r16) * K + sub * 8;
    #pragma unroll
    for (int kt = 0; kt < KT; ++kt)
        a[kt] = *(const bf16x8*)(ar + kt * 32);
    auto cc = [&](int ct) {
        f32x4 acc = {0.f, 0.f, 0.f, 0.f};
        #pragma unroll
        for (int kt = 0; kt < KT; ++kt) {
            bf16x8 bfr = *(const bf16x8*)&P[((kt * 4 + sub) * NC + ct * 16 + r16) * 8];
            acc = __builtin_amdgcn_mfma_f32_16x16x32_bf16(a[kt], bfr, acc, 0, 0, 0);
        }
        return acc;
    };
    #pragma unroll
    for (int i = 0; i < CPK; ++i) {                // plane0/plane2 pairwise
        f32x4 acc0 = cc(i);
        f32x4 acc2 = cc(2 * CPK + i);
        const long rowoff = (long)(node0 + sub * 4) * LDZ + i * 16 + r16;
        #pragma unroll
        for (int r = 0; r < 4; ++r) {
            D02[rowoff + (long)r * LDZ] = f2bf(acc0[r] - acc2[r]);
            Z2out[rowoff + (long)r * LDZ] = f2bf(acc2[r]);
        }
    }
    #pragma unroll
    for (int i = 0; i < CPK; ++i) {                // plane1
        f32x4 acc1 = cc(CPK + i);
        const long rowoff = (long)(node0 + sub * 4) * LDZ + i * 16 + r16;
        #pragma unroll
        for (int r = 0; r < 4; ++r)
            Z1[rowoff + (long)r * LDZ] = f2bf(acc1[r]);
    }
}

// ============ merged passC + gemm1 ============

__global__ __launch_bounds__(256)
void passC_gemm1(const int* __restrict__ src, const int* __restrict__ dst,
                 const int* __restrict__ blk_off_src, const int* __restrict__ blk_off_dst,
                 const int* __restrict__ tot_src, const int* __restrict__ tot_dst,
                 u16* __restrict__ sorted_srconly, u32* __restrict__ sorted_pair,
                 const u16* __restrict__ xb, const u16* __restrict__ Pb1,
                 u16* __restrict__ D02, u16* __restrict__ Z1, u16* __restrict__ Zs) {
    __shared__ int s[512];
    __shared__ int cs[NBKT], cd[NBKT];
    const int t = threadIdx.x, blk = blockIdx.x;
    if (blk >= NBLK_E) {                           // ---- gemm1 blocks (no LDS use) ----
        const int tile = (blk - NBLK_E) * 4 + (t >> 6);
        if (tile * 16 >= N_NODES) return;
        gemm_body<D_IN, 192, HID, 4>(tile, t & 63, xb, Pb1, D02, Z1, Zs);
        return;
    }
    // ---- passC blocks ----
    for (int pass = 0; pass < 2; ++pass) {
        const int* tot = pass ? tot_src : tot_dst;
        const int* bo  = pass ? blk_off_src : blk_off_dst;
        int* cx = pass ? cs : cd;
        s[t]       = (t < NBKT) ? tot[t] : 0;
        s[t + 256] = (t + 256 < NBKT) ? tot[t + 256] : 0;
        __syncthreads();
        for (int off = 1; off < 512; off <<= 1) {
            int a1 = (t >= off) ? s[t - off] : 0;
            int a2 = (t + 256 >= off) ? s[t + 256 - off] : 0;
            __syncthreads();
            s[t] += a1; s[t + 256] += a2;
            __syncthreads();
        }
        if (t < NBKT) cx[t] = s[t] - tot[t] + bo[t * NBLK_E + blk];
        if (t + 256 < NBKT) cx[t + 256] = s[t + 256] - tot[t + 256] + bo[(t + 256) * NBLK_E + blk];
        __syncthreads();
    }
    const int e0 = blk * EPB;
    if (e0 + EPB <= N_EDGES) {                     // full block: 8 edges/thread, int4 loads
        const int base = e0 + t * 8;
        int4 s0 = *(const int4*)(src + base), s1 = *(const int4*)(src + base + 4);
        int4 d0 = *(const int4*)(dst + base), d1 = *(const int4*)(dst + base + 4);
        int sv[8] = {s0.x, s0.y, s0.z, s0.w, s1.x, s1.y, s1.z, s1.w};
        int dv[8] = {d0.x, d0.y, d0.z, d0.w, d1.x, d1.y, d1.z, d1.w};
        #pragma unroll
        for (int k = 0; k < 8; ++k) {
            int ps = atomicAdd(&cs[sv[k] >> BSHIFT], 1);
            sorted_srconly[ps] = (u16)sv[k];
            int pd = atomicAdd(&cd[dv[k] >> BSHIFT], 1);
            sorted_pair[pd] = ((u32)dv[k] << 16) | (u32)sv[k];
        }
    } else {
        for (int e = e0 + t; e < N_EDGES; e += 256) {
            int sv = src[e], dv = dst[e];
            int ps = atomicAdd(&cs[sv >> BSHIFT], 1);
            sorted_srconly[ps] = (u16)sv;
            int pd = atomicAdd(&cd[dv >> BSHIFT], 1);
            sorted_pair[pd] = ((u32)dv << 16) | (u32)sv;
        }
    }
}

// passD: merged Dsrc (deg->dis + in-place Zs scaling) + Ddst (fine CSR).
__global__ __launch_bounds__(256)
void passD(const int* __restrict__ tot_src, const u16* __restrict__ sorted_srconly,
           const int* __restrict__ tot_dst, const u32* __restrict__ sorted_pair,
           float* __restrict__ dis, int* __restrict__ row_ptr, u16* __restrict__ wsrc,
           u16* __restrict__ Zs) {
    __shared__ int sred[256];
    __shared__ int hist[128];
    __shared__ int cur[128];
    __shared__ float s_dis[128];
    __shared__ u32 s_p[DCAP];
    const int t = threadIdx.x;
    const bool isSrc = blockIdx.x < NBKT;
    const int b = isSrc ? blockIdx.x : blockIdx.x - NBKT;
    const int* tot = isSrc ? tot_src : tot_dst;
    int part = 0;
    for (int i = t; i < b; i += 256) part += tot[i];
    sred[t] = part;
    if (t < 128) hist[t] = 0;
    __syncthreads();
    #pragma unroll
    for (int off = 128; off > 0; off >>= 1) {
        if (t < off) sred[t] += sred[t + off];
        __syncthreads();
    }
    const int eb = sred[0];
    const int ee = eb + tot[b];
    if (isSrc) {                                   // ---- Dsrc half ----
        for (int i = eb + t; i < ee; i += 256)
            atomicAdd(&hist[sorted_srconly[i] & 127], 1);
        __syncthreads();
        const int node0 = b << BSHIFT;
        if (t < 128) {
            int c = hist[t];
            float dv = c > 0 ? rsqrtf((float)c) : 0.0f;
            s_dis[t] = dv;
            if (node0 + t < N_NODES) dis[node0 + t] = dv;
        }
        __syncthreads();
        for (int c = t; c < 128 * 8; c += 256) {   // in-place scale Zs *= dis
            int ln = c >> 3, off8 = (c & 7) * 8;
            int n = node0 + ln;
            if (n >= N_NODES) continue;
            float dv = s_dis[ln];
            u16* zp = Zs + (long)n * HID + off8;
            uint4 q = *(uint4*)zp;
            uint4 r;
            r.x = pack2(bflo(q.x) * dv, bfhi(q.x) * dv);
            r.y = pack2(bflo(q.y) * dv, bfhi(q.y) * dv);
            r.z = pack2(bflo(q.z) * dv, bfhi(q.z) * dv);
            r.w = pack2(bflo(q.w) * dv, bfhi(q.w) * dv);
            *(uint4*)zp = r;
        }
        return;
    }
    // ---- Ddst half ----
    if (b == 0 && t == 0) row_ptr[N_NODES] = N_EDGES;
    const int cnt = ee - eb;
    const int stage = cnt < DCAP ? cnt : DCAP;
    for (int i = t; i < stage; i += 256) {
        u32 v = sorted_pair[eb + i];
        s_p[i] = v;
        atomicAdd(&hist[(v >> 16) & 127], 1);
    }
    for (int i = stage + t; i < cnt; i += 256)
        atomicAdd(&hist[(sorted_pair[eb + i] >> 16) & 127], 1);
    __syncthreads();
    if (t < 64) {
        int v0 = hist[2 * t], v1 = hist[2 * t + 1];
        int p = v0 + v1;
        int incl = p;
        #pragma unroll
        for (int off = 1; off < 64; off <<= 1) {
            int x = __shfl_up(incl, off);
            if (t >= off) incl += x;
        }
        int excl = incl - p;
        cur[2 * t] = excl;
        cur[2 * t + 1] = excl + v0;
        int node = (b << BSHIFT) + 2 * t;
        if (node < N_NODES) row_ptr[node] = eb + excl;
        if (node + 1 < N_NODES) row_ptr[node + 1] = eb + excl + v0;
    }
    __syncthreads();
    for (int i = t; i < stage; i += 256) {
        u32 v = s_p[i];
        int slot = atomicAdd(&cur[(v >> 16) & 127], 1);
        wsrc[eb + slot] = (u16)(v & 0xFFFF);
    }
    for (int i = stage + t; i < cnt; i += 256) {
        u32 v = sorted_pair[eb + i];
        int slot = atomicAdd(&cur[(v >> 16) & 127], 1);
        wsrc[eb + slot] = (u16)(v & 0xFFFF);
    }
}

// ============ gather helpers ============

__device__ inline void sum8(float (&acc)[8], uint4 q) {
    acc[0] += bflo(q.x); acc[1] += bfhi(q.x);
    acc[2] += bflo(q.y); acc[3] += bfhi(q.y);
    acc[4] += bflo(q.z); acc[5] += bfhi(q.z);
    acc[6] += bflo(q.w); acc[7] += bfhi(q.w);
}

template<int F>
__device__ __forceinline__
void gather_loop(float (&acc)[8], const u16* s_p, const u16* ws, const u16* g,
                 int beg, int mid, int end, int stage, int ebeg, int c8) {
    int e = beg;
    for (; e + 8 <= mid; e += 8) {
        int p0 = s_p[e],     p1 = s_p[e + 1], p2 = s_p[e + 2], p3 = s_p[e + 3];
        int p4 = s_p[e + 4], p5 = s_p[e + 5], p6 = s_p[e + 6], p7 = s_p[e + 7];
        uint4 q0 = *(const uint4*)(g + (long)p0 * F + c8);
        uint4 q1 = *(const uint4*)(g + (long)p1 * F + c8);
        uint4 q2 = *(const uint4*)(g + (long)p2 * F + c8);
        uint4 q3 = *(const uint4*)(g + (long)p3 * F + c8);
        uint4 q4 = *(const uint4*)(g + (long)p4 * F + c8);
        uint4 q5 = *(const uint4*)(g + (long)p5 * F + c8);
        uint4 q6 = *(const uint4*)(g + (long)p6 * F + c8);
        uint4 q7 = *(const uint4*)(g + (long)p7 * F + c8);
        sum8(acc, q0); sum8(acc, q1); sum8(acc, q2); sum8(acc, q3);
        sum8(acc, q4); sum8(acc, q5); sum8(acc, q6); sum8(acc, q7);
    }
    for (; e + 4 <= mid; e += 4) {
        int p0 = s_p[e], p1 = s_p[e + 1], p2 = s_p[e + 2], p3 = s_p[e + 3];
        uint4 q0 = *(const uint4*)(g + (long)p0 * F + c8);
        uint4 q1 = *(const uint4*)(g + (long)p1 * F + c8);
        uint4 q2 = *(const uint4*)(g + (long)p2 * F + c8);
        uint4 q3 = *(const uint4*)(g + (long)p3 * F + c8);
        sum8(acc, q0); sum8(acc, q1); sum8(acc, q2); sum8(acc, q3);
    }
    for (; e < mid; ++e)
        sum8(acc, *(const uint4*)(g + (long)s_p[e] * F + c8));
    for (e = (beg > stage ? beg : stage); e < end; ++e)     // overflow fallback (rare)
        sum8(acc, *(const uint4*)(g + (long)ws[ebeg + e] * F + c8));
}

// ============ gather propagate (P1 / P3 / P4) ============
// EPI_S  : Ŝ  = dis_d*aux1 - 2*dis_d^2*acc           (aux1 = Z1; bf16 out)
// EPI_OUT: out = aux1 - dis_d*acc + bias              (aux1 = D02'; f32 out)

#define EPI_S 0
#define EPI_OUT 2

template<int F, int FS, int NPB, int CAP, int EPI>
__global__ __launch_bounds__(256)
void gather_prop(const int* __restrict__ row_ptr, const u16* __restrict__ ws,
                 const u16* __restrict__ g, const u16* __restrict__ aux1,
                 const float* __restrict__ bias, const float* __restrict__ dis,
                 void* __restrict__ outp) {
    static_assert(NPB * (FS / 8) == 256, "block geometry");
    constexpr int SPLIT = F / FS;
    __shared__ u16 s_p[CAP];
    __shared__ int s_beg[NPB + 1];
    const int tid = threadIdx.x;
    const int nodeblk = blockIdx.x / SPLIT;
    const int half = blockIdx.x % SPLIT;
    const int node0 = nodeblk * NPB;
    if (tid <= NPB) {
        int n = node0 + tid;
        s_beg[tid] = row_ptr[n > N_NODES ? N_NODES : n];
    }
    __syncthreads();
    const int ebeg = s_beg[0];
    const int cnt = s_beg[NPB] - ebeg;
    const int stage = cnt < CAP ? cnt : CAP;
    for (int e = tid; e < stage; e += 256)
        s_p[e] = ws[ebeg + e];
    __syncthreads();
    constexpr int CPN = FS / 8;
    const int nl = tid / CPN;
    const int node = node0 + nl;
    if (node >= N_NODES) return;
    const int c8 = (tid % CPN) * 8 + half * FS;
    float acc[8];
    #pragma unroll
    for (int j = 0; j < 8; ++j) acc[j] = 0.0f;
    const int beg = s_beg[nl] - ebeg;
    const int end = s_beg[nl + 1] - ebeg;
    const int mid = end < stage ? end : stage;
    gather_loop<F>(acc, s_p, ws, g, beg, mid, end, stage, ebeg, c8);
    const float dd = dis[node];
    if (EPI == EPI_S) {
        const float m1 = dd, m2 = -2.0f * dd * dd;
        const uint4 z1 = *(const uint4*)(aux1 + (long)node * F + c8);
        uint4 r;
        r.x = pack2(fmaf(m1, bflo(z1.x), m2 * acc[0]), fmaf(m1, bfhi(z1.x), m2 * acc[1]));
        r.y = pack2(fmaf(m1, bflo(z1.y), m2 * acc[2]), fmaf(m1, bfhi(z1.y), m2 * acc[3]));
        r.z = pack2(fmaf(m1, bflo(z1.z), m2 * acc[4]), fmaf(m1, bfhi(z1.z), m2 * acc[5]));
        r.w = pack2(fmaf(m1, bflo(z1.w), m2 * acc[6]), fmaf(m1, bfhi(z1.w), m2 * acc[7]));
        *(uint4*)((u16*)outp + (long)node * F + c8) = r;
    } else {
        const uint4 z0 = *(const uint4*)(aux1 + (long)node * F + c8);
        const float* bb = bias + c8;
        float v0 = bflo(z0.x) - dd * acc[0] + bb[0];
        float v1 = bfhi(z0.x) - dd * acc[1] + bb[1];
        float v2 = bflo(z0.y) - dd * acc[2] + bb[2];
        float v3 = bfhi(z0.y) - dd * acc[3] + bb[3];
        float v4 = bflo(z0.z) - dd * acc[4] + bb[4];
        float v5 = bfhi(z0.z) - dd * acc[5] + bb[5];
        float v6 = bflo(z0.w) - dd * acc[6] + bb[6];
        float v7 = bfhi(z0.w) - dd * acc[7] + bb[7];
        float* op = (float*)outp + (long)node * F + c8;
        *(float4*)op = make_float4(v0, v1, v2, v3);
        *(float4*)(op + 4) = make_float4(v4, v5, v6, v7);
    }
}

// ============ fused P2 + gemm2 (W2 fragments direct from global) ============

__global__ __launch_bounds__(256)
void prop2_gemm2(const int* __restrict__ row_ptr, const u16* __restrict__ ws,
                 const u16* __restrict__ S, const u16* __restrict__ D02,
                 const float* __restrict__ b1, const float* __restrict__ dis,
                 const u16* __restrict__ Pb2,
                 u16* __restrict__ D02p, u16* __restrict__ Z1p, u16* __restrict__ Zsp) {
    constexpr int NPB = 32, CAP = 1280;
    __shared__ u16 s_p[CAP];
    __shared__ int s_beg[NPB + 1];
    __shared__ u16 h_tile[NPB][HID + 8];           // +8 pad: break 128B-stride banks
    const int tid = threadIdx.x;
    const int node0 = blockIdx.x * NPB;
    if (tid <= NPB) {
        int n = node0 + tid;
        s_beg[tid] = row_ptr[n > N_NODES ? N_NODES : n];
    }
    __syncthreads();
    const int ebeg = s_beg[0];
    const int cnt = s_beg[NPB] - ebeg;
    const int stage = cnt < CAP ? cnt : CAP;
    for (int e = tid; e < stage; e += 256)
        s_p[e] = ws[ebeg + e];
    __syncthreads();
    const int nl = tid >> 3;                       // CPN = 8
    const int node = node0 + nl;
    const int c8 = (tid & 7) * 8;
    if (node < N_NODES) {                          // NO early return (barrier below)
        float acc[8];
        #pragma unroll
        for (int j = 0; j < 8; ++j) acc[j] = 0.0f;
        const int beg = s_beg[nl] - ebeg;
        const int end = s_beg[nl + 1] - ebeg;
        const int mid = end < stage ? end : stage;
        gather_loop<HID>(acc, s_p, ws, S, beg, mid, end, stage, ebeg, c8);
        const float dd = dis[node];
        const uint4 z0 = *(const uint4*)(D02 + (long)node * HID + c8);
        const float* bb = b1 + c8;
        float v0 = bflo(z0.x) - dd * acc[0] + bb[0];
        float v1 = bfhi(z0.x) - dd * acc[1] + bb[1];
        float v2 = bflo(z0.y) - dd * acc[2] + bb[2];
        float v3 = bfhi(z0.y) - dd * acc[3] + bb[3];
        float v4 = bflo(z0.z) - dd * acc[4] + bb[4];
        float v5 = bfhi(z0.z) - dd * acc[5] + bb[5];
        float v6 = bflo(z0.w) - dd * acc[6] + bb[6];
        float v7 = bfhi(z0.w) - dd * acc[7] + bb[7];
        uint4 r;
        r.x = pack2(fmaxf(v0, 0.f), fmaxf(v1, 0.f));
        r.y = pack2(fmaxf(v2, 0.f), fmaxf(v3, 0.f));
        r.z = pack2(fmaxf(v4, 0.f), fmaxf(v5, 0.f));
        r.w = pack2(fmaxf(v6, 0.f), fmaxf(v7, 0.f));
        *(uint4*)&h_tile[nl][c8] = r;
    }
    __syncthreads();
    // ---- gemm2 from LDS h_tile: waves 0,1 handle the block's two 16-node tiles ----
    const int w = tid >> 6;
    if (w >= 2) return;
    const int tile = blockIdx.x * 2 + w;
    if (tile * 16 >= N_NODES) return;
    const int lane = tid & 63;
    const int sub = lane >> 4, r16 = lane & 15;
    const int gnode0 = tile * 16;
    float dis4[4];
    #pragma unroll
    for (int r = 0; r < 4; ++r) dis4[r] = dis[gnode0 + sub * 4 + r];
    bf16x8 a[2];
    const u16* ar = &h_tile[w * 16 + r16][sub * 8];
    a[0] = *(const bf16x8*)(ar);
    a[1] = *(const bf16x8*)(ar + 32);
    auto cc = [&](int ct) {
        f32x4 acc = {0.f, 0.f, 0.f, 0.f};
        #pragma unroll
        for (int kt = 0; kt < 2; ++kt) {
            bf16x8 bfr = *(const bf16x8*)&Pb2[((kt * 4 + sub) * 48 + ct * 16 + r16) * 8];
            acc = __builtin_amdgcn_mfma_f32_16x16x32_bf16(a[kt], bfr, acc, 0, 0, 0);
        }
        return acc;
    };
    f32x4 acc0 = cc(0);
    f32x4 acc2 = cc(2);
    f32x4 acc1 = cc(1);
    const long rowoff = (long)(gnode0 + sub * 4) * D_OUT + r16;
    #pragma unroll
    for (int r = 0; r < 4; ++r) {
        D02p[rowoff + (long)r * D_OUT] = f2bf(acc0[r] - acc2[r]);
        Zsp[rowoff + (long)r * D_OUT]  = f2bf(acc2[r] * dis4[r]);
        Z1p[rowoff + (long)r * D_OUT]  = f2bf(acc1[r]);
    }
}

// ============ launch ============

extern "C" void kernel_launch(void* const* d_in, const int* in_sizes, int n_in,
                              void* d_out, int out_size, void* d_ws, size_t ws_size,
                              hipStream_t stream) {
    const float* x  = (const float*)d_in[0];
    const int*   ei = (const int*)d_in[1];
    const float* W1 = (const float*)d_in[2];
    const float* b1 = (const float*)d_in[3];
    const float* W2 = (const float*)d_in[4];
    const float* b2 = (const float*)d_in[5];
    const int* src = ei;
    const int* dst = ei + N_EDGES;

    // ---- workspace (sections aligned; u16 region starts 16B-aligned) ----
    float* dis          = (float*)d_ws;                      // 50000
    int*   row_ptr      = (int*)(dis + N_NODES);             // 50016
    int*   blk_cnt_src  = row_ptr + 50016;                   // 152896
    int*   blk_cnt_dst  = blk_cnt_src + 152896;              // 152896
    int*   tot_src      = blk_cnt_dst + 152896;              // 512
    int*   tot_dst      = tot_src + 512;                     // 512
    u16*   srconly      = (u16*)(tot_dst + 512);             // E u16
    u32*   sorted_pair  = (u32*)(srconly + N_EDGES);         // E u32
    u16*   wsrc         = (u16*)(sorted_pair + N_EDGES);     // E u16
    u16*   D02          = wsrc + N_EDGES;                    // N*64  (Z0 - Z2)
    u16*   Z1b          = D02 + (long)N_NODES * HID;         // N*64
    u16*   Zs           = Z1b + (long)N_NODES * HID;         // N*64  (Z2, scaled in passD)
    u16*   S            = Zs  + (long)N_NODES * HID;         // N*64  (Ŝ, pre-scaled)
    u16*   D02p         = S   + (long)N_NODES * HID;         // N*16
    u16*   Z1p          = D02p + (long)N_NODES * D_OUT;      // N*16
    u16*   Zsp          = Z1p  + (long)N_NODES * D_OUT;      // N*16
    u16*   Sp           = Zsp  + (long)N_NODES * D_OUT;      // N*16
    u16*   Pb1          = Sp   + (long)N_NODES * D_OUT;      // 18432
    u16*   Pb2          = Pb1 + 18432;                       // 3072
    u16*   xb           = Pb2 + 3072;                        // N*96 bf16 x

    // ---- build + layer-1 GEMM (gemm1 overlapped with passC) ----
    passA<<<NBLK_E + PACK_BLKS + CVT_BLKS, 256, 0, stream>>>(
        src, dst, blk_cnt_src, blk_cnt_dst, W1, W2, Pb1, Pb2, x, xb);
    passB<<<2 * NBKT, 64, 0, stream>>>(blk_cnt_src, blk_cnt_dst, tot_src, tot_dst);
    passC_gemm1<<<NBLK_E + GEMM1_BLKS, 256, 0, stream>>>(
        src, dst, blk_cnt_src, blk_cnt_dst, tot_src, tot_dst,
        srconly, sorted_pair, xb, Pb1, D02, Z1b, Zs);
    passD<<<2 * NBKT, 256, 0, stream>>>(tot_src, srconly, tot_dst, sorted_pair,
                                        dis, row_ptr, wsrc, Zs);

    // ---- layer 1: P1 (split), then fused P2+gemm2 ----
    gather_prop<HID, 32, 64, 1536, EPI_S><<<2 * ((N_NODES + 63) / 64), 256, 0, stream>>>(
        row_ptr, wsrc, Zs, Z1b, nullptr, dis, S);
    prop2_gemm2<<<(N_NODES + 31) / 32, 256, 0, stream>>>(
        row_ptr, wsrc, S, D02, b1, dis, Pb2, D02p, Z1p, Zsp);

    // ---- layer 2 props ----
    gather_prop<D_OUT, 16, 128, 3072, EPI_S><<<(N_NODES + 127) / 128, 256, 0, stream>>>(
        row_ptr, wsrc, Zsp, Z1p, nullptr, dis, Sp);
    gather_prop<D_OUT, 16, 128, 3072, EPI_OUT><<<(N_NODES + 127) / 128, 256, 0, stream>>>(
        row_ptr, wsrc, Sp, D02p, b2, dis, (float*)d_out);
}

// Round 17
// 106.599 us; speedup vs baseline: 1.4722x; 1.0325x over previous
//
#include <hip/hip_runtime.h>

#define N_NODES 50000
#define N_EDGES 800000
#define D_IN 96
#define HID 64
#define D_OUT 16

#define EPB 2048                                   // edges per block (passes A/C)
#define NBLK_E ((N_EDGES + EPB - 1) / EPB)         // 391
#define BSHIFT 7                                   // 128 nodes per bucket
#define NBKT ((N_NODES + 127) / 128)               // 391
#define DCAP 2560                                  // Ddst LDS edge staging cap (u32)
#define PACK_TOT (3 * D_IN * HID + 3 * HID * D_OUT)   // 21504
#define PACK_BLKS (PACK_TOT / 256)                 // 84
#define CVT_N (N_NODES * D_IN)                     // 4800000
#define CVT_BLKS ((CVT_N / 8 + 255) / 256)         // 2344
#define GEMM1_BLKS ((N_NODES / 16 + 3) / 4)        // 782

typedef unsigned short u16;
typedef unsigned int u32;
typedef __attribute__((ext_vector_type(4))) float f32x4;
typedef __attribute__((ext_vector_type(8))) short bf16x8;

__device__ inline float bflo(u32 v) { union { u32 i; float f; } u; u.i = v << 16; return u.f; }
__device__ inline float bfhi(u32 v) { union { u32 i; float f; } u; u.i = v & 0xffff0000u; return u.f; }
__device__ inline u16 f2bf(float f) {              // RTNE
    union { float f; u32 i; } u; u.f = f;
    return (u16)((u.i + 0x7fffu + ((u.i >> 16) & 1u)) >> 16);
}
__device__ inline u32 pack2(float lo, float hi) {
    return (u32)f2bf(lo) | ((u32)f2bf(hi) << 16);
}

// ============ passA: coarse histograms + weight pack + x->bf16 convert ============

__global__ __launch_bounds__(256)
void passA(const int* __restrict__ src, const int* __restrict__ dst,
           int* __restrict__ blk_cnt_src, int* __restrict__ blk_cnt_dst,
           const float* __restrict__ W1, const float* __restrict__ W2,
           u16* __restrict__ Pb1, u16* __restrict__ Pb2,
           const float* __restrict__ x, u16* __restrict__ xb) {
    const int t = threadIdx.x, blk = blockIdx.x;
    if (blk >= NBLK_E + PACK_BLKS) {               // ---- x convert blocks ----
        long idx8 = ((long)(blk - NBLK_E - PACK_BLKS) * 256 + t) * 8;
        if (idx8 < CVT_N) {
            float4 a0 = *(const float4*)(x + idx8);
            float4 a1 = *(const float4*)(x + idx8 + 4);
            uint4 r;
            r.x = pack2(a0.x, a0.y); r.y = pack2(a0.z, a0.w);
            r.z = pack2(a1.x, a1.y); r.w = pack2(a1.z, a1.w);
            *(uint4*)(xb + idx8) = r;
        }
        return;
    }
    if (blk >= NBLK_E) {                           // ---- weight-pack blocks ----
        int tt = (blk - NBLK_E) * 256 + t;
        if (tt < 3 * D_IN * HID) {                 // 18432: K=96, NC=192, OUTW=64
            int j = tt & 7, rest = tt >> 3;
            int c = rest % 192, i = (rest / 192) * 8 + j;
            int kc = c / 64, o = c % 64;
            Pb1[tt] = f2bf(W1[((long)kc * D_IN + i) * HID + o]);
        } else if (tt < PACK_TOT) {
            int t2 = tt - 3 * D_IN * HID;          // 3072: K=64, NC=48, OUTW=16
            int j = t2 & 7, rest = t2 >> 3;
            int c = rest % 48, i = (rest / 48) * 8 + j;
            int kc = c / 16, o = c % 16;
            Pb2[t2] = f2bf(W2[((long)kc * HID + i) * D_OUT + o]);
        }
        return;
    }
    // ---- histogram blocks ----
    __shared__ int hs[NBKT], hd[NBKT];
    for (int i = t; i < NBKT; i += 256) { hs[i] = 0; hd[i] = 0; }
    __syncthreads();
    const int e0 = blk * EPB;
    if (e0 + EPB <= N_EDGES) {                     // full block: 8 edges/thread, int4 loads
        const int base = e0 + t * 8;
        int4 s0 = *(const int4*)(src + base), s1 = *(const int4*)(src + base + 4);
        int4 d0 = *(const int4*)(dst + base), d1 = *(const int4*)(dst + base + 4);
        atomicAdd(&hs[s0.x >> BSHIFT], 1); atomicAdd(&hs[s0.y >> BSHIFT], 1);
        atomicAdd(&hs[s0.z >> BSHIFT], 1); atomicAdd(&hs[s0.w >> BSHIFT], 1);
        atomicAdd(&hs[s1.x >> BSHIFT], 1); atomicAdd(&hs[s1.y >> BSHIFT], 1);
        atomicAdd(&hs[s1.z >> BSHIFT], 1); atomicAdd(&hs[s1.w >> BSHIFT], 1);
        atomicAdd(&hd[d0.x >> BSHIFT], 1); atomicAdd(&hd[d0.y >> BSHIFT], 1);
        atomicAdd(&hd[d0.z >> BSHIFT], 1); atomicAdd(&hd[d0.w >> BSHIFT], 1);
        atomicAdd(&hd[d1.x >> BSHIFT], 1); atomicAdd(&hd[d1.y >> BSHIFT], 1);
        atomicAdd(&hd[d1.z >> BSHIFT], 1); atomicAdd(&hd[d1.w >> BSHIFT], 1);
    } else {                                       // tail block
        for (int e = e0 + t; e < N_EDGES; e += 256) {
            atomicAdd(&hs[src[e] >> BSHIFT], 1);
            atomicAdd(&hd[dst[e] >> BSHIFT], 1);
        }
    }
    __syncthreads();
    for (int b = t; b < NBKT; b += 256) {
        blk_cnt_src[b * NBLK_E + blk] = hs[b];
        blk_cnt_dst[b * NBLK_E + blk] = hd[b];
    }
}

// passB: per-bucket exclusive scan over the block dimension (in place), emit totals.
__global__ __launch_bounds__(64)
void passB(int* __restrict__ blk_cnt_src, int* __restrict__ blk_cnt_dst,
           int* __restrict__ tot_src, int* __restrict__ tot_dst) {
    const int b = blockIdx.x;
    int* cnt; int* tot;
    if (b < NBKT) { cnt = blk_cnt_dst + b * NBLK_E;          tot = tot_dst + b; }
    else          { cnt = blk_cnt_src + (b - NBKT) * NBLK_E; tot = tot_src + (b - NBKT); }
    const int lane = threadIdx.x;
    int carry = 0;
    for (int base0 = 0; base0 < NBLK_E; base0 += 64) {
        int i = base0 + lane;
        int v = (i < NBLK_E) ? cnt[i] : 0;
        int incl = v;
        #pragma unroll
        for (int off = 1; off < 64; off <<= 1) {
            int x = __shfl_up(incl, off);
            if (lane >= off) incl += x;
        }
        if (i < NBLK_E) cnt[i] = carry + incl - v;
        carry += __shfl(incl, 63);
    }
    if (lane == 0) *tot = carry;
}

// ============ gemm body (bf16 A; B-fragments direct from global) ============

template<int K, int NC, int LDZ, int CPK>
__device__ __forceinline__
void gemm_body(int tile, int lane, const u16* __restrict__ A, const u16* __restrict__ P,
               u16* __restrict__ D02, u16* __restrict__ Z1, u16* __restrict__ Z2out) {
    constexpr int KT = K / 32;
    const int node0 = tile * 16;
    const int sub = lane >> 4, r16 = lane & 15;
    bf16x8 a[KT];
    const u16* ar = A + (long)(node0 + r16) * K + sub * 8;
    #pragma unroll
    for (int kt = 0; kt < KT; ++kt)
        a[kt] = *(const bf16x8*)(ar + kt * 32);
    auto cc = [&](int ct) {
        f32x4 acc = {0.f, 0.f, 0.f, 0.f};
        #pragma unroll
        for (int kt = 0; kt < KT; ++kt) {
            bf16x8 bfr = *(const bf16x8*)&P[((kt * 4 + sub) * NC + ct * 16 + r16) * 8];
            acc = __builtin_amdgcn_mfma_f32_16x16x32_bf16(a[kt], bfr, acc, 0, 0, 0);
        }
        return acc;
    };
    #pragma unroll
    for (int i = 0; i < CPK; ++i) {                // plane0/plane2 pairwise
        f32x4 acc0 = cc(i);
        f32x4 acc2 = cc(2 * CPK + i);
        const long rowoff = (long)(node0 + sub * 4) * LDZ + i * 16 + r16;
        #pragma unroll
        for (int r = 0; r < 4; ++r) {
            D02[rowoff + (long)r * LDZ] = f2bf(acc0[r] - acc2[r]);
            Z2out[rowoff + (long)r * LDZ] = f2bf(acc2[r]);
        }
    }
    #pragma unroll
    for (int i = 0; i < CPK; ++i) {                // plane1
        f32x4 acc1 = cc(CPK + i);
        const long rowoff = (long)(node0 + sub * 4) * LDZ + i * 16 + r16;
        #pragma unroll
        for (int r = 0; r < 4; ++r)
            Z1[rowoff + (long)r * LDZ] = f2bf(acc1[r]);
    }
}

// ============ merged passC + gemm1 ============

__global__ __launch_bounds__(256)
void passC_gemm1(const int* __restrict__ src, const int* __restrict__ dst,
                 const int* __restrict__ blk_off_src, const int* __restrict__ blk_off_dst,
                 const int* __restrict__ tot_src, const int* __restrict__ tot_dst,
                 u16* __restrict__ sorted_srconly, u32* __restrict__ sorted_pair,
                 const u16* __restrict__ xb, const u16* __restrict__ Pb1,
                 u16* __restrict__ D02, u16* __restrict__ Z1, u16* __restrict__ Zs) {
    __shared__ int s[512];
    __shared__ int cs[NBKT], cd[NBKT];
    const int t = threadIdx.x, blk = blockIdx.x;
    if (blk >= NBLK_E) {                           // ---- gemm1 blocks (no LDS use) ----
        const int tile = (blk - NBLK_E) * 4 + (t >> 6);
        if (tile * 16 >= N_NODES) return;
        gemm_body<D_IN, 192, HID, 4>(tile, t & 63, xb, Pb1, D02, Z1, Zs);
        return;
    }
    // ---- passC blocks ----
    for (int pass = 0; pass < 2; ++pass) {
        const int* tot = pass ? tot_src : tot_dst;
        const int* bo  = pass ? blk_off_src : blk_off_dst;
        int* cx = pass ? cs : cd;
        s[t]       = (t < NBKT) ? tot[t] : 0;
        s[t + 256] = (t + 256 < NBKT) ? tot[t + 256] : 0;
        __syncthreads();
        for (int off = 1; off < 512; off <<= 1) {
            int a1 = (t >= off) ? s[t - off] : 0;
            int a2 = (t + 256 >= off) ? s[t + 256 - off] : 0;
            __syncthreads();
            s[t] += a1; s[t + 256] += a2;
            __syncthreads();
        }
        if (t < NBKT) cx[t] = s[t] - tot[t] + bo[t * NBLK_E + blk];
        if (t + 256 < NBKT) cx[t + 256] = s[t + 256] - tot[t + 256] + bo[(t + 256) * NBLK_E + blk];
        __syncthreads();
    }
    const int e0 = blk * EPB;
    if (e0 + EPB <= N_EDGES) {                     // full block: 8 edges/thread, int4 loads
        const int base = e0 + t * 8;
        int4 s0 = *(const int4*)(src + base), s1 = *(const int4*)(src + base + 4);
        int4 d0 = *(const int4*)(dst + base), d1 = *(const int4*)(dst + base + 4);
        int sv[8] = {s0.x, s0.y, s0.z, s0.w, s1.x, s1.y, s1.z, s1.w};
        int dv[8] = {d0.x, d0.y, d0.z, d0.w, d1.x, d1.y, d1.z, d1.w};
        #pragma unroll
        for (int k = 0; k < 8; ++k) {
            int ps = atomicAdd(&cs[sv[k] >> BSHIFT], 1);
            sorted_srconly[ps] = (u16)sv[k];
            int pd = atomicAdd(&cd[dv[k] >> BSHIFT], 1);
            sorted_pair[pd] = ((u32)dv[k] << 16) | (u32)sv[k];
        }
    } else {
        for (int e = e0 + t; e < N_EDGES; e += 256) {
            int sv = src[e], dv = dst[e];
            int ps = atomicAdd(&cs[sv >> BSHIFT], 1);
            sorted_srconly[ps] = (u16)sv;
            int pd = atomicAdd(&cd[dv >> BSHIFT], 1);
            sorted_pair[pd] = ((u32)dv << 16) | (u32)sv;
        }
    }
}

// passD: merged Dsrc (deg->dis + in-place Zs scaling) + Ddst (fine CSR).
// Ddst stages sorted_pair via skew-aligned uint4 (4 records / 16B load).
__global__ __launch_bounds__(256)
void passD(const int* __restrict__ tot_src, const u16* __restrict__ sorted_srconly,
           const int* __restrict__ tot_dst, const u32* __restrict__ sorted_pair,
           float* __restrict__ dis, int* __restrict__ row_ptr, u16* __restrict__ wsrc,
           u16* __restrict__ Zs) {
    __shared__ int sred[256];
    __shared__ int hist[128];
    __shared__ int cur[128];
    __shared__ float s_dis[128];
    __shared__ __align__(16) u32 s_p[DCAP];
    const int t = threadIdx.x;
    const bool isSrc = blockIdx.x < NBKT;
    const int b = isSrc ? blockIdx.x : blockIdx.x - NBKT;
    const int* tot = isSrc ? tot_src : tot_dst;
    int part = 0;
    for (int i = t; i < b; i += 256) part += tot[i];
    sred[t] = part;
    if (t < 128) hist[t] = 0;
    __syncthreads();
    #pragma unroll
    for (int off = 128; off > 0; off >>= 1) {
        if (t < off) sred[t] += sred[t + off];
        __syncthreads();
    }
    const int eb = sred[0];
    const int ee = eb + tot[b];
    if (isSrc) {                                   // ---- Dsrc half ----
        for (int i = eb + t; i < ee; i += 256)
            atomicAdd(&hist[sorted_srconly[i] & 127], 1);
        __syncthreads();
        const int node0 = b << BSHIFT;
        if (t < 128) {
            int c = hist[t];
            float dv = c > 0 ? rsqrtf((float)c) : 0.0f;
            s_dis[t] = dv;
            if (node0 + t < N_NODES) dis[node0 + t] = dv;
        }
        __syncthreads();
        for (int c = t; c < 128 * 8; c += 256) {   // in-place scale Zs *= dis
            int ln = c >> 3, off8 = (c & 7) * 8;
            int n = node0 + ln;
            if (n >= N_NODES) continue;
            float dv = s_dis[ln];
            u16* zp = Zs + (long)n * HID + off8;
            uint4 q = *(uint4*)zp;
            uint4 r;
            r.x = pack2(bflo(q.x) * dv, bfhi(q.x) * dv);
            r.y = pack2(bflo(q.y) * dv, bfhi(q.y) * dv);
            r.z = pack2(bflo(q.z) * dv, bfhi(q.z) * dv);
            r.w = pack2(bflo(q.w) * dv, bfhi(q.w) * dv);
            *(uint4*)zp = r;
        }
        return;
    }
    // ---- Ddst half (vector-staged) ----
    if (b == 0 && t == 0) row_ptr[N_NODES] = N_EDGES;
    const int cnt = ee - eb;
    const int skew = eb & 3;
    const int gb = eb - skew;                      // aligned base (element index)
    const int tot4 = skew + cnt;
    int nv = (tot4 + 3) >> 2;
    if (nv > (DCAP >> 2)) nv = DCAP >> 2;
    for (int i = t; i < nv; i += 256)
        *(uint4*)&s_p[i * 4] = *(const uint4*)(sorted_pair + gb + i * 4);
    __syncthreads();
    const int lstage = nv * 4;                     // locals [0,lstage) staged
    const int lbeg = skew, lend = skew + cnt;
    const int lmid = lend < lstage ? lend : lstage;
    for (int l = lbeg + t; l < lmid; l += 256)
        atomicAdd(&hist[(s_p[l] >> 16) & 127], 1);
    for (int l = (lbeg > lstage ? lbeg : lstage) + t; l < lend; l += 256)
        atomicAdd(&hist[(sorted_pair[gb + l] >> 16) & 127], 1);
    __syncthreads();
    if (t < 64) {
        int v0 = hist[2 * t], v1 = hist[2 * t + 1];
        int p = v0 + v1;
        int incl = p;
        #pragma unroll
        for (int off = 1; off < 64; off <<= 1) {
            int x = __shfl_up(incl, off);
            if (t >= off) incl += x;
        }
        int excl = incl - p;
        cur[2 * t] = excl;
        cur[2 * t + 1] = excl + v0;
        int node = (b << BSHIFT) + 2 * t;
        if (node < N_NODES) row_ptr[node] = eb + excl;
        if (node + 1 < N_NODES) row_ptr[node + 1] = eb + excl + v0;
    }
    __syncthreads();
    for (int l = lbeg + t; l < lmid; l += 256) {
        u32 v = s_p[l];
        int slot = atomicAdd(&cur[(v >> 16) & 127], 1);
        wsrc[eb + slot] = (u16)(v & 0xFFFF);
    }
    for (int l = (lbeg > lstage ? lbeg : lstage) + t; l < lend; l += 256) {
        u32 v = sorted_pair[gb + l];
        int slot = atomicAdd(&cur[(v >> 16) & 127], 1);
        wsrc[eb + slot] = (u16)(v & 0xFFFF);
    }
}

// ============ gather helpers ============

__device__ inline void sum8(float (&acc)[8], uint4 q) {
    acc[0] += bflo(q.x); acc[1] += bfhi(q.x);
    acc[2] += bflo(q.y); acc[3] += bfhi(q.y);
    acc[4] += bflo(q.z); acc[5] += bfhi(q.z);
    acc[6] += bflo(q.w); acc[7] += bfhi(q.w);
}

template<int F>
__device__ __forceinline__
void gather_loop(float (&acc)[8], const u16* s_p, const u16* ws, const u16* g,
                 int beg, int mid, int end, int stage, int gb, int c8) {
    int e = beg;
    for (; e + 8 <= mid; e += 8) {
        int p0 = s_p[e],     p1 = s_p[e + 1], p2 = s_p[e + 2], p3 = s_p[e + 3];
        int p4 = s_p[e + 4], p5 = s_p[e + 5], p6 = s_p[e + 6], p7 = s_p[e + 7];
        uint4 q0 = *(const uint4*)(g + (long)p0 * F + c8);
        uint4 q1 = *(const uint4*)(g + (long)p1 * F + c8);
        uint4 q2 = *(const uint4*)(g + (long)p2 * F + c8);
        uint4 q3 = *(const uint4*)(g + (long)p3 * F + c8);
        uint4 q4 = *(const uint4*)(g + (long)p4 * F + c8);
        uint4 q5 = *(const uint4*)(g + (long)p5 * F + c8);
        uint4 q6 = *(const uint4*)(g + (long)p6 * F + c8);
        uint4 q7 = *(const uint4*)(g + (long)p7 * F + c8);
        sum8(acc, q0); sum8(acc, q1); sum8(acc, q2); sum8(acc, q3);
        sum8(acc, q4); sum8(acc, q5); sum8(acc, q6); sum8(acc, q7);
    }
    for (; e + 4 <= mid; e += 4) {
        int p0 = s_p[e], p1 = s_p[e + 1], p2 = s_p[e + 2], p3 = s_p[e + 3];
        uint4 q0 = *(const uint4*)(g + (long)p0 * F + c8);
        uint4 q1 = *(const uint4*)(g + (long)p1 * F + c8);
        uint4 q2 = *(const uint4*)(g + (long)p2 * F + c8);
        uint4 q3 = *(const uint4*)(g + (long)p3 * F + c8);
        sum8(acc, q0); sum8(acc, q1); sum8(acc, q2); sum8(acc, q3);
    }
    for (; e < mid; ++e)
        sum8(acc, *(const uint4*)(g + (long)s_p[e] * F + c8));
    for (e = (beg > stage ? beg : stage); e < end; ++e)     // overflow fallback (rare)
        sum8(acc, *(const uint4*)(g + (long)ws[gb + e] * F + c8));
}

// Skew-aligned u16 staging: stage ws[gb + 0 .. nv*8) into s_p[0 .. nv*8), gb = ebeg & ~7.
// Returns nv*8 (staged local bound). Local index l <-> global gb + l.
template<int CAP>
__device__ __forceinline__
int stage_u16(u16* s_p, const u16* __restrict__ ws, int gb, int tot, int tid) {
    int nv = (tot + 7) >> 3;
    if (nv > (CAP >> 3)) nv = CAP >> 3;
    for (int i = tid; i < nv; i += 256)
        *(uint4*)&s_p[i * 8] = *(const uint4*)(ws + gb + i * 8);
    return nv * 8;
}

// ============ gather propagate (P1 / P3 / P4) ============
// EPI_S  : Ŝ  = dis_d*aux1 - 2*dis_d^2*acc           (aux1 = Z1; bf16 out)
// EPI_OUT: out = aux1 - dis_d*acc + bias              (aux1 = D02'; f32 out)

#define EPI_S 0
#define EPI_OUT 2

template<int F, int FS, int NPB, int CAP, int EPI>
__global__ __launch_bounds__(256)
void gather_prop(const int* __restrict__ row_ptr, const u16* __restrict__ ws,
                 const u16* __restrict__ g, const u16* __restrict__ aux1,
                 const float* __restrict__ bias, const float* __restrict__ dis,
                 void* __restrict__ outp) {
    static_assert(NPB * (FS / 8) == 256, "block geometry");
    constexpr int SPLIT = F / FS;
    __shared__ __align__(16) u16 s_p[CAP];
    __shared__ int s_beg[NPB + 1];
    const int tid = threadIdx.x;
    const int nodeblk = blockIdx.x / SPLIT;
    const int half = blockIdx.x % SPLIT;
    const int node0 = nodeblk * NPB;
    if (tid <= NPB) {
        int n = node0 + tid;
        s_beg[tid] = row_ptr[n > N_NODES ? N_NODES : n];
    }
    __syncthreads();
    const int ebeg = s_beg[0];
    const int cnt = s_beg[NPB] - ebeg;
    const int skew = ebeg & 7;
    const int gb = ebeg - skew;
    const int lstage = stage_u16<CAP>(s_p, ws, gb, skew + cnt, tid);
    __syncthreads();
    constexpr int CPN = FS / 8;
    const int nl = tid / CPN;
    const int node = node0 + nl;
    if (node >= N_NODES) return;
    const int c8 = (tid % CPN) * 8 + half * FS;
    float acc[8];
    #pragma unroll
    for (int j = 0; j < 8; ++j) acc[j] = 0.0f;
    const int lbeg = s_beg[nl] - gb;
    const int lend = s_beg[nl + 1] - gb;
    const int lmid = lend < lstage ? lend : lstage;
    gather_loop<F>(acc, s_p, ws, g, lbeg, lmid, lend, lstage, gb, c8);
    const float dd = dis[node];
    if (EPI == EPI_S) {
        const float m1 = dd, m2 = -2.0f * dd * dd;
        const uint4 z1 = *(const uint4*)(aux1 + (long)node * F + c8);
        uint4 r;
        r.x = pack2(fmaf(m1, bflo(z1.x), m2 * acc[0]), fmaf(m1, bfhi(z1.x), m2 * acc[1]));
        r.y = pack2(fmaf(m1, bflo(z1.y), m2 * acc[2]), fmaf(m1, bfhi(z1.y), m2 * acc[3]));
        r.z = pack2(fmaf(m1, bflo(z1.z), m2 * acc[4]), fmaf(m1, bfhi(z1.z), m2 * acc[5]));
        r.w = pack2(fmaf(m1, bflo(z1.w), m2 * acc[6]), fmaf(m1, bfhi(z1.w), m2 * acc[7]));
        *(uint4*)((u16*)outp + (long)node * F + c8) = r;
    } else {
        const uint4 z0 = *(const uint4*)(aux1 + (long)node * F + c8);
        const float* bb = bias + c8;
        float v0 = bflo(z0.x) - dd * acc[0] + bb[0];
        float v1 = bfhi(z0.x) - dd * acc[1] + bb[1];
        float v2 = bflo(z0.y) - dd * acc[2] + bb[2];
        float v3 = bfhi(z0.y) - dd * acc[3] + bb[3];
        float v4 = bflo(z0.z) - dd * acc[4] + bb[4];
        float v5 = bfhi(z0.z) - dd * acc[5] + bb[5];
        float v6 = bflo(z0.w) - dd * acc[6] + bb[6];
        float v7 = bfhi(z0.w) - dd * acc[7] + bb[7];
        float* op = (float*)outp + (long)node * F + c8;
        *(float4*)op = make_float4(v0, v1, v2, v3);
        *(float4*)(op + 4) = make_float4(v4, v5, v6, v7);
    }
}

// ============ fused P2 + gemm2 (W2 fragments direct from global) ============

__global__ __launch_bounds__(256)
void prop2_gemm2(const int* __restrict__ row_ptr, const u16* __restrict__ ws,
                 const u16* __restrict__ S, const u16* __restrict__ D02,
                 const float* __restrict__ b1, const float* __restrict__ dis,
                 const u16* __restrict__ Pb2,
                 u16* __restrict__ D02p, u16* __restrict__ Z1p, u16* __restrict__ Zsp) {
    constexpr int NPB = 32, CAP = 1288;            // 1280 + 8 skew headroom
    __shared__ __align__(16) u16 s_p[CAP];
    __shared__ int s_beg[NPB + 1];
    __shared__ u16 h_tile[NPB][HID + 8];           // +8 pad: break 128B-stride banks
    const int tid = threadIdx.x;
    const int node0 = blockIdx.x * NPB;
    if (tid <= NPB) {
        int n = node0 + tid;
        s_beg[tid] = row_ptr[n > N_NODES ? N_NODES : n];
    }
    __syncthreads();
    const int ebeg = s_beg[0];
    const int cnt = s_beg[NPB] - ebeg;
    const int skew = ebeg & 7;
    const int gb = ebeg - skew;
    const int lstage = stage_u16<CAP>(s_p, ws, gb, skew + cnt, tid);
    __syncthreads();
    const int nl = tid >> 3;                       // CPN = 8
    const int node = node0 + nl;
    const int c8 = (tid & 7) * 8;
    if (node < N_NODES) {                          // NO early return (barrier below)
        float acc[8];
        #pragma unroll
        for (int j = 0; j < 8; ++j) acc[j] = 0.0f;
        const int lbeg = s_beg[nl] - gb;
        const int lend = s_beg[nl + 1] - gb;
        const int lmid = lend < lstage ? lend : lstage;
        gather_loop<HID>(acc, s_p, ws, S, lbeg, lmid, lend, lstage, gb, c8);
        const float dd = dis[node];
        const uint4 z0 = *(const uint4*)(D02 + (long)node * HID + c8);
        const float* bb = b1 + c8;
        float v0 = bflo(z0.x) - dd * acc[0] + bb[0];
        float v1 = bfhi(z0.x) - dd * acc[1] + bb[1];
        float v2 = bflo(z0.y) - dd * acc[2] + bb[2];
        float v3 = bfhi(z0.y) - dd * acc[3] + bb[3];
        float v4 = bflo(z0.z) - dd * acc[4] + bb[4];
        float v5 = bfhi(z0.z) - dd * acc[5] + bb[5];
        float v6 = bflo(z0.w) - dd * acc[6] + bb[6];
        float v7 = bfhi(z0.w) - dd * acc[7] + bb[7];
        uint4 r;
        r.x = pack2(fmaxf(v0, 0.f), fmaxf(v1, 0.f));
        r.y = pack2(fmaxf(v2, 0.f), fmaxf(v3, 0.f));
        r.z = pack2(fmaxf(v4, 0.f), fmaxf(v5, 0.f));
        r.w = pack2(fmaxf(v6, 0.f), fmaxf(v7, 0.f));
        *(uint4*)&h_tile[nl][c8] = r;
    }
    __syncthreads();
    // ---- gemm2 from LDS h_tile: waves 0,1 handle the block's two 16-node tiles ----
    const int w = tid >> 6;
    if (w >= 2) return;
    const int tile = blockIdx.x * 2 + w;
    if (tile * 16 >= N_NODES) return;
    const int lane = tid & 63;
    const int sub = lane >> 4, r16 = lane & 15;
    const int gnode0 = tile * 16;
    float dis4[4];
    #pragma unroll
    for (int r = 0; r < 4; ++r) dis4[r] = dis[gnode0 + sub * 4 + r];
    bf16x8 a[2];
    const u16* ar = &h_tile[w * 16 + r16][sub * 8];
    a[0] = *(const bf16x8*)(ar);
    a[1] = *(const bf16x8*)(ar + 32);
    auto cc = [&](int ct) {
        f32x4 acc = {0.f, 0.f, 0.f, 0.f};
        #pragma unroll
        for (int kt = 0; kt < 2; ++kt) {
            bf16x8 bfr = *(const bf16x8*)&Pb2[((kt * 4 + sub) * 48 + ct * 16 + r16) * 8];
            acc = __builtin_amdgcn_mfma_f32_16x16x32_bf16(a[kt], bfr, acc, 0, 0, 0);
        }
        return acc;
    };
    f32x4 acc0 = cc(0);
    f32x4 acc2 = cc(2);
    f32x4 acc1 = cc(1);
    const long rowoff = (long)(gnode0 + sub * 4) * D_OUT + r16;
    #pragma unroll
    for (int r = 0; r < 4; ++r) {
        D02p[rowoff + (long)r * D_OUT] = f2bf(acc0[r] - acc2[r]);
        Zsp[rowoff + (long)r * D_OUT]  = f2bf(acc2[r] * dis4[r]);
        Z1p[rowoff + (long)r * D_OUT]  = f2bf(acc1[r]);
    }
}

// ============ launch ============

extern "C" void kernel_launch(void* const* d_in, const int* in_sizes, int n_in,
                              void* d_out, int out_size, void* d_ws, size_t ws_size,
                              hipStream_t stream) {
    const float* x  = (const float*)d_in[0];
    const int*   ei = (const int*)d_in[1];
    const float* W1 = (const float*)d_in[2];
    const float* b1 = (const float*)d_in[3];
    const float* W2 = (const float*)d_in[4];
    const float* b2 = (const float*)d_in[5];
    const int* src = ei;
    const int* dst = ei + N_EDGES;

    // ---- workspace (sections aligned; u16 region starts 16B-aligned) ----
    float* dis          = (float*)d_ws;                      // 50000
    int*   row_ptr      = (int*)(dis + N_NODES);             // 50016
    int*   blk_cnt_src  = row_ptr + 50016;                   // 152896
    int*   blk_cnt_dst  = blk_cnt_src + 152896;              // 152896
    int*   tot_src      = blk_cnt_dst + 152896;              // 512
    int*   tot_dst      = tot_src + 512;                     // 512
    u16*   srconly      = (u16*)(tot_dst + 512);             // E u16
    u32*   sorted_pair  = (u32*)(srconly + N_EDGES);         // E u32
    u16*   wsrc         = (u16*)(sorted_pair + N_EDGES);     // E u16
    u16*   D02          = wsrc + N_EDGES;                    // N*64  (Z0 - Z2)
    u16*   Z1b          = D02 + (long)N_NODES * HID;         // N*64
    u16*   Zs           = Z1b + (long)N_NODES * HID;         // N*64  (Z2, scaled in passD)
    u16*   S            = Zs  + (long)N_NODES * HID;         // N*64  (Ŝ, pre-scaled)
    u16*   D02p         = S   + (long)N_NODES * HID;         // N*16
    u16*   Z1p          = D02p + (long)N_NODES * D_OUT;      // N*16
    u16*   Zsp          = Z1p  + (long)N_NODES * D_OUT;      // N*16
    u16*   Sp           = Zsp  + (long)N_NODES * D_OUT;      // N*16
    u16*   Pb1          = Sp   + (long)N_NODES * D_OUT;      // 18432
    u16*   Pb2          = Pb1 + 18432;                       // 3072
    u16*   xb           = Pb2 + 3072;                        // N*96 bf16 x

    // ---- build + layer-1 GEMM (gemm1 overlapped with passC) ----
    passA<<<NBLK_E + PACK_BLKS + CVT_BLKS, 256, 0, stream>>>(
        src, dst, blk_cnt_src, blk_cnt_dst, W1, W2, Pb1, Pb2, x, xb);
    passB<<<2 * NBKT, 64, 0, stream>>>(blk_cnt_src, blk_cnt_dst, tot_src, tot_dst);
    passC_gemm1<<<NBLK_E + GEMM1_BLKS, 256, 0, stream>>>(
        src, dst, blk_cnt_src, blk_cnt_dst, tot_src, tot_dst,
        srconly, sorted_pair, xb, Pb1, D02, Z1b, Zs);
    passD<<<2 * NBKT, 256, 0, stream>>>(tot_src, srconly, tot_dst, sorted_pair,
                                        dis, row_ptr, wsrc, Zs);

    // ---- layer 1: P1 (split), then fused P2+gemm2 ----
    gather_prop<HID, 32, 64, 1552, EPI_S><<<2 * ((N_NODES + 63) / 64), 256, 0, stream>>>(
        row_ptr, wsrc, Zs, Z1b, nullptr, dis, S);
    prop2_gemm2<<<(N_NODES + 31) / 32, 256, 0, stream>>>(
        row_ptr, wsrc, S, D02, b1, dis, Pb2, D02p, Z1p, Zsp);

    // ---- layer 2 props ----
    gather_prop<D_OUT, 16, 128, 3088, EPI_S><<<(N_NODES + 127) / 128, 256, 0, stream>>>(
        row_ptr, wsrc, Zsp, Z1p, nullptr, dis, Sp);
    gather_prop<D_OUT, 16, 128, 3088, EPI_OUT><<<(N_NODES + 127) / 128, 256, 0, stream>>>(
        row_ptr, wsrc, Sp, D02p, b2, dis, (float*)d_out);
}

// Round 18
// 100.258 us; speedup vs baseline: 1.5653x; 1.0632x over previous
//
#include <hip/hip_runtime.h>

#define N_NODES 50000
#define N_EDGES 800000
#define D_IN 96
#define HID 64
#define D_OUT 16

#define EPB 4096                                   // edges per block (passes A/C)
#define NBLK_E ((N_EDGES + EPB - 1) / EPB)         // 196
#define BSHIFT 7                                   // 128 nodes per bucket
#define NBKT ((N_NODES + 127) / 128)               // 391
#define DCAP 2560                                  // Ddst LDS edge staging cap (u32)
#define PACK_TOT (3 * D_IN * HID + 3 * HID * D_OUT)   // 21504
#define PACK_BLKS (PACK_TOT / 256)                 // 84
#define CVT_N (N_NODES * D_IN)                     // 4800000
#define CVT_BLKS ((CVT_N / 8 + 255) / 256)         // 2344
#define GEMM1_BLKS ((N_NODES / 16 + 3) / 4)        // 782

typedef unsigned short u16;
typedef unsigned int u32;
typedef __attribute__((ext_vector_type(4))) float f32x4;
typedef __attribute__((ext_vector_type(8))) short bf16x8;

__device__ inline float bflo(u32 v) { union { u32 i; float f; } u; u.i = v << 16; return u.f; }
__device__ inline float bfhi(u32 v) { union { u32 i; float f; } u; u.i = v & 0xffff0000u; return u.f; }
__device__ inline u16 f2bf(float f) {              // RTNE
    union { float f; u32 i; } u; u.f = f;
    return (u16)((u.i + 0x7fffu + ((u.i >> 16) & 1u)) >> 16);
}
__device__ inline u32 pack2(float lo, float hi) {
    return (u32)f2bf(lo) | ((u32)f2bf(hi) << 16);
}

// ============ passA: coarse histograms + weight pack + x->bf16 convert ============

__global__ __launch_bounds__(256)
void passA(const int* __restrict__ src, const int* __restrict__ dst,
           int* __restrict__ blk_cnt_src, int* __restrict__ blk_cnt_dst,
           const float* __restrict__ W1, const float* __restrict__ W2,
           u16* __restrict__ Pb1, u16* __restrict__ Pb2,
           const float* __restrict__ x, u16* __restrict__ xb) {
    const int t = threadIdx.x, blk = blockIdx.x;
    if (blk >= NBLK_E + PACK_BLKS) {               // ---- x convert blocks ----
        long idx8 = ((long)(blk - NBLK_E - PACK_BLKS) * 256 + t) * 8;
        if (idx8 < CVT_N) {
            float4 a0 = *(const float4*)(x + idx8);
            float4 a1 = *(const float4*)(x + idx8 + 4);
            uint4 r;
            r.x = pack2(a0.x, a0.y); r.y = pack2(a0.z, a0.w);
            r.z = pack2(a1.x, a1.y); r.w = pack2(a1.z, a1.w);
            *(uint4*)(xb + idx8) = r;
        }
        return;
    }
    if (blk >= NBLK_E) {                           // ---- weight-pack blocks ----
        int tt = (blk - NBLK_E) * 256 + t;
        if (tt < 3 * D_IN * HID) {                 // 18432: K=96, NC=192, OUTW=64
            int j = tt & 7, rest = tt >> 3;
            int c = rest % 192, i = (rest / 192) * 8 + j;
            int kc = c / 64, o = c % 64;
            Pb1[tt] = f2bf(W1[((long)kc * D_IN + i) * HID + o]);
        } else if (tt < PACK_TOT) {
            int t2 = tt - 3 * D_IN * HID;          // 3072: K=64, NC=48, OUTW=16
            int j = t2 & 7, rest = t2 >> 3;
            int c = rest % 48, i = (rest / 48) * 8 + j;
            int kc = c / 16, o = c % 16;
            Pb2[t2] = f2bf(W2[((long)kc * HID + i) * D_OUT + o]);
        }
        return;
    }
    // ---- histogram blocks ----
    __shared__ int hs[NBKT], hd[NBKT];
    for (int i = t; i < NBKT; i += 256) { hs[i] = 0; hd[i] = 0; }
    __syncthreads();
    const int e0 = blk * EPB;
    if (e0 + EPB <= N_EDGES) {                     // full block: 16 edges/thread
        const int base = e0 + t * 16;
        #pragma unroll
        for (int v = 0; v < 4; ++v) {
            int4 s4 = *(const int4*)(src + base + v * 4);
            int4 d4 = *(const int4*)(dst + base + v * 4);
            atomicAdd(&hs[s4.x >> BSHIFT], 1); atomicAdd(&hs[s4.y >> BSHIFT], 1);
            atomicAdd(&hs[s4.z >> BSHIFT], 1); atomicAdd(&hs[s4.w >> BSHIFT], 1);
            atomicAdd(&hd[d4.x >> BSHIFT], 1); atomicAdd(&hd[d4.y >> BSHIFT], 1);
            atomicAdd(&hd[d4.z >> BSHIFT], 1); atomicAdd(&hd[d4.w >> BSHIFT], 1);
        }
    } else {                                       // tail block
        for (int e = e0 + t; e < N_EDGES; e += 256) {
            atomicAdd(&hs[src[e] >> BSHIFT], 1);
            atomicAdd(&hd[dst[e] >> BSHIFT], 1);
        }
    }
    __syncthreads();
    for (int b = t; b < NBKT; b += 256) {
        blk_cnt_src[b * NBLK_E + blk] = hs[b];
        blk_cnt_dst[b * NBLK_E + blk] = hd[b];
    }
}

// passB: per-bucket exclusive scan over the block dimension (in place), emit totals.
__global__ __launch_bounds__(64)
void passB(int* __restrict__ blk_cnt_src, int* __restrict__ blk_cnt_dst,
           int* __restrict__ tot_src, int* __restrict__ tot_dst) {
    const int b = blockIdx.x;
    int* cnt; int* tot;
    if (b < NBKT) { cnt = blk_cnt_dst + b * NBLK_E;          tot = tot_dst + b; }
    else          { cnt = blk_cnt_src + (b - NBKT) * NBLK_E; tot = tot_src + (b - NBKT); }
    const int lane = threadIdx.x;
    int carry = 0;
    for (int base0 = 0; base0 < NBLK_E; base0 += 64) {
        int i = base0 + lane;
        int v = (i < NBLK_E) ? cnt[i] : 0;
        int incl = v;
        #pragma unroll
        for (int off = 1; off < 64; off <<= 1) {
            int x = __shfl_up(incl, off);
            if (lane >= off) incl += x;
        }
        if (i < NBLK_E) cnt[i] = carry + incl - v;
        carry += __shfl(incl, 63);
    }
    if (lane == 0) *tot = carry;
}

// ============ gemm body (bf16 A; B-fragments direct from global) ============

template<int K, int NC, int LDZ, int CPK>
__device__ __forceinline__
void gemm_body(int tile, int lane, const u16* __restrict__ A, const u16* __restrict__ P,
               u16* __restrict__ D02, u16* __restrict__ Z1, u16* __restrict__ Z2out) {
    constexpr int KT = K / 32;
    const int node0 = tile * 16;
    const int sub = lane >> 4, r16 = lane & 15;
    bf16x8 a[KT];
    const u16* ar = A + (long)(node0 + r16) * K + sub * 8;
    #pragma unroll
    for (int kt = 0; kt < KT; ++kt)
        a[kt] = *(const bf16x8*)(ar + kt * 32);
    auto cc = [&](int ct) {
        f32x4 acc = {0.f, 0.f, 0.f, 0.f};
        #pragma unroll
        for (int kt = 0; kt < KT; ++kt) {
            bf16x8 bfr = *(const bf16x8*)&P[((kt * 4 + sub) * NC + ct * 16 + r16) * 8];
            acc = __builtin_amdgcn_mfma_f32_16x16x32_bf16(a[kt], bfr, acc, 0, 0, 0);
        }
        return acc;
    };
    #pragma unroll
    for (int i = 0; i < CPK; ++i) {                // plane0/plane2 pairwise
        f32x4 acc0 = cc(i);
        f32x4 acc2 = cc(2 * CPK + i);
        const long rowoff = (long)(node0 + sub * 4) * LDZ + i * 16 + r16;
        #pragma unroll
        for (int r = 0; r < 4; ++r) {
            D02[rowoff + (long)r * LDZ] = f2bf(acc0[r] - acc2[r]);
            Z2out[rowoff + (long)r * LDZ] = f2bf(acc2[r]);
        }
    }
    #pragma unroll
    for (int i = 0; i < CPK; ++i) {                // plane1
        f32x4 acc1 = cc(CPK + i);
        const long rowoff = (long)(node0 + sub * 4) * LDZ + i * 16 + r16;
        #pragma unroll
        for (int r = 0; r < 4; ++r)
            Z1[rowoff + (long)r * LDZ] = f2bf(acc1[r]);
    }
}

// ============ merged passC + gemm1 ============

__global__ __launch_bounds__(256)
void passC_gemm1(const int* __restrict__ src, const int* __restrict__ dst,
                 const int* __restrict__ blk_off_src, const int* __restrict__ blk_off_dst,
                 const int* __restrict__ tot_src, const int* __restrict__ tot_dst,
                 u16* __restrict__ sorted_srconly, u32* __restrict__ sorted_pair,
                 const u16* __restrict__ xb, const u16* __restrict__ Pb1,
                 u16* __restrict__ D02, u16* __restrict__ Z1, u16* __restrict__ Zs) {
    __shared__ int s[512];
    __shared__ int cs[NBKT], cd[NBKT];
    const int t = threadIdx.x, blk = blockIdx.x;
    if (blk >= NBLK_E) {                           // ---- gemm1 blocks (no LDS use) ----
        const int tile = (blk - NBLK_E) * 4 + (t >> 6);
        if (tile * 16 >= N_NODES) return;
        gemm_body<D_IN, 192, HID, 4>(tile, t & 63, xb, Pb1, D02, Z1, Zs);
        return;
    }
    // ---- passC blocks ----
    for (int pass = 0; pass < 2; ++pass) {
        const int* tot = pass ? tot_src : tot_dst;
        const int* bo  = pass ? blk_off_src : blk_off_dst;
        int* cx = pass ? cs : cd;
        s[t]       = (t < NBKT) ? tot[t] : 0;
        s[t + 256] = (t + 256 < NBKT) ? tot[t + 256] : 0;
        __syncthreads();
        for (int off = 1; off < 512; off <<= 1) {
            int a1 = (t >= off) ? s[t - off] : 0;
            int a2 = (t + 256 >= off) ? s[t + 256 - off] : 0;
            __syncthreads();
            s[t] += a1; s[t + 256] += a2;
            __syncthreads();
        }
        if (t < NBKT) cx[t] = s[t] - tot[t] + bo[t * NBLK_E + blk];
        if (t + 256 < NBKT) cx[t + 256] = s[t + 256] - tot[t + 256] + bo[(t + 256) * NBLK_E + blk];
        __syncthreads();
    }
    const int e0 = blk * EPB;
    if (e0 + EPB <= N_EDGES) {                     // full block: 16 edges/thread
        const int base = e0 + t * 16;
        #pragma unroll
        for (int v = 0; v < 4; ++v) {
            int4 s4 = *(const int4*)(src + base + v * 4);
            int4 d4 = *(const int4*)(dst + base + v * 4);
            int sv[4] = {s4.x, s4.y, s4.z, s4.w};
            int dv[4] = {d4.x, d4.y, d4.z, d4.w};
            #pragma unroll
            for (int k = 0; k < 4; ++k) {
                int ps = atomicAdd(&cs[sv[k] >> BSHIFT], 1);
                sorted_srconly[ps] = (u16)sv[k];
                int pd = atomicAdd(&cd[dv[k] >> BSHIFT], 1);
                sorted_pair[pd] = ((u32)dv[k] << 16) | (u32)sv[k];
            }
        }
    } else {
        for (int e = e0 + t; e < N_EDGES; e += 256) {
            int sv = src[e], dv = dst[e];
            int ps = atomicAdd(&cs[sv >> BSHIFT], 1);
            sorted_srconly[ps] = (u16)sv;
            int pd = atomicAdd(&cd[dv >> BSHIFT], 1);
            sorted_pair[pd] = ((u32)dv << 16) | (u32)sv;
        }
    }
}

// passD: merged Dsrc (deg->dis + in-place Zs scaling) + Ddst (fine CSR).
__global__ __launch_bounds__(256)
void passD(const int* __restrict__ tot_src, const u16* __restrict__ sorted_srconly,
           const int* __restrict__ tot_dst, const u32* __restrict__ sorted_pair,
           float* __restrict__ dis, int* __restrict__ row_ptr, u16* __restrict__ wsrc,
           u16* __restrict__ Zs) {
    __shared__ int sred[256];
    __shared__ int hist[128];
    __shared__ int cur[128];
    __shared__ float s_dis[128];
    __shared__ __align__(16) u32 s_p[DCAP];
    const int t = threadIdx.x;
    const bool isSrc = blockIdx.x < NBKT;
    const int b = isSrc ? blockIdx.x : blockIdx.x - NBKT;
    const int* tot = isSrc ? tot_src : tot_dst;
    int part = 0;
    for (int i = t; i < b; i += 256) part += tot[i];
    sred[t] = part;
    if (t < 128) hist[t] = 0;
    __syncthreads();
    #pragma unroll
    for (int off = 128; off > 0; off >>= 1) {
        if (t < off) sred[t] += sred[t + off];
        __syncthreads();
    }
    const int eb = sred[0];
    const int ee = eb + tot[b];
    if (isSrc) {                                   // ---- Dsrc half (uint4 reads) ----
        const int cnt = ee - eb;
        const int skew = eb & 7;
        const int gb = eb - skew;
        const int nv = (skew + cnt + 7) >> 3;
        for (int i = t; i < nv; i += 256) {
            uint4 q = *(const uint4*)(sorted_srconly + gb + i * 8);
            u32 w[4] = {q.x, q.y, q.z, q.w};
            int lo = i * 8;
            #pragma unroll
            for (int k = 0; k < 4; ++k) {
                int l0 = lo + 2 * k, l1 = l0 + 1;
                if (l0 >= skew && l0 < skew + cnt) atomicAdd(&hist[w[k] & 127], 1);
                if (l1 >= skew && l1 < skew + cnt) atomicAdd(&hist[(w[k] >> 16) & 127], 1);
            }
        }
        __syncthreads();
        const int node0 = b << BSHIFT;
        if (t < 128) {
            int c = hist[t];
            float dv = c > 0 ? rsqrtf((float)c) : 0.0f;
            s_dis[t] = dv;
            if (node0 + t < N_NODES) dis[node0 + t] = dv;
        }
        __syncthreads();
        for (int c = t; c < 128 * 8; c += 256) {   // in-place scale Zs *= dis
            int ln = c >> 3, off8 = (c & 7) * 8;
            int n = node0 + ln;
            if (n >= N_NODES) continue;
            float dv = s_dis[ln];
            u16* zp = Zs + (long)n * HID + off8;
            uint4 q = *(uint4*)zp;
            uint4 r;
            r.x = pack2(bflo(q.x) * dv, bfhi(q.x) * dv);
            r.y = pack2(bflo(q.y) * dv, bfhi(q.y) * dv);
            r.z = pack2(bflo(q.z) * dv, bfhi(q.z) * dv);
            r.w = pack2(bflo(q.w) * dv, bfhi(q.w) * dv);
            *(uint4*)zp = r;
        }
        return;
    }
    // ---- Ddst half (vector-staged) ----
    if (b == 0 && t == 0) row_ptr[N_NODES] = N_EDGES;
    const int cnt = ee - eb;
    const int skew = eb & 3;
    const int gb = eb - skew;                      // aligned base (element index)
    const int tot4 = skew + cnt;
    int nv = (tot4 + 3) >> 2;
    if (nv > (DCAP >> 2)) nv = DCAP >> 2;
    for (int i = t; i < nv; i += 256)
        *(uint4*)&s_p[i * 4] = *(const uint4*)(sorted_pair + gb + i * 4);
    __syncthreads();
    const int lstage = nv * 4;                     // locals [0,lstage) staged
    const int lbeg = skew, lend = skew + cnt;
    const int lmid = lend < lstage ? lend : lstage;
    for (int l = lbeg + t; l < lmid; l += 256)
        atomicAdd(&hist[(s_p[l] >> 16) & 127], 1);
    for (int l = (lbeg > lstage ? lbeg : lstage) + t; l < lend; l += 256)
        atomicAdd(&hist[(sorted_pair[gb + l] >> 16) & 127], 1);
    __syncthreads();
    if (t < 64) {
        int v0 = hist[2 * t], v1 = hist[2 * t + 1];
        int p = v0 + v1;
        int incl = p;
        #pragma unroll
        for (int off = 1; off < 64; off <<= 1) {
            int x = __shfl_up(incl, off);
            if (t >= off) incl += x;
        }
        int excl = incl - p;
        cur[2 * t] = excl;
        cur[2 * t + 1] = excl + v0;
        int node = (b << BSHIFT) + 2 * t;
        if (node < N_NODES) row_ptr[node] = eb + excl;
        if (node + 1 < N_NODES) row_ptr[node + 1] = eb + excl + v0;
    }
    __syncthreads();
    for (int l = lbeg + t; l < lmid; l += 256) {
        u32 v = s_p[l];
        int slot = atomicAdd(&cur[(v >> 16) & 127], 1);
        wsrc[eb + slot] = (u16)(v & 0xFFFF);
    }
    for (int l = (lbeg > lstage ? lbeg : lstage) + t; l < lend; l += 256) {
        u32 v = sorted_pair[gb + l];
        int slot = atomicAdd(&cur[(v >> 16) & 127], 1);
        wsrc[eb + slot] = (u16)(v & 0xFFFF);
    }
}

// ============ gather helpers ============

__device__ inline void sum8(float (&acc)[8], uint4 q) {
    acc[0] += bflo(q.x); acc[1] += bfhi(q.x);
    acc[2] += bflo(q.y); acc[3] += bfhi(q.y);
    acc[4] += bflo(q.z); acc[5] += bfhi(q.z);
    acc[6] += bflo(q.w); acc[7] += bfhi(q.w);
}

template<int F>
__device__ __forceinline__
void gather_loop(float (&acc)[8], const u16* s_p, const u16* ws, const u16* g,
                 int beg, int mid, int end, int stage, int gb, int c8) {
    int e = beg;
    for (; e + 8 <= mid; e += 8) {
        int p0 = s_p[e],     p1 = s_p[e + 1], p2 = s_p[e + 2], p3 = s_p[e + 3];
        int p4 = s_p[e + 4], p5 = s_p[e + 5], p6 = s_p[e + 6], p7 = s_p[e + 7];
        uint4 q0 = *(const uint4*)(g + (long)p0 * F + c8);
        uint4 q1 = *(const uint4*)(g + (long)p1 * F + c8);
        uint4 q2 = *(const uint4*)(g + (long)p2 * F + c8);
        uint4 q3 = *(const uint4*)(g + (long)p3 * F + c8);
        uint4 q4 = *(const uint4*)(g + (long)p4 * F + c8);
        uint4 q5 = *(const uint4*)(g + (long)p5 * F + c8);
        uint4 q6 = *(const uint4*)(g + (long)p6 * F + c8);
        uint4 q7 = *(const uint4*)(g + (long)p7 * F + c8);
        sum8(acc, q0); sum8(acc, q1); sum8(acc, q2); sum8(acc, q3);
        sum8(acc, q4); sum8(acc, q5); sum8(acc, q6); sum8(acc, q7);
    }
    for (; e + 4 <= mid; e += 4) {
        int p0 = s_p[e], p1 = s_p[e + 1], p2 = s_p[e + 2], p3 = s_p[e + 3];
        uint4 q0 = *(const uint4*)(g + (long)p0 * F + c8);
        uint4 q1 = *(const uint4*)(g + (long)p1 * F + c8);
        uint4 q2 = *(const uint4*)(g + (long)p2 * F + c8);
        uint4 q3 = *(const uint4*)(g + (long)p3 * F + c8);
        sum8(acc, q0); sum8(acc, q1); sum8(acc, q2); sum8(acc, q3);
    }
    for (; e < mid; ++e)
        sum8(acc, *(const uint4*)(g + (long)s_p[e] * F + c8));
    for (e = (beg > stage ? beg : stage); e < end; ++e)     // overflow fallback (rare)
        sum8(acc, *(const uint4*)(g + (long)ws[gb + e] * F + c8));
}

// Skew-aligned u16 staging: stage ws[gb + 0 .. nv*8) into s_p[0 .. nv*8), gb = ebeg & ~7.
template<int CAP>
__device__ __forceinline__
int stage_u16(u16* s_p, const u16* __restrict__ ws, int gb, int tot, int tid) {
    int nv = (tot + 7) >> 3;
    if (nv > (CAP >> 3)) nv = CAP >> 3;
    for (int i = tid; i < nv; i += 256)
        *(uint4*)&s_p[i * 8] = *(const uint4*)(ws + gb + i * 8);
    return nv * 8;
}

// ============ gather propagate (P1 / P3 / P4) ============
// EPI_S  : Ŝ  = dis_d*aux1 - 2*dis_d^2*acc           (aux1 = Z1; bf16 out)
// EPI_OUT: out = aux1 - dis_d*acc + bias              (aux1 = D02'; f32 out)

#define EPI_S 0
#define EPI_OUT 2

template<int F, int NPB, int CAP, int EPI>
__global__ __launch_bounds__(256)
void gather_prop(const int* __restrict__ row_ptr, const u16* __restrict__ ws,
                 const u16* __restrict__ g, const u16* __restrict__ aux1,
                 const float* __restrict__ bias, const float* __restrict__ dis,
                 void* __restrict__ outp) {
    static_assert(NPB * (F / 8) == 256, "block geometry");
    __shared__ __align__(16) u16 s_p[CAP];
    __shared__ int s_beg[NPB + 1];
    const int tid = threadIdx.x;
    const int node0 = blockIdx.x * NPB;
    if (tid <= NPB) {
        int n = node0 + tid;
        s_beg[tid] = row_ptr[n > N_NODES ? N_NODES : n];
    }
    __syncthreads();
    const int ebeg = s_beg[0];
    const int cnt = s_beg[NPB] - ebeg;
    const int skew = ebeg & 7;
    const int gb = ebeg - skew;
    const int lstage = stage_u16<CAP>(s_p, ws, gb, skew + cnt, tid);
    __syncthreads();
    constexpr int CPN = F / 8;
    const int nl = tid / CPN;
    const int node = node0 + nl;
    if (node >= N_NODES) return;
    const int c8 = (tid % CPN) * 8;
    float acc[8];
    #pragma unroll
    for (int j = 0; j < 8; ++j) acc[j] = 0.0f;
    const int lbeg = s_beg[nl] - gb;
    const int lend = s_beg[nl + 1] - gb;
    const int lmid = lend < lstage ? lend : lstage;
    gather_loop<F>(acc, s_p, ws, g, lbeg, lmid, lend, lstage, gb, c8);
    const float dd = dis[node];
    if (EPI == EPI_S) {
        const float m1 = dd, m2 = -2.0f * dd * dd;
        const uint4 z1 = *(const uint4*)(aux1 + (long)node * F + c8);
        uint4 r;
        r.x = pack2(fmaf(m1, bflo(z1.x), m2 * acc[0]), fmaf(m1, bfhi(z1.x), m2 * acc[1]));
        r.y = pack2(fmaf(m1, bflo(z1.y), m2 * acc[2]), fmaf(m1, bfhi(z1.y), m2 * acc[3]));
        r.z = pack2(fmaf(m1, bflo(z1.z), m2 * acc[4]), fmaf(m1, bfhi(z1.z), m2 * acc[5]));
        r.w = pack2(fmaf(m1, bflo(z1.w), m2 * acc[6]), fmaf(m1, bfhi(z1.w), m2 * acc[7]));
        *(uint4*)((u16*)outp + (long)node * F + c8) = r;
    } else {
        const uint4 z0 = *(const uint4*)(aux1 + (long)node * F + c8);
        const float* bb = bias + c8;
        float v0 = bflo(z0.x) - dd * acc[0] + bb[0];
        float v1 = bfhi(z0.x) - dd * acc[1] + bb[1];
        float v2 = bflo(z0.y) - dd * acc[2] + bb[2];
        float v3 = bfhi(z0.y) - dd * acc[3] + bb[3];
        float v4 = bflo(z0.z) - dd * acc[4] + bb[4];
        float v5 = bfhi(z0.z) - dd * acc[5] + bb[5];
        float v6 = bflo(z0.w) - dd * acc[6] + bb[6];
        float v7 = bfhi(z0.w) - dd * acc[7] + bb[7];
        float* op = (float*)outp + (long)node * F + c8;
        *(float4*)op = make_float4(v0, v1, v2, v3);
        *(float4*)(op + 4) = make_float4(v4, v5, v6, v7);
    }
}

// ============ fused P2 + gemm2 (W2 fragments direct from global) ============

__global__ __launch_bounds__(256)
void prop2_gemm2(const int* __restrict__ row_ptr, const u16* __restrict__ ws,
                 const u16* __restrict__ S, const u16* __restrict__ D02,
                 const float* __restrict__ b1, const float* __restrict__ dis,
                 const u16* __restrict__ Pb2,
                 u16* __restrict__ D02p, u16* __restrict__ Z1p, u16* __restrict__ Zsp) {
    constexpr int NPB = 32, CAP = 1288;            // 1280 + 8 skew headroom
    __shared__ __align__(16) u16 s_p[CAP];
    __shared__ int s_beg[NPB + 1];
    __shared__ u16 h_tile[NPB][HID + 8];           // +8 pad: break 128B-stride banks
    const int tid = threadIdx.x;
    const int node0 = blockIdx.x * NPB;
    if (tid <= NPB) {
        int n = node0 + tid;
        s_beg[tid] = row_ptr[n > N_NODES ? N_NODES : n];
    }
    __syncthreads();
    const int ebeg = s_beg[0];
    const int cnt = s_beg[NPB] - ebeg;
    const int skew = ebeg & 7;
    const int gb = ebeg - skew;
    const int lstage = stage_u16<CAP>(s_p, ws, gb, skew + cnt, tid);
    __syncthreads();
    const int nl = tid >> 3;                       // CPN = 8
    const int node = node0 + nl;
    const int c8 = (tid & 7) * 8;
    if (node < N_NODES) {                          // NO early return (barrier below)
        float acc[8];
        #pragma unroll
        for (int j = 0; j < 8; ++j) acc[j] = 0.0f;
        const int lbeg = s_beg[nl] - gb;
        const int lend = s_beg[nl + 1] - gb;
        const int lmid = lend < lstage ? lend : lstage;
        gather_loop<HID>(acc, s_p, ws, S, lbeg, lmid, lend, lstage, gb, c8);
        const float dd = dis[node];
        const uint4 z0 = *(const uint4*)(D02 + (long)node * HID + c8);
        const float* bb = b1 + c8;
        float v0 = bflo(z0.x) - dd * acc[0] + bb[0];
        float v1 = bfhi(z0.x) - dd * acc[1] + bb[1];
        float v2 = bflo(z0.y) - dd * acc[2] + bb[2];
        float v3 = bfhi(z0.y) - dd * acc[3] + bb[3];
        float v4 = bflo(z0.z) - dd * acc[4] + bb[4];
        float v5 = bfhi(z0.z) - dd * acc[5] + bb[5];
        float v6 = bflo(z0.w) - dd * acc[6] + bb[6];
        float v7 = bfhi(z0.w) - dd * acc[7] + bb[7];
        uint4 r;
        r.x = pack2(fmaxf(v0, 0.f), fmaxf(v1, 0.f));
        r.y = pack2(fmaxf(v2, 0.f), fmaxf(v3, 0.f));
        r.z = pack2(fmaxf(v4, 0.f), fmaxf(v5, 0.f));
        r.w = pack2(fmaxf(v6, 0.f), fmaxf(v7, 0.f));
        *(uint4*)&h_tile[nl][c8] = r;
    }
    __syncthreads();
    // ---- gemm2 from LDS h_tile: waves 0,1 handle the block's two 16-node tiles ----
    const int w = tid >> 6;
    if (w >= 2) return;
    const int tile = blockIdx.x * 2 + w;
    if (tile * 16 >= N_NODES) return;
    const int lane = tid & 63;
    const int sub = lane >> 4, r16 = lane & 15;
    const int gnode0 = tile * 16;
    float dis4[4];
    #pragma unroll
    for (int r = 0; r < 4; ++r) dis4[r] = dis[gnode0 + sub * 4 + r];
    bf16x8 a[2];
    const u16* ar = &h_tile[w * 16 + r16][sub * 8];
    a[0] = *(const bf16x8*)(ar);
    a[1] = *(const bf16x8*)(ar + 32);
    auto cc = [&](int ct) {
        f32x4 acc = {0.f, 0.f, 0.f, 0.f};
        #pragma unroll
        for (int kt = 0; kt < 2; ++kt) {
            bf16x8 bfr = *(const bf16x8*)&Pb2[((kt * 4 + sub) * 48 + ct * 16 + r16) * 8];
            acc = __builtin_amdgcn_mfma_f32_16x16x32_bf16(a[kt], bfr, acc, 0, 0, 0);
        }
        return acc;
    };
    f32x4 acc0 = cc(0);
    f32x4 acc2 = cc(2);
    f32x4 acc1 = cc(1);
    const long rowoff = (long)(gnode0 + sub * 4) * D_OUT + r16;
    #pragma unroll
    for (int r = 0; r < 4; ++r) {
        D02p[rowoff + (long)r * D_OUT] = f2bf(acc0[r] - acc2[r]);
        Zsp[rowoff + (long)r * D_OUT]  = f2bf(acc2[r] * dis4[r]);
        Z1p[rowoff + (long)r * D_OUT]  = f2bf(acc1[r]);
    }
}

// ============ launch ============

extern "C" void kernel_launch(void* const* d_in, const int* in_sizes, int n_in,
                              void* d_out, int out_size, void* d_ws, size_t ws_size,
                              hipStream_t stream) {
    const float* x  = (const float*)d_in[0];
    const int*   ei = (const int*)d_in[1];
    const float* W1 = (const float*)d_in[2];
    const float* b1 = (const float*)d_in[3];
    const float* W2 = (const float*)d_in[4];
    const float* b2 = (const float*)d_in[5];
    const int* src = ei;
    const int* dst = ei + N_EDGES;

    // ---- workspace (sections aligned; u16 region starts 16B-aligned) ----
    float* dis          = (float*)d_ws;                      // 50000
    int*   row_ptr      = (int*)(dis + N_NODES);             // 50016
    int*   blk_cnt_src  = row_ptr + 50016;                   // 152896 (padded)
    int*   blk_cnt_dst  = blk_cnt_src + 152896;              // 152896
    int*   tot_src      = blk_cnt_dst + 152896;              // 512
    int*   tot_dst      = tot_src + 512;                     // 512
    u16*   srconly      = (u16*)(tot_dst + 512);             // E u16
    u32*   sorted_pair  = (u32*)(srconly + N_EDGES);         // E u32
    u16*   wsrc         = (u16*)(sorted_pair + N_EDGES);     // E u16
    u16*   D02          = wsrc + N_EDGES;                    // N*64  (Z0 - Z2)
    u16*   Z1b          = D02 + (long)N_NODES * HID;         // N*64
    u16*   Zs           = Z1b + (long)N_NODES * HID;         // N*64  (Z2, scaled in passD)
    u16*   S            = Zs  + (long)N_NODES * HID;         // N*64  (Ŝ, pre-scaled)
    u16*   D02p         = S   + (long)N_NODES * HID;         // N*16
    u16*   Z1p          = D02p + (long)N_NODES * D_OUT;      // N*16
    u16*   Zsp          = Z1p  + (long)N_NODES * D_OUT;      // N*16
    u16*   Sp           = Zsp  + (long)N_NODES * D_OUT;      // N*16
    u16*   Pb1          = Sp   + (long)N_NODES * D_OUT;      // 18432
    u16*   Pb2          = Pb1 + 18432;                       // 3072
    u16*   xb           = Pb2 + 3072;                        // N*96 bf16 x

    // ---- build + layer-1 GEMM (gemm1 overlapped with passC) ----
    passA<<<NBLK_E + PACK_BLKS + CVT_BLKS, 256, 0, stream>>>(
        src, dst, blk_cnt_src, blk_cnt_dst, W1, W2, Pb1, Pb2, x, xb);
    passB<<<2 * NBKT, 64, 0, stream>>>(blk_cnt_src, blk_cnt_dst, tot_src, tot_dst);
    passC_gemm1<<<NBLK_E + GEMM1_BLKS, 256, 0, stream>>>(
        src, dst, blk_cnt_src, blk_cnt_dst, tot_src, tot_dst,
        srconly, sorted_pair, xb, Pb1, D02, Z1b, Zs);
    passD<<<2 * NBKT, 256, 0, stream>>>(tot_src, srconly, tot_dst, sorted_pair,
                                        dis, row_ptr, wsrc, Zs);

    // ---- layer 1: P1, then fused P2+gemm2 ----
    gather_prop<HID, 32, 1288, EPI_S><<<(N_NODES + 31) / 32, 256, 0, stream>>>(
        row_ptr, wsrc, Zs, Z1b, nullptr, dis, S);
    prop2_gemm2<<<(N_NODES + 31) / 32, 256, 0, stream>>>(
        row_ptr, wsrc, S, D02, b1, dis, Pb2, D02p, Z1p, Zsp);

    // ---- layer 2 props ----
    gather_prop<D_OUT, 128, 3088, EPI_S><<<(N_NODES + 127) / 128, 256, 0, stream>>>(
        row_ptr, wsrc, Zsp, Z1p, nullptr, dis, Sp);
    gather_prop<D_OUT, 128, 3088, EPI_OUT><<<(N_NODES + 127) / 128, 256, 0, stream>>>(
        row_ptr, wsrc, Sp, D02p, b2, dis, (float*)d_out);
}

// Round 19
// 98.404 us; speedup vs baseline: 1.5948x; 1.0188x over previous
//
#include <hip/hip_runtime.h>

#define N_NODES 50000
#define N_EDGES 800000
#define D_IN 96
#define HID 64
#define D_OUT 16

#define EPB 4096                                   // edges per block (passes A/C)
#define NBLK_E ((N_EDGES + EPB - 1) / EPB)         // 196
#define BSHIFT 7                                   // 128 nodes per bucket
#define NBKT ((N_NODES + 127) / 128)               // 391
#define DCAP 2560                                  // Ddst LDS edge staging cap (u32)
#define PACK_TOT (3 * D_IN * HID + 3 * HID * D_OUT)   // 21504
#define PACK_BLKS (PACK_TOT / 256)                 // 84
#define GEMM1_BLKS ((N_NODES / 16 + 3) / 4)        // 782

typedef unsigned short u16;
typedef unsigned int u32;
typedef __attribute__((ext_vector_type(4))) float f32x4;
typedef __attribute__((ext_vector_type(8))) short bf16x8;

__device__ inline float bflo(u32 v) { union { u32 i; float f; } u; u.i = v << 16; return u.f; }
__device__ inline float bfhi(u32 v) { union { u32 i; float f; } u; u.i = v & 0xffff0000u; return u.f; }
__device__ inline u16 f2bf(float f) {              // RTNE
    union { float f; u32 i; } u; u.f = f;
    return (u16)((u.i + 0x7fffu + ((u.i >> 16) & 1u)) >> 16);
}
__device__ inline u32 pack2(float lo, float hi) {
    return (u32)f2bf(lo) | ((u32)f2bf(hi) << 16);
}

// ============ passA: coarse histograms + weight pack ============

__global__ __launch_bounds__(256)
void passA(const int* __restrict__ src, const int* __restrict__ dst,
           int* __restrict__ blk_cnt_src, int* __restrict__ blk_cnt_dst,
           const float* __restrict__ W1, const float* __restrict__ W2,
           u16* __restrict__ Pb1, u16* __restrict__ Pb2) {
    const int t = threadIdx.x, blk = blockIdx.x;
    if (blk >= NBLK_E) {                           // ---- weight-pack blocks ----
        int tt = (blk - NBLK_E) * 256 + t;
        if (tt < 3 * D_IN * HID) {                 // 18432: K=96, NC=192, OUTW=64
            int j = tt & 7, rest = tt >> 3;
            int c = rest % 192, i = (rest / 192) * 8 + j;
            int kc = c / 64, o = c % 64;
            Pb1[tt] = f2bf(W1[((long)kc * D_IN + i) * HID + o]);
        } else if (tt < PACK_TOT) {
            int t2 = tt - 3 * D_IN * HID;          // 3072: K=64, NC=48, OUTW=16
            int j = t2 & 7, rest = t2 >> 3;
            int c = rest % 48, i = (rest / 48) * 8 + j;
            int kc = c / 16, o = c % 16;
            Pb2[t2] = f2bf(W2[((long)kc * HID + i) * D_OUT + o]);
        }
        return;
    }
    // ---- histogram blocks ----
    __shared__ int hs[NBKT], hd[NBKT];
    for (int i = t; i < NBKT; i += 256) { hs[i] = 0; hd[i] = 0; }
    __syncthreads();
    const int e0 = blk * EPB;
    if (e0 + EPB <= N_EDGES) {                     // full block: 16 edges/thread
        const int base = e0 + t * 16;
        #pragma unroll
        for (int v = 0; v < 4; ++v) {
            int4 s4 = *(const int4*)(src + base + v * 4);
            int4 d4 = *(const int4*)(dst + base + v * 4);
            atomicAdd(&hs[s4.x >> BSHIFT], 1); atomicAdd(&hs[s4.y >> BSHIFT], 1);
            atomicAdd(&hs[s4.z >> BSHIFT], 1); atomicAdd(&hs[s4.w >> BSHIFT], 1);
            atomicAdd(&hd[d4.x >> BSHIFT], 1); atomicAdd(&hd[d4.y >> BSHIFT], 1);
            atomicAdd(&hd[d4.z >> BSHIFT], 1); atomicAdd(&hd[d4.w >> BSHIFT], 1);
        }
    } else {                                       // tail block
        for (int e = e0 + t; e < N_EDGES; e += 256) {
            atomicAdd(&hs[src[e] >> BSHIFT], 1);
            atomicAdd(&hd[dst[e] >> BSHIFT], 1);
        }
    }
    __syncthreads();
    for (int b = t; b < NBKT; b += 256) {
        blk_cnt_src[b * NBLK_E + blk] = hs[b];
        blk_cnt_dst[b * NBLK_E + blk] = hd[b];
    }
}

// passB: per-bucket exclusive scan over the block dimension; one wave per bucket.
__global__ __launch_bounds__(256)
void passB(int* __restrict__ blk_cnt_src, int* __restrict__ blk_cnt_dst,
           int* __restrict__ tot_src, int* __restrict__ tot_dst) {
    const int b = blockIdx.x * 4 + (threadIdx.x >> 6);
    if (b >= 2 * NBKT) return;
    int* cnt; int* tot;
    if (b < NBKT) { cnt = blk_cnt_dst + b * NBLK_E;          tot = tot_dst + b; }
    else          { cnt = blk_cnt_src + (b - NBKT) * NBLK_E; tot = tot_src + (b - NBKT); }
    const int lane = threadIdx.x & 63;
    int carry = 0;
    for (int base0 = 0; base0 < NBLK_E; base0 += 64) {
        int i = base0 + lane;
        int v = (i < NBLK_E) ? cnt[i] : 0;
        int incl = v;
        #pragma unroll
        for (int off = 1; off < 64; off <<= 1) {
            int x = __shfl_up(incl, off);
            if (lane >= off) incl += x;
        }
        if (i < NBLK_E) cnt[i] = carry + incl - v;
        carry += __shfl(incl, 63);
    }
    if (lane == 0) *tot = carry;
}

// ============ gemm body (B-fragments direct from global) ============
// Emits: D02 = Z0 - Z2 ; Z1 ; Z2out = Z2 (raw; scaled later in passD)

template<int K, int NC, int LDZ, int CPK, bool AF32>
__device__ __forceinline__
void gemm_body(int tile, int lane, const void* __restrict__ Av, const u16* __restrict__ P,
               u16* __restrict__ D02, u16* __restrict__ Z1, u16* __restrict__ Z2out) {
    constexpr int KT = K / 32;
    const int node0 = tile * 16;
    const int sub = lane >> 4, r16 = lane & 15;
    bf16x8 a[KT];
    if constexpr (AF32) {
        const float* ar = (const float*)Av + (long)(node0 + r16) * K + sub * 8;
        #pragma unroll
        for (int kt = 0; kt < KT; ++kt) {
            float4 a0 = *(const float4*)(ar + kt * 32);
            float4 a1 = *(const float4*)(ar + kt * 32 + 4);
            union { bf16x8 v; uint4 q; } u;
            u.q.x = pack2(a0.x, a0.y); u.q.y = pack2(a0.z, a0.w);
            u.q.z = pack2(a1.x, a1.y); u.q.w = pack2(a1.z, a1.w);
            a[kt] = u.v;
        }
    } else {
        const u16* ar = (const u16*)Av + (long)(node0 + r16) * K + sub * 8;
        #pragma unroll
        for (int kt = 0; kt < KT; ++kt)
            a[kt] = *(const bf16x8*)(ar + kt * 32);
    }
    auto cc = [&](int ct) {
        f32x4 acc = {0.f, 0.f, 0.f, 0.f};
        #pragma unroll
        for (int kt = 0; kt < KT; ++kt) {
            bf16x8 bfr = *(const bf16x8*)&P[((kt * 4 + sub) * NC + ct * 16 + r16) * 8];
            acc = __builtin_amdgcn_mfma_f32_16x16x32_bf16(a[kt], bfr, acc, 0, 0, 0);
        }
        return acc;
    };
    #pragma unroll
    for (int i = 0; i < CPK; ++i) {                // plane0/plane2 pairwise
        f32x4 acc0 = cc(i);
        f32x4 acc2 = cc(2 * CPK + i);
        const long rowoff = (long)(node0 + sub * 4) * LDZ + i * 16 + r16;
        #pragma unroll
        for (int r = 0; r < 4; ++r) {
            D02[rowoff + (long)r * LDZ] = f2bf(acc0[r] - acc2[r]);
            Z2out[rowoff + (long)r * LDZ] = f2bf(acc2[r]);
        }
    }
    #pragma unroll
    for (int i = 0; i < CPK; ++i) {                // plane1
        f32x4 acc1 = cc(CPK + i);
        const long rowoff = (long)(node0 + sub * 4) * LDZ + i * 16 + r16;
        #pragma unroll
        for (int r = 0; r < 4; ++r)
            Z1[rowoff + (long)r * LDZ] = f2bf(acc1[r]);
    }
}

// ============ merged passC + gemm1 ============

__global__ __launch_bounds__(256)
void passC_gemm1(const int* __restrict__ src, const int* __restrict__ dst,
                 const int* __restrict__ blk_off_src, const int* __restrict__ blk_off_dst,
                 const int* __restrict__ tot_src, const int* __restrict__ tot_dst,
                 u16* __restrict__ sorted_srconly, u32* __restrict__ sorted_pair,
                 const float* __restrict__ x, const u16* __restrict__ Pb1,
                 u16* __restrict__ D02, u16* __restrict__ Z1, u16* __restrict__ Zs) {
    __shared__ int s[512];
    __shared__ int cs[NBKT], cd[NBKT];
    const int t = threadIdx.x, blk = blockIdx.x;
    if (blk >= NBLK_E) {                           // ---- gemm1 blocks (no LDS use) ----
        const int tile = (blk - NBLK_E) * 4 + (t >> 6);
        if (tile * 16 >= N_NODES) return;
        gemm_body<D_IN, 192, HID, 4, true>(tile, t & 63, x, Pb1, D02, Z1, Zs);
        return;
    }
    // ---- passC blocks ----
    for (int pass = 0; pass < 2; ++pass) {
        const int* tot = pass ? tot_src : tot_dst;
        const int* bo  = pass ? blk_off_src : blk_off_dst;
        int* cx = pass ? cs : cd;
        s[t]       = (t < NBKT) ? tot[t] : 0;
        s[t + 256] = (t + 256 < NBKT) ? tot[t + 256] : 0;
        __syncthreads();
        for (int off = 1; off < 512; off <<= 1) {
            int a1 = (t >= off) ? s[t - off] : 0;
            int a2 = (t + 256 >= off) ? s[t + 256 - off] : 0;
            __syncthreads();
            s[t] += a1; s[t + 256] += a2;
            __syncthreads();
        }
        if (t < NBKT) cx[t] = s[t] - tot[t] + bo[t * NBLK_E + blk];
        if (t + 256 < NBKT) cx[t + 256] = s[t + 256] - tot[t + 256] + bo[(t + 256) * NBLK_E + blk];
        __syncthreads();
    }
    const int e0 = blk * EPB;
    if (e0 + EPB <= N_EDGES) {                     // full block: 16 edges/thread
        const int base = e0 + t * 16;
        #pragma unroll
        for (int v = 0; v < 4; ++v) {
            int4 s4 = *(const int4*)(src + base + v * 4);
            int4 d4 = *(const int4*)(dst + base + v * 4);
            int sv[4] = {s4.x, s4.y, s4.z, s4.w};
            int dv[4] = {d4.x, d4.y, d4.z, d4.w};
            #pragma unroll
            for (int k = 0; k < 4; ++k) {
                int ps = atomicAdd(&cs[sv[k] >> BSHIFT], 1);
                sorted_srconly[ps] = (u16)sv[k];
                int pd = atomicAdd(&cd[dv[k] >> BSHIFT], 1);
                sorted_pair[pd] = ((u32)dv[k] << 16) | (u32)sv[k];
            }
        }
    } else {
        for (int e = e0 + t; e < N_EDGES; e += 256) {
            int sv = src[e], dv = dst[e];
            int ps = atomicAdd(&cs[sv >> BSHIFT], 1);
            sorted_srconly[ps] = (u16)sv;
            int pd = atomicAdd(&cd[dv >> BSHIFT], 1);
            sorted_pair[pd] = ((u32)dv << 16) | (u32)sv;
        }
    }
}

// passD: merged Dsrc (deg->dis + in-place Zs scaling) + Ddst (fine CSR).
__global__ __launch_bounds__(256)
void passD(const int* __restrict__ tot_src, const u16* __restrict__ sorted_srconly,
           const int* __restrict__ tot_dst, const u32* __restrict__ sorted_pair,
           float* __restrict__ dis, int* __restrict__ row_ptr, u16* __restrict__ wsrc,
           u16* __restrict__ Zs) {
    __shared__ int sred[256];
    __shared__ int hist[128];
    __shared__ int cur[128];
    __shared__ float s_dis[128];
    __shared__ __align__(16) u32 s_p[DCAP];
    const int t = threadIdx.x;
    const bool isSrc = blockIdx.x < NBKT;
    const int b = isSrc ? blockIdx.x : blockIdx.x - NBKT;
    const int* tot = isSrc ? tot_src : tot_dst;
    int part = 0;
    for (int i = t; i < b; i += 256) part += tot[i];
    sred[t] = part;
    if (t < 128) hist[t] = 0;
    __syncthreads();
    #pragma unroll
    for (int off = 128; off > 0; off >>= 1) {
        if (t < off) sred[t] += sred[t + off];
        __syncthreads();
    }
    const int eb = sred[0];
    const int ee = eb + tot[b];
    if (isSrc) {                                   // ---- Dsrc half (uint4 reads) ----
        const int cnt = ee - eb;
        const int skew = eb & 7;
        const int gb = eb - skew;
        const int nv = (skew + cnt + 7) >> 3;
        for (int i = t; i < nv; i += 256) {
            uint4 q = *(const uint4*)(sorted_srconly + gb + i * 8);
            u32 w[4] = {q.x, q.y, q.z, q.w};
            int lo = i * 8;
            #pragma unroll
            for (int k = 0; k < 4; ++k) {
                int l0 = lo + 2 * k, l1 = l0 + 1;
                if (l0 >= skew && l0 < skew + cnt) atomicAdd(&hist[w[k] & 127], 1);
                if (l1 >= skew && l1 < skew + cnt) atomicAdd(&hist[(w[k] >> 16) & 127], 1);
            }
        }
        __syncthreads();
        const int node0 = b << BSHIFT;
        if (t < 128) {
            int c = hist[t];
            float dv = c > 0 ? rsqrtf((float)c) : 0.0f;
            s_dis[t] = dv;
            if (node0 + t < N_NODES) dis[node0 + t] = dv;
        }
        __syncthreads();
        for (int c = t; c < 128 * 8; c += 256) {   // in-place scale Zs *= dis
            int ln = c >> 3, off8 = (c & 7) * 8;
            int n = node0 + ln;
            if (n >= N_NODES) continue;
            float dv = s_dis[ln];
            u16* zp = Zs + (long)n * HID + off8;
            uint4 q = *(uint4*)zp;
            uint4 r;
            r.x = pack2(bflo(q.x) * dv, bfhi(q.x) * dv);
            r.y = pack2(bflo(q.y) * dv, bfhi(q.y) * dv);
            r.z = pack2(bflo(q.z) * dv, bfhi(q.z) * dv);
            r.w = pack2(bflo(q.w) * dv, bfhi(q.w) * dv);
            *(uint4*)zp = r;
        }
        return;
    }
    // ---- Ddst half (vector-staged) ----
    if (b == 0 && t == 0) row_ptr[N_NODES] = N_EDGES;
    const int cnt = ee - eb;
    const int skew = eb & 3;
    const int gb = eb - skew;                      // aligned base (element index)
    const int tot4 = skew + cnt;
    int nv = (tot4 + 3) >> 2;
    if (nv > (DCAP >> 2)) nv = DCAP >> 2;
    for (int i = t; i < nv; i += 256)
        *(uint4*)&s_p[i * 4] = *(const uint4*)(sorted_pair + gb + i * 4);
    __syncthreads();
    const int lstage = nv * 4;                     // locals [0,lstage) staged
    const int lbeg = skew, lend = skew + cnt;
    const int lmid = lend < lstage ? lend : lstage;
    for (int l = lbeg + t; l < lmid; l += 256)
        atomicAdd(&hist[(s_p[l] >> 16) & 127], 1);
    for (int l = (lbeg > lstage ? lbeg : lstage) + t; l < lend; l += 256)
        atomicAdd(&hist[(sorted_pair[gb + l] >> 16) & 127], 1);
    __syncthreads();
    if (t < 64) {
        int v0 = hist[2 * t], v1 = hist[2 * t + 1];
        int p = v0 + v1;
        int incl = p;
        #pragma unroll
        for (int off = 1; off < 64; off <<= 1) {
            int x = __shfl_up(incl, off);
            if (t >= off) incl += x;
        }
        int excl = incl - p;
        cur[2 * t] = excl;
        cur[2 * t + 1] = excl + v0;
        int node = (b << BSHIFT) + 2 * t;
        if (node < N_NODES) row_ptr[node] = eb + excl;
        if (node + 1 < N_NODES) row_ptr[node + 1] = eb + excl + v0;
    }
    __syncthreads();
    for (int l = lbeg + t; l < lmid; l += 256) {
        u32 v = s_p[l];
        int slot = atomicAdd(&cur[(v >> 16) & 127], 1);
        wsrc[eb + slot] = (u16)(v & 0xFFFF);
    }
    for (int l = (lbeg > lstage ? lbeg : lstage) + t; l < lend; l += 256) {
        u32 v = sorted_pair[gb + l];
        int slot = atomicAdd(&cur[(v >> 16) & 127], 1);
        wsrc[eb + slot] = (u16)(v & 0xFFFF);
    }
}

// ============ gather helpers ============

__device__ inline void sum8(float (&acc)[8], uint4 q) {
    acc[0] += bflo(q.x); acc[1] += bfhi(q.x);
    acc[2] += bflo(q.y); acc[3] += bfhi(q.y);
    acc[4] += bflo(q.z); acc[5] += bfhi(q.z);
    acc[6] += bflo(q.w); acc[7] += bfhi(q.w);
}

template<int F>
__device__ __forceinline__
void gather_loop(float (&acc)[8], const u16* s_p, const u16* ws, const u16* g,
                 int beg, int mid, int end, int stage, int gb, int c8) {
    int e = beg;
    for (; e + 8 <= mid; e += 8) {
        int p0 = s_p[e],     p1 = s_p[e + 1], p2 = s_p[e + 2], p3 = s_p[e + 3];
        int p4 = s_p[e + 4], p5 = s_p[e + 5], p6 = s_p[e + 6], p7 = s_p[e + 7];
        uint4 q0 = *(const uint4*)(g + (long)p0 * F + c8);
        uint4 q1 = *(const uint4*)(g + (long)p1 * F + c8);
        uint4 q2 = *(const uint4*)(g + (long)p2 * F + c8);
        uint4 q3 = *(const uint4*)(g + (long)p3 * F + c8);
        uint4 q4 = *(const uint4*)(g + (long)p4 * F + c8);
        uint4 q5 = *(const uint4*)(g + (long)p5 * F + c8);
        uint4 q6 = *(const uint4*)(g + (long)p6 * F + c8);
        uint4 q7 = *(const uint4*)(g + (long)p7 * F + c8);
        sum8(acc, q0); sum8(acc, q1); sum8(acc, q2); sum8(acc, q3);
        sum8(acc, q4); sum8(acc, q5); sum8(acc, q6); sum8(acc, q7);
    }
    for (; e + 4 <= mid; e += 4) {
        int p0 = s_p[e], p1 = s_p[e + 1], p2 = s_p[e + 2], p3 = s_p[e + 3];
        uint4 q0 = *(const uint4*)(g + (long)p0 * F + c8);
        uint4 q1 = *(const uint4*)(g + (long)p1 * F + c8);
        uint4 q2 = *(const uint4*)(g + (long)p2 * F + c8);
        uint4 q3 = *(const uint4*)(g + (long)p3 * F + c8);
        sum8(acc, q0); sum8(acc, q1); sum8(acc, q2); sum8(acc, q3);
    }
    for (; e < mid; ++e)
        sum8(acc, *(const uint4*)(g + (long)s_p[e] * F + c8));
    for (e = (beg > stage ? beg : stage); e < end; ++e)     // overflow fallback (rare)
        sum8(acc, *(const uint4*)(g + (long)ws[gb + e] * F + c8));
}

// Skew-aligned u16 staging: stage ws[gb + 0 .. nv*8) into s_p[0 .. nv*8), gb = ebeg & ~7.
template<int CAP>
__device__ __forceinline__
int stage_u16(u16* s_p, const u16* __restrict__ ws, int gb, int tot, int tid) {
    int nv = (tot + 7) >> 3;
    if (nv > (CAP >> 3)) nv = CAP >> 3;
    for (int i = tid; i < nv; i += 256)
        *(uint4*)&s_p[i * 8] = *(const uint4*)(ws + gb + i * 8);
    return nv * 8;
}

// ============ gather propagate (P1 / P3 / P4) ============
// EPI_S  : Ŝ  = dis_d*aux1 - 2*dis_d^2*acc           (aux1 = Z1; bf16 out)
// EPI_OUT: out = aux1 - dis_d*acc + bias              (aux1 = D02'; f32 out)

#define EPI_S 0
#define EPI_OUT 2

template<int F, int NPB, int CAP, int EPI>
__global__ __launch_bounds__(256)
void gather_prop(const int* __restrict__ row_ptr, const u16* __restrict__ ws,
                 const u16* __restrict__ g, const u16* __restrict__ aux1,
                 const float* __restrict__ bias, const float* __restrict__ dis,
                 void* __restrict__ outp) {
    static_assert(NPB * (F / 8) == 256, "block geometry");
    __shared__ __align__(16) u16 s_p[CAP];
    __shared__ int s_beg[NPB + 1];
    const int tid = threadIdx.x;
    const int node0 = blockIdx.x * NPB;
    if (tid <= NPB) {
        int n = node0 + tid;
        s_beg[tid] = row_ptr[n > N_NODES ? N_NODES : n];
    }
    __syncthreads();
    const int ebeg = s_beg[0];
    const int cnt = s_beg[NPB] - ebeg;
    const int skew = ebeg & 7;
    const int gb = ebeg - skew;
    const int lstage = stage_u16<CAP>(s_p, ws, gb, skew + cnt, tid);
    __syncthreads();
    constexpr int CPN = F / 8;
    const int nl = tid / CPN;
    const int node = node0 + nl;
    if (node >= N_NODES) return;
    const int c8 = (tid % CPN) * 8;
    float acc[8];
    #pragma unroll
    for (int j = 0; j < 8; ++j) acc[j] = 0.0f;
    const int lbeg = s_beg[nl] - gb;
    const int lend = s_beg[nl + 1] - gb;
    const int lmid = lend < lstage ? lend : lstage;
    gather_loop<F>(acc, s_p, ws, g, lbeg, lmid, lend, lstage, gb, c8);
    const float dd = dis[node];
    if (EPI == EPI_S) {
        const float m1 = dd, m2 = -2.0f * dd * dd;
        const uint4 z1 = *(const uint4*)(aux1 + (long)node * F + c8);
        uint4 r;
        r.x = pack2(fmaf(m1, bflo(z1.x), m2 * acc[0]), fmaf(m1, bfhi(z1.x), m2 * acc[1]));
        r.y = pack2(fmaf(m1, bflo(z1.y), m2 * acc[2]), fmaf(m1, bfhi(z1.y), m2 * acc[3]));
        r.z = pack2(fmaf(m1, bflo(z1.z), m2 * acc[4]), fmaf(m1, bfhi(z1.z), m2 * acc[5]));
        r.w = pack2(fmaf(m1, bflo(z1.w), m2 * acc[6]), fmaf(m1, bfhi(z1.w), m2 * acc[7]));
        *(uint4*)((u16*)outp + (long)node * F + c8) = r;
    } else {
        const uint4 z0 = *(const uint4*)(aux1 + (long)node * F + c8);
        const float* bb = bias + c8;
        float v0 = bflo(z0.x) - dd * acc[0] + bb[0];
        float v1 = bfhi(z0.x) - dd * acc[1] + bb[1];
        float v2 = bflo(z0.y) - dd * acc[2] + bb[2];
        float v3 = bfhi(z0.y) - dd * acc[3] + bb[3];
        float v4 = bflo(z0.z) - dd * acc[4] + bb[4];
        float v5 = bfhi(z0.z) - dd * acc[5] + bb[5];
        float v6 = bflo(z0.w) - dd * acc[6] + bb[6];
        float v7 = bfhi(z0.w) - dd * acc[7] + bb[7];
        float* op = (float*)outp + (long)node * F + c8;
        *(float4*)op = make_float4(v0, v1, v2, v3);
        *(float4*)(op + 4) = make_float4(v4, v5, v6, v7);
    }
}

// ============ fused P2 + gemm2 (W2 fragments direct from global) ============

__global__ __launch_bounds__(256)
void prop2_gemm2(const int* __restrict__ row_ptr, const u16* __restrict__ ws,
                 const u16* __restrict__ S, const u16* __restrict__ D02,
                 const float* __restrict__ b1, const float* __restrict__ dis,
                 const u16* __restrict__ Pb2,
                 u16* __restrict__ D02p, u16* __restrict__ Z1p, u16* __restrict__ Zsp) {
    constexpr int NPB = 32, CAP = 1288;            // 1280 + 8 skew headroom
    __shared__ __align__(16) u16 s_p[CAP];
    __shared__ int s_beg[NPB + 1];
    __shared__ u16 h_tile[NPB][HID + 8];           // +8 pad: break 128B-stride banks
    const int tid = threadIdx.x;
    const int node0 = blockIdx.x * NPB;
    if (tid <= NPB) {
        int n = node0 + tid;
        s_beg[tid] = row_ptr[n > N_NODES ? N_NODES : n];
    }
    __syncthreads();
    const int ebeg = s_beg[0];
    const int cnt = s_beg[NPB] - ebeg;
    const int skew = ebeg & 7;
    const int gb = ebeg - skew;
    const int lstage = stage_u16<CAP>(s_p, ws, gb, skew + cnt, tid);
    __syncthreads();
    const int nl = tid >> 3;                       // CPN = 8
    const int node = node0 + nl;
    const int c8 = (tid & 7) * 8;
    if (node < N_NODES) {                          // NO early return (barrier below)
        float acc[8];
        #pragma unroll
        for (int j = 0; j < 8; ++j) acc[j] = 0.0f;
        const int lbeg = s_beg[nl] - gb;
        const int lend = s_beg[nl + 1] - gb;
        const int lmid = lend < lstage ? lend : lstage;
        gather_loop<HID>(acc, s_p, ws, S, lbeg, lmid, lend, lstage, gb, c8);
        const float dd = dis[node];
        const uint4 z0 = *(const uint4*)(D02 + (long)node * HID + c8);
        const float* bb = b1 + c8;
        float v0 = bflo(z0.x) - dd * acc[0] + bb[0];
        float v1 = bfhi(z0.x) - dd * acc[1] + bb[1];
        float v2 = bflo(z0.y) - dd * acc[2] + bb[2];
        float v3 = bfhi(z0.y) - dd * acc[3] + bb[3];
        float v4 = bflo(z0.z) - dd * acc[4] + bb[4];
        float v5 = bfhi(z0.z) - dd * acc[5] + bb[5];
        float v6 = bflo(z0.w) - dd * acc[6] + bb[6];
        float v7 = bfhi(z0.w) - dd * acc[7] + bb[7];
        uint4 r;
        r.x = pack2(fmaxf(v0, 0.f), fmaxf(v1, 0.f));
        r.y = pack2(fmaxf(v2, 0.f), fmaxf(v3, 0.f));
        r.z = pack2(fmaxf(v4, 0.f), fmaxf(v5, 0.f));
        r.w = pack2(fmaxf(v6, 0.f), fmaxf(v7, 0.f));
        *(uint4*)&h_tile[nl][c8] = r;
    }
    __syncthreads();
    // ---- gemm2 from LDS h_tile: waves 0,1 handle the block's two 16-node tiles ----
    const int w = tid >> 6;
    if (w >= 2) return;
    const int tile = blockIdx.x * 2 + w;
    if (tile * 16 >= N_NODES) return;
    const int lane = tid & 63;
    const int sub = lane >> 4, r16 = lane & 15;
    const int gnode0 = tile * 16;
    float dis4[4];
    #pragma unroll
    for (int r = 0; r < 4; ++r) dis4[r] = dis[gnode0 + sub * 4 + r];
    bf16x8 a[2];
    const u16* ar = &h_tile[w * 16 + r16][sub * 8];
    a[0] = *(const bf16x8*)(ar);
    a[1] = *(const bf16x8*)(ar + 32);
    auto cc = [&](int ct) {
        f32x4 acc = {0.f, 0.f, 0.f, 0.f};
        #pragma unroll
        for (int kt = 0; kt < 2; ++kt) {
            bf16x8 bfr = *(const bf16x8*)&Pb2[((kt * 4 + sub) * 48 + ct * 16 + r16) * 8];
            acc = __builtin_amdgcn_mfma_f32_16x16x32_bf16(a[kt], bfr, acc, 0, 0, 0);
        }
        return acc;
    };
    f32x4 acc0 = cc(0);
    f32x4 acc2 = cc(2);
    f32x4 acc1 = cc(1);
    const long rowoff = (long)(gnode0 + sub * 4) * D_OUT + r16;
    #pragma unroll
    for (int r = 0; r < 4; ++r) {
        D02p[rowoff + (long)r * D_OUT] = f2bf(acc0[r] - acc2[r]);
        Zsp[rowoff + (long)r * D_OUT]  = f2bf(acc2[r] * dis4[r]);
        Z1p[rowoff + (long)r * D_OUT]  = f2bf(acc1[r]);
    }
}

// ============ launch ============

extern "C" void kernel_launch(void* const* d_in, const int* in_sizes, int n_in,
                              void* d_out, int out_size, void* d_ws, size_t ws_size,
                              hipStream_t stream) {
    const float* x  = (const float*)d_in[0];
    const int*   ei = (const int*)d_in[1];
    const float* W1 = (const float*)d_in[2];
    const float* b1 = (const float*)d_in[3];
    const float* W2 = (const float*)d_in[4];
    const float* b2 = (const float*)d_in[5];
    const int* src = ei;
    const int* dst = ei + N_EDGES;

    // ---- workspace (sections aligned; u16 region starts 16B-aligned) ----
    float* dis          = (float*)d_ws;                      // 50000
    int*   row_ptr      = (int*)(dis + N_NODES);             // 50016
    int*   blk_cnt_src  = row_ptr + 50016;                   // 152896 (padded)
    int*   blk_cnt_dst  = blk_cnt_src + 152896;              // 152896
    int*   tot_src      = blk_cnt_dst + 152896;              // 512
    int*   tot_dst      = tot_src + 512;                     // 512
    u16*   srconly      = (u16*)(tot_dst + 512);             // E u16
    u32*   sorted_pair  = (u32*)(srconly + N_EDGES);         // E u32
    u16*   wsrc         = (u16*)(sorted_pair + N_EDGES);     // E u16
    u16*   D02          = wsrc + N_EDGES;                    // N*64  (Z0 - Z2)
    u16*   Z1b          = D02 + (long)N_NODES * HID;         // N*64
    u16*   Zs           = Z1b + (long)N_NODES * HID;         // N*64  (Z2, scaled in passD)
    u16*   S            = Zs  + (long)N_NODES * HID;         // N*64  (Ŝ, pre-scaled)
    u16*   D02p         = S   + (long)N_NODES * HID;         // N*16
    u16*   Z1p          = D02p + (long)N_NODES * D_OUT;      // N*16
    u16*   Zsp          = Z1p  + (long)N_NODES * D_OUT;      // N*16
    u16*   Sp           = Zsp  + (long)N_NODES * D_OUT;      // N*16
    u16*   Pb1          = Sp   + (long)N_NODES * D_OUT;      // 18432
    u16*   Pb2          = Pb1 + 18432;                       // 3072

    // ---- build + layer-1 GEMM (gemm1 overlapped with passC) ----
    passA<<<NBLK_E + PACK_BLKS, 256, 0, stream>>>(
        src, dst, blk_cnt_src, blk_cnt_dst, W1, W2, Pb1, Pb2);
    passB<<<(2 * NBKT + 3) / 4, 256, 0, stream>>>(blk_cnt_src, blk_cnt_dst, tot_src, tot_dst);
    passC_gemm1<<<NBLK_E + GEMM1_BLKS, 256, 0, stream>>>(
        src, dst, blk_cnt_src, blk_cnt_dst, tot_src, tot_dst,
        srconly, sorted_pair, x, Pb1, D02, Z1b, Zs);
    passD<<<2 * NBKT, 256, 0, stream>>>(tot_src, srconly, tot_dst, sorted_pair,
                                        dis, row_ptr, wsrc, Zs);

    // ---- layer 1: P1, then fused P2+gemm2 ----
    gather_prop<HID, 32, 1288, EPI_S><<<(N_NODES + 31) / 32, 256, 0, stream>>>(
        row_ptr, wsrc, Zs, Z1b, nullptr, dis, S);
    prop2_gemm2<<<(N_NODES + 31) / 32, 256, 0, stream>>>(
        row_ptr, wsrc, S, D02, b1, dis, Pb2, D02p, Z1p, Zsp);

    // ---- layer 2 props ----
    gather_prop<D_OUT, 128, 3088, EPI_S><<<(N_NODES + 127) / 128, 256, 0, stream>>>(
        row_ptr, wsrc, Zsp, Z1p, nullptr, dis, Sp);
    gather_prop<D_OUT, 128, 3088, EPI_OUT><<<(N_NODES + 127) / 128, 256, 0, stream>>>(
        row_ptr, wsrc, Sp, D02p, b2, dis, (float*)d_out);
}